// Round 4
// baseline (277.628 us; speedup 1.0000x reference)
//
#include <hip/hip_runtime.h>
#include <hip/hip_bf16.h>
#include <cstdint>
#include <cstddef>

typedef __attribute__((ext_vector_type(4))) float f32x4;
typedef __attribute__((ext_vector_type(8))) short bf16x8;

#define B_    2
#define T_    2048
#define EMB_  2048
#define NQ_   32
#define NKV_  8
#define HEAD_ 64
#define NTOT_ 3072
#define M_    (B_ * T_)     // 4096
#define QBLK_ 128
#define NK_   32            // K=2048 / BK=64 for both GEMMs

#define MFMA_ __builtin_amdgcn_mfma_f32_16x16x32_bf16

__device__ __forceinline__ unsigned short f2bf(float f) {
  union { float f; unsigned int u; } v; v.f = f;
  unsigned int r = v.u + 0x7fffu + ((v.u >> 16) & 1u);
  return (unsigned short)(r >> 16);
}

__device__ __forceinline__ float bf2f(unsigned short u) {
  union { unsigned int u; float f; } v; v.u = (unsigned int)u << 16; return v.f;
}

__device__ __forceinline__ unsigned int pk_bf16(float lo, float hi) {
  __hip_bfloat162 h = __float22bfloat162_rn(make_float2(lo, hi));
  union { __hip_bfloat162 h; unsigned int u; } c; c.h = h;
  return c.u;
}

__device__ __forceinline__ void gload_lds16(const void* g, void* l) {
  __builtin_amdgcn_global_load_lds(
      (const __attribute__((address_space(1))) void*)g,
      (__attribute__((address_space(3))) void*)l, 16, 0, 0);
}

// ---------------- elementwise converts / relayouts ----------------

__global__ void cvt_bf16_kernel(const float* __restrict__ src,
                                unsigned short* __restrict__ dst, int n4) {
  int i = blockIdx.x * blockDim.x + threadIdx.x;
  if (i >= n4) return;
  float4 v = ((const float4*)src)[i];
  unsigned long long pk =
      (unsigned long long)f2bf(v.x) |
      ((unsigned long long)f2bf(v.y) << 16) |
      ((unsigned long long)f2bf(v.z) << 32) |
      ((unsigned long long)f2bf(v.w) << 48);
  *(unsigned long long*)(dst + (size_t)i * 4) = pk;
}

// src fp32 [R][C]  ->  dst bf16 [C][R]
__global__ void transpose_cvt_kernel(const float* __restrict__ src,
                                     unsigned short* __restrict__ dst,
                                     int R, int C) {
  __shared__ float tile[32][33];
  int c0 = blockIdx.x * 32, r0 = blockIdx.y * 32;
  int tx = threadIdx.x, ty = threadIdx.y;
#pragma unroll
  for (int k = 0; k < 4; ++k)
    tile[ty + 8 * k][tx] = src[(size_t)(r0 + ty + 8 * k) * C + c0 + tx];
  __syncthreads();
#pragma unroll
  for (int k = 0; k < 4; ++k)
    dst[(size_t)(c0 + ty + 8 * k) * R + r0 + tx] = f2bf(tile[tx][ty + 8 * k]);
}

__global__ void concat_bias_kernel(const float* __restrict__ bq,
                                   const float* __restrict__ bk,
                                   const float* __restrict__ bv,
                                   float* __restrict__ dst) {
  int i = blockIdx.x * 256 + threadIdx.x;
  if (i < 2048) dst[i] = bq[i];
  else if (i < 2560) dst[i] = bk[i - 2048];
  else if (i < 3072) dst[i] = bv[i - 2560];
}

#define L2_10000 13.2877123795494f

// QKVlin bf16 [4096][3072] -> Qh bf16 [b][h][t][64] with RoPE; 0.125 folded.
__global__ void rope_q_kernel(const unsigned short* __restrict__ qkv,
                              unsigned short* __restrict__ Qh) {
  int idx = blockIdx.x * 256 + threadIdx.x;   // B*T*NQ*32
  int i  = idx & 31;
  int h  = (idx >> 5) & 31;
  int bt = idx >> 10;
  int t  = bt & (T_ - 1);
  int b  = bt >> 11;
  float invf = exp2f(-(float)i * (L2_10000 / 32.f));
  float ang = (float)t * invf;
  float s, c; sincosf(ang, &s, &c);
  const unsigned short* row = qkv + (size_t)bt * NTOT_ + h * 64;
  float x1 = bf2f(row[i]), x2 = bf2f(row[i + 32]);
  unsigned short* q = Qh + ((size_t)(b * NQ_ + h) * T_ + t) * HEAD_;
  q[i]      = f2bf((x1 * c - x2 * s) * 0.125f);
  q[i + 32] = f2bf((x2 * c + x1 * s) * 0.125f);
}

__global__ void rope_k_kernel(const unsigned short* __restrict__ qkv,
                              unsigned short* __restrict__ Kh) {
  int idx = blockIdx.x * 256 + threadIdx.x;   // B*T*NKV*32
  int i  = idx & 31;
  int kh = (idx >> 5) & 7;
  int bt = idx >> 8;
  int t  = bt & (T_ - 1);
  int b  = bt >> 11;
  float invf = exp2f(-(float)i * (L2_10000 / 32.f));
  float ang = (float)t * invf;
  float s, c; sincosf(ang, &s, &c);
  const unsigned short* row = qkv + (size_t)bt * NTOT_ + 2048 + kh * 64;
  float x1 = bf2f(row[i]), x2 = bf2f(row[i + 32]);
  unsigned short* kp = Kh + ((size_t)(b * NKV_ + kh) * T_ + t) * HEAD_;
  kp[i]      = f2bf(x1 * c - x2 * s);
  kp[i + 32] = f2bf(x2 * c + x1 * s);
}

// V (bf16 in QKVlin) -> Vt bf16 [b][kh][d][t]  (pure relayout copy)
__global__ void vt_kernel(const unsigned short* __restrict__ qkv,
                          unsigned short* __restrict__ Vt) {
  int idx = blockIdx.x * 256 + threadIdx.x;   // B*NKV*HEAD*T
  int t  = idx & (T_ - 1);
  int d  = (idx >> 11) & 63;
  int kh = (idx >> 17) & 7;
  int b  = idx >> 20;
  Vt[((size_t)((b * NKV_ + kh) * 64 + d)) * T_ + t] =
      qkv[(size_t)(b * T_ + t) * NTOT_ + 2560 + kh * 64 + d];
}

// ---------------- 256x256 8-phase GEMM (T2+T3+T4+T5), K=2048 ----------------
// C[M][N] = A[4096][2048](bf16) x BT[N][2048](bf16)^T + bias.
// 512 threads = 8 waves (2M x 4N). Per-wave C = 128x64 via interleaved 16-row
// blocks: A-row(fi) = fi*32 + wm*16 + l16 (fi 0..7), B-col(fjg) = fjg*64 +
// wn*16 + l16 -> phase quadrants align with LDS half-tiles for all waves.
// LDS [2 dbuf][A,B][256 rows][64] bf16, 16B-unit XOR swizzle (unit ^= row&7),
// staged via global_load_lds with pre-swizzled source. 1 half-tile staged per
// phase; vmcnt(6) once per K-tile (drain 0 only at tile NK-2).

template <typename OutT>
__launch_bounds__(512, 2)
__global__ void gemm256_8ph(const unsigned short* __restrict__ A,
                            const unsigned short* __restrict__ BT,
                            const float* __restrict__ bias,
                            OutT* __restrict__ C, int N) {
  __shared__ unsigned short sh[2][2][16384];   // 128 KiB
  const int tid = threadIdx.x;
  const int lane = tid & 63, l16 = lane & 15, lg = lane >> 4;
  const int wave = tid >> 6, wm = wave >> 2, wn = wave & 3;
  const int nwg = gridDim.x;
  const int bid = blockIdx.x;
  const int sw = (bid & 7) * (nwg >> 3) + (bid >> 3);   // XCD swizzle (nwg%8==0)
  const int mt = sw & 15, nt = sw >> 4;
  const int m0 = mt * 256, n0 = nt * 256;
  const int usrc = (tid & 7) ^ ((tid >> 3) & 7);   // pre-swizzled source unit
  const int swz = l16 & 7;
  const int uo0 = (lg ^ swz) << 3;         // element offset, k-chunk 0
  const int uo1 = ((4 + lg) ^ swz) << 3;   // k-chunk 1

  f32x4 acc[8][4];
#pragma unroll
  for (int i = 0; i < 8; ++i)
#pragma unroll
    for (int j = 0; j < 4; ++j) acc[i][j] = (f32x4){0.f, 0.f, 0.f, 0.f};

  auto STG = [&](int ht) {
    if (ht >= 4 * NK_) return;
    const int kt = ht >> 2, reg = ht & 3, bufi = kt & 1;
    const unsigned short* src = (reg < 2) ? A : BT;
    const int grow = ((reg < 2) ? m0 : n0) + ((reg & 1) ? 128 : 0);
    unsigned short* dst = &sh[bufi][reg >> 1][(reg & 1) ? 8192 : 0];
    const size_t base = (size_t)(grow + (tid >> 3)) * 2048 + kt * 64 + usrc * 8;
    gload_lds16(src + base, (char*)dst + tid * 16);
    gload_lds16(src + base + (size_t)64 * 2048, (char*)dst + tid * 16 + 8192);
  };

  // prologue: tile0 all + tile1 {A0,A1,B0}
#pragma unroll
  for (int ht = 0; ht < 7; ++ht) STG(ht);
  asm volatile("s_waitcnt vmcnt(6)" ::: "memory");
  __builtin_amdgcn_s_barrier();

  bf16x8 af[4][2], bfr[2][2];
#pragma unroll 2
  for (int t = 0; t < NK_; ++t) {
    const unsigned short* Ab = &sh[t & 1][0][0];
    const unsigned short* Bb = &sh[t & 1][1][0];

    // ---- phase 1: quadrant (A-lo, B-lo) ----
#pragma unroll
    for (int fi = 0; fi < 4; ++fi) {
      const int ro = (fi * 32 + wm * 16 + l16) * 64;
      af[fi][0] = *(const bf16x8*)(Ab + ro + uo0);
      af[fi][1] = *(const bf16x8*)(Ab + ro + uo1);
    }
#pragma unroll
    for (int fj = 0; fj < 2; ++fj) {
      const int ro = (fj * 64 + wn * 16 + l16) * 64;
      bfr[fj][0] = *(const bf16x8*)(Bb + ro + uo0);
      bfr[fj][1] = *(const bf16x8*)(Bb + ro + uo1);
    }
    STG(7 + 4 * t);                               // (t+1) B1
    __builtin_amdgcn_s_barrier();
    asm volatile("s_waitcnt lgkmcnt(0)" ::: "memory");
    __builtin_amdgcn_sched_barrier(0);
    __builtin_amdgcn_s_setprio(1);
#pragma unroll
    for (int fi = 0; fi < 4; ++fi)
#pragma unroll
      for (int fj = 0; fj < 2; ++fj) {
        acc[fi][fj] = MFMA_(af[fi][0], bfr[fj][0], acc[fi][fj], 0, 0, 0);
        acc[fi][fj] = MFMA_(af[fi][1], bfr[fj][1], acc[fi][fj], 0, 0, 0);
      }
    __builtin_amdgcn_s_setprio(0);
    __builtin_amdgcn_s_barrier();

    // ---- phase 2: (A-lo, B-hi) ----
#pragma unroll
    for (int fj = 0; fj < 2; ++fj) {
      const int ro = ((2 + fj) * 64 + wn * 16 + l16) * 64;
      bfr[fj][0] = *(const bf16x8*)(Bb + ro + uo0);
      bfr[fj][1] = *(const bf16x8*)(Bb + ro + uo1);
    }
    STG(8 + 4 * t);                               // (t+2) A0
    __builtin_amdgcn_s_barrier();
    asm volatile("s_waitcnt lgkmcnt(0)" ::: "memory");
    __builtin_amdgcn_sched_barrier(0);
    __builtin_amdgcn_s_setprio(1);
#pragma unroll
    for (int fi = 0; fi < 4; ++fi)
#pragma unroll
      for (int fj = 0; fj < 2; ++fj) {
        acc[fi][2 + fj] = MFMA_(af[fi][0], bfr[fj][0], acc[fi][2 + fj], 0, 0, 0);
        acc[fi][2 + fj] = MFMA_(af[fi][1], bfr[fj][1], acc[fi][2 + fj], 0, 0, 0);
      }
    __builtin_amdgcn_s_setprio(0);
    __builtin_amdgcn_s_barrier();

    // ---- phase 3: (A-hi, B-hi) ----
#pragma unroll
    for (int fi = 0; fi < 4; ++fi) {
      const int ro = ((4 + fi) * 32 + wm * 16 + l16) * 64;
      af[fi][0] = *(const bf16x8*)(Ab + ro + uo0);
      af[fi][1] = *(const bf16x8*)(Ab + ro + uo1);
    }
    STG(9 + 4 * t);                               // (t+2) A1
    __builtin_amdgcn_s_barrier();
    asm volatile("s_waitcnt lgkmcnt(0)" ::: "memory");
    __builtin_amdgcn_sched_barrier(0);
    __builtin_amdgcn_s_setprio(1);
#pragma unroll
    for (int fi = 0; fi < 4; ++fi)
#pragma unroll
      for (int fj = 0; fj < 2; ++fj) {
        acc[4 + fi][2 + fj] = MFMA_(af[fi][0], bfr[fj][0], acc[4 + fi][2 + fj], 0, 0, 0);
        acc[4 + fi][2 + fj] = MFMA_(af[fi][1], bfr[fj][1], acc[4 + fi][2 + fj], 0, 0, 0);
      }
    __builtin_amdgcn_s_setprio(0);
    __builtin_amdgcn_s_barrier();

    // ---- phase 4: (A-hi, B-lo) ----
#pragma unroll
    for (int fj = 0; fj < 2; ++fj) {
      const int ro = (fj * 64 + wn * 16 + l16) * 64;
      bfr[fj][0] = *(const bf16x8*)(Bb + ro + uo0);
      bfr[fj][1] = *(const bf16x8*)(Bb + ro + uo1);
    }
    STG(10 + 4 * t);                              // (t+2) B0
    __builtin_amdgcn_s_barrier();
    asm volatile("s_waitcnt lgkmcnt(0)" ::: "memory");
    __builtin_amdgcn_sched_barrier(0);
    __builtin_amdgcn_s_setprio(1);
#pragma unroll
    for (int fi = 0; fi < 4; ++fi)
#pragma unroll
      for (int fj = 0; fj < 2; ++fj) {
        acc[4 + fi][fj] = MFMA_(af[fi][0], bfr[fj][0], acc[4 + fi][fj], 0, 0, 0);
        acc[4 + fi][fj] = MFMA_(af[fi][1], bfr[fj][1], acc[4 + fi][fj], 0, 0, 0);
      }
    __builtin_amdgcn_s_setprio(0);
    if (t < NK_ - 2)       asm volatile("s_waitcnt vmcnt(6)" ::: "memory");
    else if (t == NK_ - 2) asm volatile("s_waitcnt vmcnt(0)" ::: "memory");
    __builtin_amdgcn_s_barrier();
  }

  // ---- epilogue ----
#pragma unroll
  for (int fjg = 0; fjg < 4; ++fjg) {
    const int col = n0 + fjg * 64 + wn * 16 + l16;
    const float bv = bias[col];
#pragma unroll
    for (int fi = 0; fi < 8; ++fi) {
      const int row0 = m0 + fi * 32 + wm * 16 + lg * 4;
#pragma unroll
      for (int r = 0; r < 4; ++r) {
        const float v = acc[fi][fjg][r] + bv;
        if constexpr (sizeof(OutT) == 2)
          ((unsigned short*)C)[(size_t)(row0 + r) * N + col] = f2bf(v);
        else
          ((float*)C)[(size_t)(row0 + r) * N + col] = v;
      }
    }
  }
}

// ---------------- flash attention (causal, GQA), swapped-QK^T ----------------
// grid (16, NQ, B) heavy-first; 4 waves x 32 q rows; KV tiles 64, dbuf,
// counted vmcnt; defer-max (THR=8); setprio around MFMA clusters.

__launch_bounds__(256, 2)
__global__ void flash_attn_kernel(const unsigned short* __restrict__ Qh,
                                  const unsigned short* __restrict__ Kh,
                                  const unsigned short* __restrict__ Vt,
                                  unsigned short* __restrict__ Y) {
  __shared__ unsigned short Klds[2][64 * 64];
  __shared__ unsigned short Vlds[2][64 * 64];
  __shared__ unsigned short Plds[4][32 * 64];
  const int tid = threadIdx.x;
  const int wave = tid >> 6, lane = tid & 63;
  const int l16 = lane & 15, lg = lane >> 4;
  const int h = blockIdx.y, b = blockIdx.z;
  const int kh = h >> 2;

  const size_t kbase = (size_t)(b * NKV_ + kh) * T_ * HEAD_;
  const size_t vbase = (size_t)(b * NKV_ + kh) * HEAD_ * T_;
  const int srow = tid >> 3;
  const int csrc = (tid & 7) ^ (srow & 7);
  unsigned short* pl = Plds[wave];
  const f32x4 zero4 = {0.f, 0.f, 0.f, 0.f};

#define STAGE(bi, kv0) do {                                                         \
    gload_lds16(Kh + kbase + (size_t)((kv0) + srow) * HEAD_ + csrc * 8,             \
                (char*)Klds[bi] + tid * 16);                                        \
    gload_lds16(Kh + kbase + (size_t)((kv0) + srow + 32) * HEAD_ + csrc * 8,        \
                (char*)Klds[bi] + 4096 + tid * 16);                                 \
    gload_lds16(Vt + vbase + (size_t)srow * T_ + (kv0) + csrc * 8,                  \
                (char*)Vlds[bi] + tid * 16);                                        \
    gload_lds16(Vt + vbase + (size_t)(srow + 32) * T_ + (kv0) + csrc * 8,           \
                (char*)Vlds[bi] + 4096 + tid * 16);                                 \
  } while (0)

  const int qt = 15 - (int)blockIdx.x;   // heavy blocks dispatched first
  const int q0 = qt * QBLK_;
  const int nt = (q0 >> 6) + 2;

  bf16x8 aq[2][2];
#pragma unroll
  for (int qh = 0; qh < 2; ++qh) {
    const unsigned short* qp =
        Qh + ((size_t)(b * NQ_ + h) * T_ + q0 + wave * 32 + qh * 16 + l16) * HEAD_;
    aq[qh][0] = *(const bf16x8*)(qp + lg * 8);
    aq[qh][1] = *(const bf16x8*)(qp + 32 + lg * 8);
  }

  f32x4 oacc[2][4];
#pragma unroll
  for (int qh = 0; qh < 2; ++qh)
#pragma unroll
    for (int df = 0; df < 4; ++df) oacc[qh][df] = zero4;
  float mreg[2] = {-1e30f, -1e30f};
  float lp[2] = {0.f, 0.f};

  STAGE(0, 0);

  for (int t = 0; t < nt; ++t) {
    if (t + 1 < nt) {
      STAGE((t + 1) & 1, (t + 1) * 64);
      asm volatile("s_waitcnt vmcnt(4)" ::: "memory");
    } else {
      asm volatile("s_waitcnt vmcnt(0)" ::: "memory");
    }
    __builtin_amdgcn_s_barrier();
    __builtin_amdgcn_sched_barrier(0);

    const unsigned short* Kb = Klds[t & 1];
    const unsigned short* Vb = Vlds[t & 1];
    const int kv0 = t * 64;

    // ---- S^T = K Q^T ----
    float p[2][4][4];
    __builtin_amdgcn_s_setprio(1);
#pragma unroll
    for (int cf = 0; cf < 4; ++cf) {
      const int krow = cf * 16 + l16;
      const bf16x8 k0 = *(const bf16x8*)(Kb + krow * 64 + ((lg ^ (krow & 7)) << 3));
      const bf16x8 k1 = *(const bf16x8*)(Kb + krow * 64 + (((4 + lg) ^ (krow & 7)) << 3));
#pragma unroll
      for (int qh = 0; qh < 2; ++qh) {
        f32x4 z = zero4;
        z = MFMA_(k0, aq[qh][0], z, 0, 0, 0);
        z = MFMA_(k1, aq[qh][1], z, 0, 0, 0);
#pragma unroll
        for (int r = 0; r < 4; ++r) p[qh][cf][r] = z[r];
      }
    }
    __builtin_amdgcn_s_setprio(0);

    if (t >= nt - 2) {
#pragma unroll
      for (int qh = 0; qh < 2; ++qh) {
        const int qg = q0 + wave * 32 + qh * 16 + l16;
#pragma unroll
        for (int cf = 0; cf < 4; ++cf)
#pragma unroll
          for (int r = 0; r < 4; ++r)
            if (kv0 + cf * 16 + lg * 4 + r > qg) p[qh][cf][r] = -1e30f;
      }
    }

    // ---- online softmax with defer-max ----
    float pm[2];
#pragma unroll
    for (int qh = 0; qh < 2; ++qh) {
      float m = p[qh][0][0];
#pragma unroll
      for (int cf = 0; cf < 4; ++cf)
#pragma unroll
        for (int r = 0; r < 4; ++r) m = fmaxf(m, p[qh][cf][r]);
      m = fmaxf(m, __shfl_xor(m, 16, 64));
      m = fmaxf(m, __shfl_xor(m, 32, 64));
      pm[qh] = m;
    }
    const float dmax = fmaxf(pm[0] - mreg[0], pm[1] - mreg[1]);
    if (!__all(dmax <= 8.f)) {
#pragma unroll
      for (int qh = 0; qh < 2; ++qh) {
        const float mnew = fmaxf(mreg[qh], pm[qh]);
        const float corr = __expf(mreg[qh] - mnew);
        mreg[qh] = mnew;
        lp[qh] *= corr;
#pragma unroll
        for (int df = 0; df < 4; ++df)
#pragma unroll
          for (int r = 0; r < 4; ++r) oacc[qh][df][r] *= corr;
      }
    }
#pragma unroll
    for (int qh = 0; qh < 2; ++qh) {
      float ps = 0.f;
#pragma unroll
      for (int cf = 0; cf < 4; ++cf)
#pragma unroll
        for (int r = 0; r < 4; ++r) {
          const float e = __expf(p[qh][cf][r] - mreg[qh]);
          p[qh][cf][r] = e;
          ps += e;
        }
      lp[qh] += ps;
    }

    // ---- P -> LDS (swizzled b64), read back as B-frags ----
#pragma unroll
    for (int qh = 0; qh < 2; ++qh) {
      const int row = qh * 16 + l16;
#pragma unroll
      for (int cf = 0; cf < 4; ++cf) {
        const unsigned int w0 = pk_bf16(p[qh][cf][0], p[qh][cf][1]);
        const unsigned int w1 = pk_bf16(p[qh][cf][2], p[qh][cf][3]);
        const int u = cf * 2 + (lg >> 1);
        char* ad = (char*)pl + row * 128 + ((u ^ (row & 7)) << 4) + ((lg & 1) << 3);
        *(unsigned long long*)ad =
            (unsigned long long)w0 | ((unsigned long long)w1 << 32);
      }
    }
    bf16x8 pf[2][2];
#pragma unroll
    for (int qh = 0; qh < 2; ++qh) {
      const int row = qh * 16 + l16;
#pragma unroll
      for (int k2 = 0; k2 < 2; ++k2) {
        const int u = k2 * 4 + lg;
        pf[qh][k2] = *(const bf16x8*)((char*)pl + row * 128 + ((u ^ (row & 7)) << 4));
      }
    }

    // ---- O^T += V^T P^T ----
    __builtin_amdgcn_s_setprio(1);
#pragma unroll
    for (int df = 0; df < 4; ++df) {
      const int vrow = df * 16 + l16;
      const bf16x8 v0 = *(const bf16x8*)(Vb + vrow * 64 + ((lg ^ (vrow & 7)) << 3));
      const bf16x8 v1 = *(const bf16x8*)(Vb + vrow * 64 + (((4 + lg) ^ (vrow & 7)) << 3));
#pragma unroll
      for (int qh = 0; qh < 2; ++qh) {
        oacc[qh][df] = MFMA_(v0, pf[qh][0], oacc[qh][df], 0, 0, 0);
        oacc[qh][df] = MFMA_(v1, pf[qh][1], oacc[qh][df], 0, 0, 0);
      }
    }
    __builtin_amdgcn_s_setprio(0);

    asm volatile("s_waitcnt lgkmcnt(0)" ::: "memory");
    __builtin_amdgcn_sched_barrier(0);
    __builtin_amdgcn_s_barrier();
  }

  // ---- epilogue ----
#pragma unroll
  for (int qh = 0; qh < 2; ++qh) {
    float lt = lp[qh];
    lt += __shfl_xor(lt, 16, 64);
    lt += __shfl_xor(lt, 32, 64);
    const float inv = 1.f / lt;
    const int tq = q0 + wave * 32 + qh * 16 + l16;
    unsigned short* yp = Y + ((size_t)(b * T_ + tq)) * EMB_ + h * HEAD_;
#pragma unroll
    for (int df = 0; df < 4; ++df) {
      const unsigned int w0 = pk_bf16(oacc[qh][df][0] * inv, oacc[qh][df][1] * inv);
      const unsigned int w1 = pk_bf16(oacc[qh][df][2] * inv, oacc[qh][df][3] * inv);
      *(unsigned long long*)(yp + df * 16 + lg * 4) =
          (unsigned long long)w0 | ((unsigned long long)w1 << 32);
    }
  }
#undef STAGE
}

// ---------------- launch ----------------

extern "C" void kernel_launch(void* const* d_in, const int* in_sizes, int n_in,
                              void* d_out, int out_size, void* d_ws, size_t ws_size,
                              hipStream_t stream) {
  const float* x  = (const float*)d_in[0];
  const float* Wq = (const float*)d_in[1];
  const float* bq = (const float*)d_in[2];
  const float* Wk = (const float*)d_in[3];
  const float* bk = (const float*)d_in[4];
  const float* Wv = (const float*)d_in[5];
  const float* bv = (const float*)d_in[6];
  const float* Wo = (const float*)d_in[7];
  const float* bo = (const float*)d_in[8];
  float* out = (float*)d_out;

  char* ws = (char*)d_ws;
  size_t off = 0;
  auto alloc = [&](size_t bytes) {
    void* p = ws + off;
    off += (bytes + 255) & ~(size_t)255;
    return p;
  };
  unsigned short* xb     = (unsigned short*)alloc((size_t)M_ * EMB_ * 2);
  unsigned short* WqkvT  = (unsigned short*)alloc((size_t)NTOT_ * EMB_ * 2);
  unsigned short* WoT    = (unsigned short*)alloc((size_t)EMB_ * EMB_ * 2);
  float*          bcat   = (float*)alloc((size_t)NTOT_ * 4);
  unsigned short* QKVlin = (unsigned short*)alloc((size_t)M_ * NTOT_ * 2);
  unsigned short* Qh     = (unsigned short*)alloc((size_t)B_ * NQ_ * T_ * HEAD_ * 2);
  unsigned short* Kh     = (unsigned short*)alloc((size_t)B_ * NKV_ * T_ * HEAD_ * 2);
  unsigned short* Vt     = (unsigned short*)alloc((size_t)B_ * NKV_ * HEAD_ * T_ * 2);
  unsigned short* Yb     = (unsigned short*)alloc((size_t)M_ * EMB_ * 2);

  cvt_bf16_kernel<<<(M_ * EMB_ / 4 + 255) / 256, 256, 0, stream>>>(x, xb, M_ * EMB_ / 4);

  dim3 tb(32, 8);
  transpose_cvt_kernel<<<dim3(EMB_ / 32, EMB_ / 32), tb, 0, stream>>>(Wq, WqkvT, EMB_, EMB_);
  transpose_cvt_kernel<<<dim3(512 / 32, EMB_ / 32), tb, 0, stream>>>(Wk, WqkvT + (size_t)2048 * 2048, EMB_, 512);
  transpose_cvt_kernel<<<dim3(512 / 32, EMB_ / 32), tb, 0, stream>>>(Wv, WqkvT + (size_t)2560 * 2048, EMB_, 512);
  transpose_cvt_kernel<<<dim3(EMB_ / 32, EMB_ / 32), tb, 0, stream>>>(Wo, WoT, EMB_, EMB_);
  concat_bias_kernel<<<(NTOT_ + 255) / 256, 256, 0, stream>>>(bq, bk, bv, bcat);

  // QKV projection: 192 blocks (16 M-tiles x 12 N-tiles), bf16 out
  gemm256_8ph<unsigned short><<<192, 512, 0, stream>>>(xb, WqkvT, bcat, QKVlin, NTOT_);

  rope_q_kernel<<<(B_ * T_ * NQ_ * 32) / 256, 256, 0, stream>>>(QKVlin, Qh);
  rope_k_kernel<<<(B_ * T_ * NKV_ * 32) / 256, 256, 0, stream>>>(QKVlin, Kh);
  vt_kernel<<<(B_ * NKV_ * HEAD_ * T_) / 256, 256, 0, stream>>>(QKVlin, Vt);

  flash_attn_kernel<<<dim3(16, NQ_, B_), 256, 0, stream>>>(Qh, Kh, Vt, Yb);

  // output projection: 128 blocks (16 x 8), fp32 out
  gemm256_8ph<float><<<128, 512, 0, stream>>>(Yb, WoT, bo, out, EMB_);

  (void)in_sizes; (void)n_in; (void)out_size; (void)ws_size;
}

// Round 5
// 248.841 us; speedup vs baseline: 1.1157x; 1.1157x over previous
//
#include <hip/hip_runtime.h>
#include <hip/hip_bf16.h>
#include <cstdint>
#include <cstddef>

typedef __attribute__((ext_vector_type(4))) float f32x4;
typedef __attribute__((ext_vector_type(8))) short bf16x8;

#define B_    2
#define T_    2048
#define EMB_  2048
#define NQ_   32
#define NKV_  8
#define HEAD_ 64
#define NTOT_ 3072
#define M_    (B_ * T_)     // 4096
#define QBLK_ 128
#define NK_   32            // K=2048 / BK=64 for the 8-phase GEMM

#define MFMA_ __builtin_amdgcn_mfma_f32_16x16x32_bf16

__device__ __forceinline__ unsigned short f2bf(float f) {
  union { float f; unsigned int u; } v; v.f = f;
  unsigned int r = v.u + 0x7fffu + ((v.u >> 16) & 1u);
  return (unsigned short)(r >> 16);
}

__device__ __forceinline__ float bf2f(unsigned short u) {
  union { unsigned int u; float f; } v; v.u = (unsigned int)u << 16; return v.f;
}

__device__ __forceinline__ unsigned int pk_bf16(float lo, float hi) {
  __hip_bfloat162 h = __float22bfloat162_rn(make_float2(lo, hi));
  union { __hip_bfloat162 h; unsigned int u; } c; c.h = h;
  return c.u;
}

__device__ __forceinline__ void gload_lds16(const void* g, void* l) {
  __builtin_amdgcn_global_load_lds(
      (const __attribute__((address_space(1))) void*)g,
      (__attribute__((address_space(3))) void*)l, 16, 0, 0);
}

// ---------------- elementwise converts / relayouts ----------------

__global__ void cvt_bf16_kernel(const float* __restrict__ src,
                                unsigned short* __restrict__ dst, int n4) {
  int i = blockIdx.x * blockDim.x + threadIdx.x;
  if (i >= n4) return;
  float4 v = ((const float4*)src)[i];
  unsigned long long pk =
      (unsigned long long)f2bf(v.x) |
      ((unsigned long long)f2bf(v.y) << 16) |
      ((unsigned long long)f2bf(v.z) << 32) |
      ((unsigned long long)f2bf(v.w) << 48);
  *(unsigned long long*)(dst + (size_t)i * 4) = pk;
}

// src fp32 [R][C]  ->  dst bf16 [C][R]
__global__ void transpose_cvt_kernel(const float* __restrict__ src,
                                     unsigned short* __restrict__ dst,
                                     int R, int C) {
  __shared__ float tile[32][33];
  int c0 = blockIdx.x * 32, r0 = blockIdx.y * 32;
  int tx = threadIdx.x, ty = threadIdx.y;
#pragma unroll
  for (int k = 0; k < 4; ++k)
    tile[ty + 8 * k][tx] = src[(size_t)(r0 + ty + 8 * k) * C + c0 + tx];
  __syncthreads();
#pragma unroll
  for (int k = 0; k < 4; ++k)
    dst[(size_t)(c0 + ty + 8 * k) * R + r0 + tx] = f2bf(tile[tx][ty + 8 * k]);
}

__global__ void concat_bias_kernel(const float* __restrict__ bq,
                                   const float* __restrict__ bk,
                                   const float* __restrict__ bv,
                                   float* __restrict__ dst) {
  int i = blockIdx.x * 256 + threadIdx.x;
  if (i < 2048) dst[i] = bq[i];
  else if (i < 2560) dst[i] = bk[i - 2048];
  else if (i < 3072) dst[i] = bv[i - 2560];
}

#define L2_10000 13.2877123795494f
#define QSCALE_  0.18033688011112043f   // 0.125 * log2(e) -> softmax in exp2

// QKVlin bf16 [4096][3072] -> Qh bf16 [b][h][t][64] with RoPE; QSCALE folded.
__global__ void rope_q_kernel(const unsigned short* __restrict__ qkv,
                              unsigned short* __restrict__ Qh) {
  int idx = blockIdx.x * 256 + threadIdx.x;   // B*T*NQ*32
  int i  = idx & 31;
  int h  = (idx >> 5) & 31;
  int bt = idx >> 10;
  int t  = bt & (T_ - 1);
  int b  = bt >> 11;
  float invf = exp2f(-(float)i * (L2_10000 / 32.f));
  float ang = (float)t * invf;
  float s, c; sincosf(ang, &s, &c);
  const unsigned short* row = qkv + (size_t)bt * NTOT_ + h * 64;
  float x1 = bf2f(row[i]), x2 = bf2f(row[i + 32]);
  unsigned short* q = Qh + ((size_t)(b * NQ_ + h) * T_ + t) * HEAD_;
  q[i]      = f2bf((x1 * c - x2 * s) * QSCALE_);
  q[i + 32] = f2bf((x2 * c + x1 * s) * QSCALE_);
}

__global__ void rope_k_kernel(const unsigned short* __restrict__ qkv,
                              unsigned short* __restrict__ Kh) {
  int idx = blockIdx.x * 256 + threadIdx.x;   // B*T*NKV*32
  int i  = idx & 31;
  int kh = (idx >> 5) & 7;
  int bt = idx >> 8;
  int t  = bt & (T_ - 1);
  int b  = bt >> 11;
  float invf = exp2f(-(float)i * (L2_10000 / 32.f));
  float ang = (float)t * invf;
  float s, c; sincosf(ang, &s, &c);
  const unsigned short* row = qkv + (size_t)bt * NTOT_ + 2048 + kh * 64;
  float x1 = bf2f(row[i]), x2 = bf2f(row[i + 32]);
  unsigned short* kp = Kh + ((size_t)(b * NKV_ + kh) * T_ + t) * HEAD_;
  kp[i]      = f2bf(x1 * c - x2 * s);
  kp[i + 32] = f2bf(x2 * c + x1 * s);
}

// V (bf16 in QKVlin) -> Vt bf16 [b][kh][d][t]
__global__ void vt_kernel(const unsigned short* __restrict__ qkv,
                          unsigned short* __restrict__ Vt) {
  int idx = blockIdx.x * 256 + threadIdx.x;   // B*NKV*HEAD*T
  int t  = idx & (T_ - 1);
  int d  = (idx >> 11) & 63;
  int kh = (idx >> 17) & 7;
  int b  = idx >> 20;
  Vt[((size_t)((b * NKV_ + kh) * 64 + d)) * T_ + t] =
      qkv[(size_t)(b * T_ + t) * NTOT_ + 2560 + kh * 64 + d];
}

// ---------------- 128x128 m97-style GEMM (out projection) ----------------

__launch_bounds__(256, 2)
__global__ void gemm_bt_bias(const unsigned short* __restrict__ A,
                             const unsigned short* __restrict__ BT,
                             const float* __restrict__ bias,
                             float* __restrict__ C, int N, int K) {
  __shared__ unsigned short Alds[128 * 32];
  __shared__ unsigned short Blds[128 * 32];
  const int tid = threadIdx.x;
  const int wave = tid >> 6, lane = tid & 63;
  const int l16 = lane & 15, lg = lane >> 4;
  const int m0 = blockIdx.x * 128;
  const int n0 = blockIdx.y * 128;
  const int wr = wave >> 1, wc = wave & 1;

  f32x4 zero4 = {0.f, 0.f, 0.f, 0.f};
  f32x4 acc[4][4];
#pragma unroll
  for (int i = 0; i < 4; ++i)
#pragma unroll
    for (int j = 0; j < 4; ++j) acc[i][j] = zero4;

  const int arow = tid >> 2;
  const int kcb  = (tid & 3) * 8;
  const int nk = K >> 5;
  for (int kt = 0; kt < nk; ++kt) {
    const int k0 = kt << 5;
    gload_lds16(A + (size_t)(m0 + arow) * K + k0 + kcb,       (char*)Alds + tid * 16);
    gload_lds16(A + (size_t)(m0 + 64 + arow) * K + k0 + kcb,  (char*)Alds + 4096 + tid * 16);
    gload_lds16(BT + (size_t)(n0 + arow) * K + k0 + kcb,      (char*)Blds + tid * 16);
    gload_lds16(BT + (size_t)(n0 + 64 + arow) * K + k0 + kcb, (char*)Blds + 4096 + tid * 16);
    __syncthreads();
    bf16x8 af[4], bfr[4];
#pragma unroll
    for (int i = 0; i < 4; ++i)
      af[i] = *(const bf16x8*)(Alds + (wr * 64 + i * 16 + l16) * 32 + lg * 8);
#pragma unroll
    for (int j = 0; j < 4; ++j)
      bfr[j] = *(const bf16x8*)(Blds + (wc * 64 + j * 16 + l16) * 32 + lg * 8);
#pragma unroll
    for (int i = 0; i < 4; ++i)
#pragma unroll
      for (int j = 0; j < 4; ++j)
        acc[i][j] = MFMA_(af[i], bfr[j], acc[i][j], 0, 0, 0);
    __syncthreads();
  }
#pragma unroll
  for (int j = 0; j < 4; ++j) {
    const int col = n0 + wc * 64 + j * 16 + l16;
    const float bv = bias[col];
#pragma unroll
    for (int i = 0; i < 4; ++i) {
      const int rowb = m0 + wr * 64 + i * 16 + lg * 4;
#pragma unroll
      for (int r = 0; r < 4; ++r)
        C[(size_t)(rowb + r) * N + col] = acc[i][j][r] + bv;
    }
  }
}

// ---------------- 256x256 8-phase GEMM (QKV projection), K=2048 ----------------

__launch_bounds__(512, 2)
__global__ void gemm256_8ph(const unsigned short* __restrict__ A,
                            const unsigned short* __restrict__ BT,
                            const float* __restrict__ bias,
                            unsigned short* __restrict__ C, int N) {
  __shared__ unsigned short sh[2][2][16384];   // 128 KiB
  const int tid = threadIdx.x;
  const int lane = tid & 63, l16 = lane & 15, lg = lane >> 4;
  const int wave = tid >> 6, wm = wave >> 2, wn = wave & 3;
  const int nwg = gridDim.x;
  const int bid = blockIdx.x;
  const int sw = (bid & 7) * (nwg >> 3) + (bid >> 3);   // XCD swizzle (nwg%8==0)
  const int mt = sw & 15, nt = sw >> 4;
  const int m0 = mt * 256, n0 = nt * 256;
  const int usrc = (tid & 7) ^ ((tid >> 3) & 7);
  const int swz = l16 & 7;
  const int uo0 = (lg ^ swz) << 3;
  const int uo1 = ((4 + lg) ^ swz) << 3;

  f32x4 acc[8][4];
#pragma unroll
  for (int i = 0; i < 8; ++i)
#pragma unroll
    for (int j = 0; j < 4; ++j) acc[i][j] = (f32x4){0.f, 0.f, 0.f, 0.f};

  auto STG = [&](int ht) {
    if (ht >= 4 * NK_) return;
    const int kt = ht >> 2, reg = ht & 3, bufi = kt & 1;
    const unsigned short* src = (reg < 2) ? A : BT;
    const int grow = ((reg < 2) ? m0 : n0) + ((reg & 1) ? 128 : 0);
    unsigned short* dst = &sh[bufi][reg >> 1][(reg & 1) ? 8192 : 0];
    const size_t base = (size_t)(grow + (tid >> 3)) * 2048 + kt * 64 + usrc * 8;
    gload_lds16(src + base, (char*)dst + tid * 16);
    gload_lds16(src + base + (size_t)64 * 2048, (char*)dst + tid * 16 + 8192);
  };

#pragma unroll
  for (int ht = 0; ht < 7; ++ht) STG(ht);
  asm volatile("s_waitcnt vmcnt(6)" ::: "memory");
  __builtin_amdgcn_s_barrier();

  bf16x8 af[4][2], bfr[2][2];
#pragma unroll 2
  for (int t = 0; t < NK_; ++t) {
    const unsigned short* Ab = &sh[t & 1][0][0];
    const unsigned short* Bb = &sh[t & 1][1][0];

#pragma unroll
    for (int fi = 0; fi < 4; ++fi) {
      const int ro = (fi * 32 + wm * 16 + l16) * 64;
      af[fi][0] = *(const bf16x8*)(Ab + ro + uo0);
      af[fi][1] = *(const bf16x8*)(Ab + ro + uo1);
    }
#pragma unroll
    for (int fj = 0; fj < 2; ++fj) {
      const int ro = (fj * 64 + wn * 16 + l16) * 64;
      bfr[fj][0] = *(const bf16x8*)(Bb + ro + uo0);
      bfr[fj][1] = *(const bf16x8*)(Bb + ro + uo1);
    }
    STG(7 + 4 * t);
    __builtin_amdgcn_s_barrier();
    asm volatile("s_waitcnt lgkmcnt(0)" ::: "memory");
    __builtin_amdgcn_sched_barrier(0);
    __builtin_amdgcn_s_setprio(1);
#pragma unroll
    for (int fi = 0; fi < 4; ++fi)
#pragma unroll
      for (int fj = 0; fj < 2; ++fj) {
        acc[fi][fj] = MFMA_(af[fi][0], bfr[fj][0], acc[fi][fj], 0, 0, 0);
        acc[fi][fj] = MFMA_(af[fi][1], bfr[fj][1], acc[fi][fj], 0, 0, 0);
      }
    __builtin_amdgcn_s_setprio(0);
    __builtin_amdgcn_s_barrier();

#pragma unroll
    for (int fj = 0; fj < 2; ++fj) {
      const int ro = ((2 + fj) * 64 + wn * 16 + l16) * 64;
      bfr[fj][0] = *(const bf16x8*)(Bb + ro + uo0);
      bfr[fj][1] = *(const bf16x8*)(Bb + ro + uo1);
    }
    STG(8 + 4 * t);
    __builtin_amdgcn_s_barrier();
    asm volatile("s_waitcnt lgkmcnt(0)" ::: "memory");
    __builtin_amdgcn_sched_barrier(0);
    __builtin_amdgcn_s_setprio(1);
#pragma unroll
    for (int fi = 0; fi < 4; ++fi)
#pragma unroll
      for (int fj = 0; fj < 2; ++fj) {
        acc[fi][2 + fj] = MFMA_(af[fi][0], bfr[fj][0], acc[fi][2 + fj], 0, 0, 0);
        acc[fi][2 + fj] = MFMA_(af[fi][1], bfr[fj][1], acc[fi][2 + fj], 0, 0, 0);
      }
    __builtin_amdgcn_s_setprio(0);
    __builtin_amdgcn_s_barrier();

#pragma unroll
    for (int fi = 0; fi < 4; ++fi) {
      const int ro = ((4 + fi) * 32 + wm * 16 + l16) * 64;
      af[fi][0] = *(const bf16x8*)(Ab + ro + uo0);
      af[fi][1] = *(const bf16x8*)(Ab + ro + uo1);
    }
    STG(9 + 4 * t);
    __builtin_amdgcn_s_barrier();
    asm volatile("s_waitcnt lgkmcnt(0)" ::: "memory");
    __builtin_amdgcn_sched_barrier(0);
    __builtin_amdgcn_s_setprio(1);
#pragma unroll
    for (int fi = 0; fi < 4; ++fi)
#pragma unroll
      for (int fj = 0; fj < 2; ++fj) {
        acc[4 + fi][2 + fj] = MFMA_(af[fi][0], bfr[fj][0], acc[4 + fi][2 + fj], 0, 0, 0);
        acc[4 + fi][2 + fj] = MFMA_(af[fi][1], bfr[fj][1], acc[4 + fi][2 + fj], 0, 0, 0);
      }
    __builtin_amdgcn_s_setprio(0);
    __builtin_amdgcn_s_barrier();

#pragma unroll
    for (int fj = 0; fj < 2; ++fj) {
      const int ro = (fj * 64 + wn * 16 + l16) * 64;
      bfr[fj][0] = *(const bf16x8*)(Bb + ro + uo0);
      bfr[fj][1] = *(const bf16x8*)(Bb + ro + uo1);
    }
    STG(10 + 4 * t);
    __builtin_amdgcn_s_barrier();
    asm volatile("s_waitcnt lgkmcnt(0)" ::: "memory");
    __builtin_amdgcn_sched_barrier(0);
    __builtin_amdgcn_s_setprio(1);
#pragma unroll
    for (int fi = 0; fi < 4; ++fi)
#pragma unroll
      for (int fj = 0; fj < 2; ++fj) {
        acc[4 + fi][fj] = MFMA_(af[fi][0], bfr[fj][0], acc[4 + fi][fj], 0, 0, 0);
        acc[4 + fi][fj] = MFMA_(af[fi][1], bfr[fj][1], acc[4 + fi][fj], 0, 0, 0);
      }
    __builtin_amdgcn_s_setprio(0);
    if (t < NK_ - 2)       asm volatile("s_waitcnt vmcnt(6)" ::: "memory");
    else if (t == NK_ - 2) asm volatile("s_waitcnt vmcnt(0)" ::: "memory");
    __builtin_amdgcn_s_barrier();
  }

#pragma unroll
  for (int fjg = 0; fjg < 4; ++fjg) {
    const int col = n0 + fjg * 64 + wn * 16 + l16;
    const float bv = bias[col];
#pragma unroll
    for (int fi = 0; fi < 8; ++fi) {
      const int row0 = m0 + fi * 32 + wm * 16 + lg * 4;
#pragma unroll
      for (int r = 0; r < 4; ++r)
        C[(size_t)(row0 + r) * N + col] = f2bf(acc[fi][fjg][r] + bv);
    }
  }
}

// ---------------- flash attention (round-3 structure, exp2 softmax) ----------------
// grid (8, NQ, B); block handles q-tiles x and 15-x (34 KV-tiles, balanced).
// 4 waves x 32 q rows. S^T via mfma(K,Q); PV via mfma(V^T,P); dbuf + counted vmcnt.

__launch_bounds__(256, 2)
__global__ void flash_attn_kernel(const unsigned short* __restrict__ Qh,
                                  const unsigned short* __restrict__ Kh,
                                  const unsigned short* __restrict__ Vt,
                                  unsigned short* __restrict__ Y) {
  __shared__ unsigned short Klds[2][64 * 64];
  __shared__ unsigned short Vlds[2][64 * 64];
  __shared__ unsigned short Plds[4][32 * 64];
  const int tid = threadIdx.x;
  const int wave = tid >> 6, lane = tid & 63;
  const int l16 = lane & 15, lg = lane >> 4;
  const int h = blockIdx.y, b = blockIdx.z;
  const int kh = h >> 2;

  const size_t kbase = (size_t)(b * NKV_ + kh) * T_ * HEAD_;
  const size_t vbase = (size_t)(b * NKV_ + kh) * HEAD_ * T_;
  const int srow = tid >> 3;
  const int csrc = (tid & 7) ^ (srow & 7);
  unsigned short* pl = Plds[wave];
  const f32x4 zero4 = {0.f, 0.f, 0.f, 0.f};

#define STAGE(bi, kv0) do {                                                         \
    gload_lds16(Kh + kbase + (size_t)((kv0) + srow) * HEAD_ + csrc * 8,             \
                (char*)Klds[bi] + tid * 16);                                        \
    gload_lds16(Kh + kbase + (size_t)((kv0) + srow + 32) * HEAD_ + csrc * 8,        \
                (char*)Klds[bi] + 4096 + tid * 16);                                 \
    gload_lds16(Vt + vbase + (size_t)srow * T_ + (kv0) + csrc * 8,                  \
                (char*)Vlds[bi] + tid * 16);                                        \
    gload_lds16(Vt + vbase + (size_t)(srow + 32) * T_ + (kv0) + csrc * 8,           \
                (char*)Vlds[bi] + 4096 + tid * 16);                                 \
  } while (0)

  for (int seg = 0; seg < 2; ++seg) {
    const int qt = seg ? (15 - (int)blockIdx.x) : (int)blockIdx.x;
    const int q0 = qt * QBLK_;
    const int nt = (q0 >> 6) + 2;

    bf16x8 aq[2][2];
#pragma unroll
    for (int qh = 0; qh < 2; ++qh) {
      const unsigned short* qp =
          Qh + ((size_t)(b * NQ_ + h) * T_ + q0 + wave * 32 + qh * 16 + l16) * HEAD_;
      aq[qh][0] = *(const bf16x8*)(qp + lg * 8);
      aq[qh][1] = *(const bf16x8*)(qp + 32 + lg * 8);
    }

    f32x4 oacc[2][4];
#pragma unroll
    for (int qh = 0; qh < 2; ++qh)
#pragma unroll
      for (int df = 0; df < 4; ++df) oacc[qh][df] = zero4;
    float mreg[2] = {-1e30f, -1e30f};
    float lp[2] = {0.f, 0.f};

    STAGE(0, 0);

    for (int t = 0; t < nt; ++t) {
      if (t + 1 < nt) {
        STAGE((t + 1) & 1, (t + 1) * 64);
        asm volatile("s_waitcnt vmcnt(4)" ::: "memory");
      } else {
        asm volatile("s_waitcnt vmcnt(0)" ::: "memory");
      }
      __builtin_amdgcn_s_barrier();
      __builtin_amdgcn_sched_barrier(0);

      const unsigned short* Kb = Klds[t & 1];
      const unsigned short* Vb = Vlds[t & 1];
      const int kv0 = t * 64;

      // ---- S^T = K Q^T (values already scaled by 0.125*log2e) ----
      float p[2][4][4];
#pragma unroll
      for (int cf = 0; cf < 4; ++cf) {
        const int krow = cf * 16 + l16;
        const bf16x8 k0 = *(const bf16x8*)(Kb + krow * 64 + ((lg ^ (krow & 7)) << 3));
        const bf16x8 k1 = *(const bf16x8*)(Kb + krow * 64 + (((4 + lg) ^ (krow & 7)) << 3));
#pragma unroll
        for (int qh = 0; qh < 2; ++qh) {
          f32x4 z = zero4;
          z = MFMA_(k0, aq[qh][0], z, 0, 0, 0);
          z = MFMA_(k1, aq[qh][1], z, 0, 0, 0);
#pragma unroll
          for (int r = 0; r < 4; ++r) p[qh][cf][r] = z[r];
        }
      }

      if (t >= nt - 2) {
#pragma unroll
        for (int qh = 0; qh < 2; ++qh) {
          const int qg = q0 + wave * 32 + qh * 16 + l16;
#pragma unroll
          for (int cf = 0; cf < 4; ++cf)
#pragma unroll
            for (int r = 0; r < 4; ++r)
              if (kv0 + cf * 16 + lg * 4 + r > qg) p[qh][cf][r] = -1e30f;
        }
      }

      // ---- online softmax in exp2 domain ----
#pragma unroll
      for (int qh = 0; qh < 2; ++qh) {
        float pm = p[qh][0][0];
#pragma unroll
        for (int cf = 0; cf < 4; ++cf)
#pragma unroll
          for (int r = 0; r < 4; ++r) pm = fmaxf(pm, p[qh][cf][r]);
        pm = fmaxf(pm, __shfl_xor(pm, 16, 64));
        pm = fmaxf(pm, __shfl_xor(pm, 32, 64));
        const float mnew = fmaxf(mreg[qh], pm);
        const float corr = exp2f(mreg[qh] - mnew);
        mreg[qh] = mnew;
        lp[qh] *= corr;
#pragma unroll
        for (int df = 0; df < 4; ++df)
#pragma unroll
          for (int r = 0; r < 4; ++r) oacc[qh][df][r] *= corr;
        float ps = 0.f;
#pragma unroll
        for (int cf = 0; cf < 4; ++cf)
#pragma unroll
          for (int r = 0; r < 4; ++r) {
            const float e = exp2f(p[qh][cf][r] - mnew);
            p[qh][cf][r] = e;
            ps += e;
          }
        lp[qh] += ps;
      }

      // ---- P -> LDS (swizzled b64), read back as B-frags ----
#pragma unroll
      for (int qh = 0; qh < 2; ++qh) {
        const int row = qh * 16 + l16;
#pragma unroll
        for (int cf = 0; cf < 4; ++cf) {
          const unsigned int w0 = pk_bf16(p[qh][cf][0], p[qh][cf][1]);
          const unsigned int w1 = pk_bf16(p[qh][cf][2], p[qh][cf][3]);
          const int u = cf * 2 + (lg >> 1);
          char* ad = (char*)pl + row * 128 + ((u ^ (row & 7)) << 4) + ((lg & 1) << 3);
          *(unsigned long long*)ad =
              (unsigned long long)w0 | ((unsigned long long)w1 << 32);
        }
      }
      bf16x8 pf[2][2];
#pragma unroll
      for (int qh = 0; qh < 2; ++qh) {
        const int row = qh * 16 + l16;
#pragma unroll
        for (int k2 = 0; k2 < 2; ++k2) {
          const int u = k2 * 4 + lg;
          pf[qh][k2] = *(const bf16x8*)((char*)pl + row * 128 + ((u ^ (row & 7)) << 4));
        }
      }

      // ---- O^T += V^T P^T ----
#pragma unroll
      for (int df = 0; df < 4; ++df) {
        const int vrow = df * 16 + l16;
        const bf16x8 v0 = *(const bf16x8*)(Vb + vrow * 64 + ((lg ^ (vrow & 7)) << 3));
        const bf16x8 v1 = *(const bf16x8*)(Vb + vrow * 64 + (((4 + lg) ^ (vrow & 7)) << 3));
#pragma unroll
        for (int qh = 0; qh < 2; ++qh) {
          oacc[qh][df] = MFMA_(v0, pf[qh][0], oacc[qh][df], 0, 0, 0);
          oacc[qh][df] = MFMA_(v1, pf[qh][1], oacc[qh][df], 0, 0, 0);
        }
      }

      asm volatile("s_waitcnt lgkmcnt(0)" ::: "memory");
      __builtin_amdgcn_sched_barrier(0);
      __builtin_amdgcn_s_barrier();
    }

    // ---- epilogue ----
#pragma unroll
    for (int qh = 0; qh < 2; ++qh) {
      float lt = lp[qh];
      lt += __shfl_xor(lt, 16, 64);
      lt += __shfl_xor(lt, 32, 64);
      const float inv = 1.f / lt;
      const int tq = q0 + wave * 32 + qh * 16 + l16;
      unsigned short* yp = Y + ((size_t)(b * T_ + tq)) * EMB_ + h * HEAD_;
#pragma unroll
      for (int df = 0; df < 4; ++df) {
        const unsigned int w0 = pk_bf16(oacc[qh][df][0] * inv, oacc[qh][df][1] * inv);
        const unsigned int w1 = pk_bf16(oacc[qh][df][2] * inv, oacc[qh][df][3] * inv);
        *(unsigned long long*)(yp + df * 16 + lg * 4) =
            (unsigned long long)w0 | ((unsigned long long)w1 << 32);
      }
    }
  }
#undef STAGE
}

// ---------------- launch ----------------

extern "C" void kernel_launch(void* const* d_in, const int* in_sizes, int n_in,
                              void* d_out, int out_size, void* d_ws, size_t ws_size,
                              hipStream_t stream) {
  const float* x  = (const float*)d_in[0];
  const float* Wq = (const float*)d_in[1];
  const float* bq = (const float*)d_in[2];
  const float* Wk = (const float*)d_in[3];
  const float* bk = (const float*)d_in[4];
  const float* Wv = (const float*)d_in[5];
  const float* bv = (const float*)d_in[6];
  const float* Wo = (const float*)d_in[7];
  const float* bo = (const float*)d_in[8];
  float* out = (float*)d_out;

  char* ws = (char*)d_ws;
  size_t off = 0;
  auto alloc = [&](size_t bytes) {
    void* p = ws + off;
    off += (bytes + 255) & ~(size_t)255;
    return p;
  };
  unsigned short* xb     = (unsigned short*)alloc((size_t)M_ * EMB_ * 2);
  unsigned short* WqkvT  = (unsigned short*)alloc((size_t)NTOT_ * EMB_ * 2);
  unsigned short* WoT    = (unsigned short*)alloc((size_t)EMB_ * EMB_ * 2);
  float*          bcat   = (float*)alloc((size_t)NTOT_ * 4);
  unsigned short* QKVlin = (unsigned short*)alloc((size_t)M_ * NTOT_ * 2);
  unsigned short* Qh     = (unsigned short*)alloc((size_t)B_ * NQ_ * T_ * HEAD_ * 2);
  unsigned short* Kh     = (unsigned short*)alloc((size_t)B_ * NKV_ * T_ * HEAD_ * 2);
  unsigned short* Vt     = (unsigned short*)alloc((size_t)B_ * NKV_ * HEAD_ * T_ * 2);
  unsigned short* Yb     = (unsigned short*)alloc((size_t)M_ * EMB_ * 2);

  cvt_bf16_kernel<<<(M_ * EMB_ / 4 + 255) / 256, 256, 0, stream>>>(x, xb, M_ * EMB_ / 4);

  dim3 tb(32, 8);
  transpose_cvt_kernel<<<dim3(EMB_ / 32, EMB_ / 32), tb, 0, stream>>>(Wq, WqkvT, EMB_, EMB_);
  transpose_cvt_kernel<<<dim3(512 / 32, EMB_ / 32), tb, 0, stream>>>(Wk, WqkvT + (size_t)2048 * 2048, EMB_, 512);
  transpose_cvt_kernel<<<dim3(512 / 32, EMB_ / 32), tb, 0, stream>>>(Wv, WqkvT + (size_t)2560 * 2048, EMB_, 512);
  transpose_cvt_kernel<<<dim3(EMB_ / 32, EMB_ / 32), tb, 0, stream>>>(Wo, WoT, EMB_, EMB_);
  concat_bias_kernel<<<(NTOT_ + 255) / 256, 256, 0, stream>>>(bq, bk, bv, bcat);

  // QKV projection: 8-phase 256^2, 192 blocks, bf16 out
  gemm256_8ph<<<192, 512, 0, stream>>>(xb, WqkvT, bcat, QKVlin, NTOT_);

  rope_q_kernel<<<(B_ * T_ * NQ_ * 32) / 256, 256, 0, stream>>>(QKVlin, Qh);
  rope_k_kernel<<<(B_ * T_ * NKV_ * 32) / 256, 256, 0, stream>>>(QKVlin, Kh);
  vt_kernel<<<(B_ * NKV_ * HEAD_ * T_) / 256, 256, 0, stream>>>(QKVlin, Vt);

  flash_attn_kernel<<<dim3(8, NQ_, B_), 256, 0, stream>>>(Qh, Kh, Vt, Yb);

  // output projection: 128^2 m97-style, 512 blocks, fp32 out
  gemm_bt_bias<<<dim3(M_ / 128, EMB_ / 128), 256, 0, stream>>>(Yb, WoT, bo, out, EMB_, EMB_);

  (void)in_sizes; (void)n_in; (void)out_size; (void)ws_size;
}

// Round 6
// 231.460 us; speedup vs baseline: 1.1995x; 1.0751x over previous
//
#include <hip/hip_runtime.h>
#include <hip/hip_bf16.h>
#include <cstdint>
#include <cstddef>

typedef __attribute__((ext_vector_type(4))) float f32x4;
typedef __attribute__((ext_vector_type(8))) short bf16x8;

#define B_    2
#define T_    2048
#define EMB_  2048
#define NQ_   32
#define NKV_  8
#define HEAD_ 64
#define NTOT_ 3072
#define M_    (B_ * T_)     // 4096
#define QBLK_ 128

#define MFMA_ __builtin_amdgcn_mfma_f32_16x16x32_bf16

__device__ __forceinline__ unsigned short f2bf(float f) {
  union { float f; unsigned int u; } v; v.f = f;
  unsigned int r = v.u + 0x7fffu + ((v.u >> 16) & 1u);
  return (unsigned short)(r >> 16);
}

__device__ __forceinline__ float bf2f(unsigned short u) {
  union { unsigned int u; float f; } v; v.u = (unsigned int)u << 16; return v.f;
}

__device__ __forceinline__ unsigned int pk_bf16(float lo, float hi) {
  __hip_bfloat162 h = __float22bfloat162_rn(make_float2(lo, hi));
  union { __hip_bfloat162 h; unsigned int u; } c; c.h = h;
  return c.u;
}

// raw v_exp_f32 (2^x) — libm exp2f takes the slow OCML fixup path
__device__ __forceinline__ float ex2(float x) {
  float r;
  asm("v_exp_f32 %0, %1" : "=v"(r) : "v"(x));
  return r;
}

__device__ __forceinline__ void gload_lds16(const void* g, void* l) {
  __builtin_amdgcn_global_load_lds(
      (const __attribute__((address_space(1))) void*)g,
      (__attribute__((address_space(3))) void*)l, 16, 0, 0);
}

// ---------------- elementwise converts / relayouts ----------------

__global__ void cvt_bf16_kernel(const float* __restrict__ src,
                                unsigned short* __restrict__ dst, int n4) {
  int i = blockIdx.x * blockDim.x + threadIdx.x;
  if (i >= n4) return;
  float4 v = ((const float4*)src)[i];
  unsigned long long pk =
      (unsigned long long)f2bf(v.x) |
      ((unsigned long long)f2bf(v.y) << 16) |
      ((unsigned long long)f2bf(v.z) << 32) |
      ((unsigned long long)f2bf(v.w) << 48);
  *(unsigned long long*)(dst + (size_t)i * 4) = pk;
}

// src fp32 [R][C]  ->  dst bf16 [C][R]
__global__ void transpose_cvt_kernel(const float* __restrict__ src,
                                     unsigned short* __restrict__ dst,
                                     int R, int C) {
  __shared__ float tile[32][33];
  int c0 = blockIdx.x * 32, r0 = blockIdx.y * 32;
  int tx = threadIdx.x, ty = threadIdx.y;
#pragma unroll
  for (int k = 0; k < 4; ++k)
    tile[ty + 8 * k][tx] = src[(size_t)(r0 + ty + 8 * k) * C + c0 + tx];
  __syncthreads();
#pragma unroll
  for (int k = 0; k < 4; ++k)
    dst[(size_t)(c0 + ty + 8 * k) * R + r0 + tx] = f2bf(tile[tx][ty + 8 * k]);
}

__global__ void concat_bias_kernel(const float* __restrict__ bq,
                                   const float* __restrict__ bk,
                                   const float* __restrict__ bv,
                                   float* __restrict__ dst) {
  int i = blockIdx.x * 256 + threadIdx.x;
  if (i < 2048) dst[i] = bq[i];
  else if (i < 2560) dst[i] = bk[i - 2048];
  else if (i < 3072) dst[i] = bv[i - 2560];
}

#define L2_10000 13.2877123795494f
#define QSCALE_  0.18033688011112043f   // 0.125 * log2(e) -> softmax in exp2

// QKVlin bf16 [4096][3072] -> Qh bf16 [b][h][t][64] with RoPE; QSCALE folded.
__global__ void rope_q_kernel(const unsigned short* __restrict__ qkv,
                              unsigned short* __restrict__ Qh) {
  int idx = blockIdx.x * 256 + threadIdx.x;   // B*T*NQ*32
  int i  = idx & 31;
  int h  = (idx >> 5) & 31;
  int bt = idx >> 10;
  int t  = bt & (T_ - 1);
  int b  = bt >> 11;
  float invf = exp2f(-(float)i * (L2_10000 / 32.f));
  float ang = (float)t * invf;
  float s, c; sincosf(ang, &s, &c);
  const unsigned short* row = qkv + (size_t)bt * NTOT_ + h * 64;
  float x1 = bf2f(row[i]), x2 = bf2f(row[i + 32]);
  unsigned short* q = Qh + ((size_t)(b * NQ_ + h) * T_ + t) * HEAD_;
  q[i]      = f2bf((x1 * c - x2 * s) * QSCALE_);
  q[i + 32] = f2bf((x2 * c + x1 * s) * QSCALE_);
}

__global__ void rope_k_kernel(const unsigned short* __restrict__ qkv,
                              unsigned short* __restrict__ Kh) {
  int idx = blockIdx.x * 256 + threadIdx.x;   // B*T*NKV*32
  int i  = idx & 31;
  int kh = (idx >> 5) & 7;
  int bt = idx >> 8;
  int t  = bt & (T_ - 1);
  int b  = bt >> 11;
  float invf = exp2f(-(float)i * (L2_10000 / 32.f));
  float ang = (float)t * invf;
  float s, c; sincosf(ang, &s, &c);
  const unsigned short* row = qkv + (size_t)bt * NTOT_ + 2048 + kh * 64;
  float x1 = bf2f(row[i]), x2 = bf2f(row[i + 32]);
  unsigned short* kp = Kh + ((size_t)(b * NKV_ + kh) * T_ + t) * HEAD_;
  kp[i]      = f2bf(x1 * c - x2 * s);
  kp[i + 32] = f2bf(x2 * c + x1 * s);
}

// V (bf16 in QKVlin) -> Vt bf16 [b][kh][d][t]
__global__ void vt_kernel(const unsigned short* __restrict__ qkv,
                          unsigned short* __restrict__ Vt) {
  int idx = blockIdx.x * 256 + threadIdx.x;   // B*NKV*HEAD*T
  int t  = idx & (T_ - 1);
  int d  = (idx >> 11) & 63;
  int kh = (idx >> 17) & 7;
  int b  = idx >> 20;
  Vt[((size_t)((b * NKV_ + kh) * 64 + d)) * T_ + t] =
      qkv[(size_t)(b * T_ + t) * NTOT_ + 2560 + kh * 64 + d];
}

// ---------------- 128x128 m97-style GEMM (both projections) ----------------

template <typename OutT>
__launch_bounds__(256, 2)
__global__ void gemm_bt_bias(const unsigned short* __restrict__ A,
                             const unsigned short* __restrict__ BT,
                             const float* __restrict__ bias,
                             OutT* __restrict__ C, int N, int K) {
  __shared__ unsigned short Alds[128 * 32];
  __shared__ unsigned short Blds[128 * 32];
  const int tid = threadIdx.x;
  const int wave = tid >> 6, lane = tid & 63;
  const int l16 = lane & 15, lg = lane >> 4;
  const int m0 = blockIdx.x * 128;
  const int n0 = blockIdx.y * 128;
  const int wr = wave >> 1, wc = wave & 1;

  f32x4 zero4 = {0.f, 0.f, 0.f, 0.f};
  f32x4 acc[4][4];
#pragma unroll
  for (int i = 0; i < 4; ++i)
#pragma unroll
    for (int j = 0; j < 4; ++j) acc[i][j] = zero4;

  const int arow = tid >> 2;
  const int kcb  = (tid & 3) * 8;
  const int nk = K >> 5;
  for (int kt = 0; kt < nk; ++kt) {
    const int k0 = kt << 5;
    gload_lds16(A + (size_t)(m0 + arow) * K + k0 + kcb,       (char*)Alds + tid * 16);
    gload_lds16(A + (size_t)(m0 + 64 + arow) * K + k0 + kcb,  (char*)Alds + 4096 + tid * 16);
    gload_lds16(BT + (size_t)(n0 + arow) * K + k0 + kcb,      (char*)Blds + tid * 16);
    gload_lds16(BT + (size_t)(n0 + 64 + arow) * K + k0 + kcb, (char*)Blds + 4096 + tid * 16);
    __syncthreads();
    bf16x8 af[4], bfr[4];
#pragma unroll
    for (int i = 0; i < 4; ++i)
      af[i] = *(const bf16x8*)(Alds + (wr * 64 + i * 16 + l16) * 32 + lg * 8);
#pragma unroll
    for (int j = 0; j < 4; ++j)
      bfr[j] = *(const bf16x8*)(Blds + (wc * 64 + j * 16 + l16) * 32 + lg * 8);
#pragma unroll
    for (int i = 0; i < 4; ++i)
#pragma unroll
      for (int j = 0; j < 4; ++j)
        acc[i][j] = MFMA_(af[i], bfr[j], acc[i][j], 0, 0, 0);
    __syncthreads();
  }
#pragma unroll
  for (int j = 0; j < 4; ++j) {
    const int col = n0 + wc * 64 + j * 16 + l16;
    const float bv = bias[col];
#pragma unroll
    for (int i = 0; i < 4; ++i) {
      const int rowb = m0 + wr * 64 + i * 16 + lg * 4;
#pragma unroll
      for (int r = 0; r < 4; ++r) {
        const float v = acc[i][j][r] + bv;
        if constexpr (sizeof(OutT) == 2)
          C[(size_t)(rowb + r) * N + col] = (OutT)f2bf(v);
        else
          C[(size_t)(rowb + r) * N + col] = (OutT)v;
      }
    }
  }
}

// ---------------- flash attention (swapped-QK^T, exp2 softmax) ----------------
// grid (8, NQ, B); block handles q-tiles x and 15-x (34 KV-tiles, balanced).
// 4 waves x 32 q rows. S^T via mfma(K,Q); PV via mfma(V^T,P); dbuf + counted
// vmcnt. Native v_exp_f32, T13 skip-rescale (THR=8), row-sum via ones-MFMA.

__launch_bounds__(256, 2)
__global__ void flash_attn_kernel(const unsigned short* __restrict__ Qh,
                                  const unsigned short* __restrict__ Kh,
                                  const unsigned short* __restrict__ Vt,
                                  unsigned short* __restrict__ Y) {
  __shared__ unsigned short Klds[2][64 * 64];
  __shared__ unsigned short Vlds[2][64 * 64];
  __shared__ unsigned short Plds[4][32 * 64];
  const int tid = threadIdx.x;
  const int wave = tid >> 6, lane = tid & 63;
  const int l16 = lane & 15, lg = lane >> 4;
  const int h = blockIdx.y, b = blockIdx.z;
  const int kh = h >> 2;

  const size_t kbase = (size_t)(b * NKV_ + kh) * T_ * HEAD_;
  const size_t vbase = (size_t)(b * NKV_ + kh) * HEAD_ * T_;
  const int srow = tid >> 3;
  const int csrc = (tid & 7) ^ (srow & 7);
  unsigned short* pl = Plds[wave];
  const f32x4 zero4 = {0.f, 0.f, 0.f, 0.f};
  const short one_bf = (short)0x3F80;
  const bf16x8 onesv = {one_bf, one_bf, one_bf, one_bf,
                        one_bf, one_bf, one_bf, one_bf};

#define STAGE(bi, kv0) do {                                                         \
    gload_lds16(Kh + kbase + (size_t)((kv0) + srow) * HEAD_ + csrc * 8,             \
                (char*)Klds[bi] + tid * 16);                                        \
    gload_lds16(Kh + kbase + (size_t)((kv0) + srow + 32) * HEAD_ + csrc * 8,        \
                (char*)Klds[bi] + 4096 + tid * 16);                                 \
    gload_lds16(Vt + vbase + (size_t)srow * T_ + (kv0) + csrc * 8,                  \
                (char*)Vlds[bi] + tid * 16);                                        \
    gload_lds16(Vt + vbase + (size_t)(srow + 32) * T_ + (kv0) + csrc * 8,           \
                (char*)Vlds[bi] + 4096 + tid * 16);                                 \
  } while (0)

  for (int seg = 0; seg < 2; ++seg) {
    const int qt = seg ? (15 - (int)blockIdx.x) : (int)blockIdx.x;
    const int q0 = qt * QBLK_;
    const int nt = (q0 >> 6) + 2;

    bf16x8 aq[2][2];
#pragma unroll
    for (int qh = 0; qh < 2; ++qh) {
      const unsigned short* qp =
          Qh + ((size_t)(b * NQ_ + h) * T_ + q0 + wave * 32 + qh * 16 + l16) * HEAD_;
      aq[qh][0] = *(const bf16x8*)(qp + lg * 8);
      aq[qh][1] = *(const bf16x8*)(qp + 32 + lg * 8);
    }

    f32x4 oacc[2][4];
    f32x4 lsum[2];
#pragma unroll
    for (int qh = 0; qh < 2; ++qh) {
      lsum[qh] = zero4;
#pragma unroll
      for (int df = 0; df < 4; ++df) oacc[qh][df] = zero4;
    }
    float mreg[2] = {-1e30f, -1e30f};

    STAGE(0, 0);

    for (int t = 0; t < nt; ++t) {
      if (t + 1 < nt) {
        STAGE((t + 1) & 1, (t + 1) * 64);
        asm volatile("s_waitcnt vmcnt(4)" ::: "memory");
      } else {
        asm volatile("s_waitcnt vmcnt(0)" ::: "memory");
      }
      __builtin_amdgcn_s_barrier();
      __builtin_amdgcn_sched_barrier(0);

      const unsigned short* Kb = Klds[t & 1];
      const unsigned short* Vb = Vlds[t & 1];
      const int kv0 = t * 64;

      // ---- S^T = K Q^T (values pre-scaled by 0.125*log2e) ----
      float p[2][4][4];
#pragma unroll
      for (int cf = 0; cf < 4; ++cf) {
        const int krow = cf * 16 + l16;
        const bf16x8 k0 = *(const bf16x8*)(Kb + krow * 64 + ((lg ^ (krow & 7)) << 3));
        const bf16x8 k1 = *(const bf16x8*)(Kb + krow * 64 + (((4 + lg) ^ (krow & 7)) << 3));
#pragma unroll
        for (int qh = 0; qh < 2; ++qh) {
          f32x4 z = zero4;
          z = MFMA_(k0, aq[qh][0], z, 0, 0, 0);
          z = MFMA_(k1, aq[qh][1], z, 0, 0, 0);
#pragma unroll
          for (int r = 0; r < 4; ++r) p[qh][cf][r] = z[r];
        }
      }

      if (t >= nt - 2) {
#pragma unroll
        for (int qh = 0; qh < 2; ++qh) {
          const int qg = q0 + wave * 32 + qh * 16 + l16;
#pragma unroll
          for (int cf = 0; cf < 4; ++cf)
#pragma unroll
            for (int r = 0; r < 4; ++r)
              if (kv0 + cf * 16 + lg * 4 + r > qg) p[qh][cf][r] = -1e30f;
        }
      }

      // ---- tile max (max3-friendly chains, seeded with running max) ----
      float mn[2];
#pragma unroll
      for (int qh = 0; qh < 2; ++qh) {
        float m = mreg[qh];
#pragma unroll
        for (int cf = 0; cf < 4; ++cf) {
          m = fmaxf(m, fmaxf(p[qh][cf][0], p[qh][cf][1]));
          m = fmaxf(m, fmaxf(p[qh][cf][2], p[qh][cf][3]));
        }
        m = fmaxf(m, __shfl_xor(m, 16, 64));
        m = fmaxf(m, __shfl_xor(m, 32, 64));
        mn[qh] = m;
      }

      // ---- T13: rescale only when the max actually grew past THR ----
      const float dmax = fmaxf(mn[0] - mreg[0], mn[1] - mreg[1]);
      if (!__all(dmax <= 8.f)) {
#pragma unroll
        for (int qh = 0; qh < 2; ++qh) {
          const float corr = ex2(mreg[qh] - mn[qh]);
          mreg[qh] = mn[qh];
          lsum[qh][0] *= corr;
#pragma unroll
          for (int df = 0; df < 4; ++df)
#pragma unroll
            for (int r = 0; r < 4; ++r) oacc[qh][df][r] *= corr;
        }
      }

      // ---- exp (raw v_exp_f32) ----
#pragma unroll
      for (int qh = 0; qh < 2; ++qh)
#pragma unroll
        for (int cf = 0; cf < 4; ++cf)
#pragma unroll
          for (int r = 0; r < 4; ++r)
            p[qh][cf][r] = ex2(p[qh][cf][r] - mreg[qh]);

      // ---- P -> LDS (swizzled b64), read back as B-frags ----
#pragma unroll
      for (int qh = 0; qh < 2; ++qh) {
        const int row = qh * 16 + l16;
#pragma unroll
        for (int cf = 0; cf < 4; ++cf) {
          const unsigned int w0 = pk_bf16(p[qh][cf][0], p[qh][cf][1]);
          const unsigned int w1 = pk_bf16(p[qh][cf][2], p[qh][cf][3]);
          const int u = cf * 2 + (lg >> 1);
          char* ad = (char*)pl + row * 128 + ((u ^ (row & 7)) << 4) + ((lg & 1) << 3);
          *(unsigned long long*)ad =
              (unsigned long long)w0 | ((unsigned long long)w1 << 32);
        }
      }
      bf16x8 pf[2][2];
#pragma unroll
      for (int qh = 0; qh < 2; ++qh) {
        const int row = qh * 16 + l16;
#pragma unroll
        for (int k2 = 0; k2 < 2; ++k2) {
          const int u = k2 * 4 + lg;
          pf[qh][k2] = *(const bf16x8*)((char*)pl + row * 128 + ((u ^ (row & 7)) << 4));
        }
      }

      // ---- O^T += V^T P^T ; row-sum via ones-MFMA ----
#pragma unroll
      for (int qh = 0; qh < 2; ++qh) {
        lsum[qh] = MFMA_(onesv, pf[qh][0], lsum[qh], 0, 0, 0);
        lsum[qh] = MFMA_(onesv, pf[qh][1], lsum[qh], 0, 0, 0);
      }
#pragma unroll
      for (int df = 0; df < 4; ++df) {
        const int vrow = df * 16 + l16;
        const bf16x8 v0 = *(const bf16x8*)(Vb + vrow * 64 + ((lg ^ (vrow & 7)) << 3));
        const bf16x8 v1 = *(const bf16x8*)(Vb + vrow * 64 + (((4 + lg) ^ (vrow & 7)) << 3));
#pragma unroll
        for (int qh = 0; qh < 2; ++qh) {
          oacc[qh][df] = MFMA_(v0, pf[qh][0], oacc[qh][df], 0, 0, 0);
          oacc[qh][df] = MFMA_(v1, pf[qh][1], oacc[qh][df], 0, 0, 0);
        }
      }

      asm volatile("s_waitcnt lgkmcnt(0)" ::: "memory");
      __builtin_amdgcn_sched_barrier(0);
      __builtin_amdgcn_s_barrier();
    }

    // ---- epilogue: lsum[qh][0] already holds the full row sum ----
#pragma unroll
    for (int qh = 0; qh < 2; ++qh) {
      const float inv = 1.f / lsum[qh][0];
      const int tq = q0 + wave * 32 + qh * 16 + l16;
      unsigned short* yp = Y + ((size_t)(b * T_ + tq)) * EMB_ + h * HEAD_;
#pragma unroll
      for (int df = 0; df < 4; ++df) {
        const unsigned int w0 = pk_bf16(oacc[qh][df][0] * inv, oacc[qh][df][1] * inv);
        const unsigned int w1 = pk_bf16(oacc[qh][df][2] * inv, oacc[qh][df][3] * inv);
        *(unsigned long long*)(yp + df * 16 + lg * 4) =
            (unsigned long long)w0 | ((unsigned long long)w1 << 32);
      }
    }
  }
#undef STAGE
}

// ---------------- launch ----------------

extern "C" void kernel_launch(void* const* d_in, const int* in_sizes, int n_in,
                              void* d_out, int out_size, void* d_ws, size_t ws_size,
                              hipStream_t stream) {
  const float* x  = (const float*)d_in[0];
  const float* Wq = (const float*)d_in[1];
  const float* bq = (const float*)d_in[2];
  const float* Wk = (const float*)d_in[3];
  const float* bk = (const float*)d_in[4];
  const float* Wv = (const float*)d_in[5];
  const float* bv = (const float*)d_in[6];
  const float* Wo = (const float*)d_in[7];
  const float* bo = (const float*)d_in[8];
  float* out = (float*)d_out;

  char* ws = (char*)d_ws;
  size_t off = 0;
  auto alloc = [&](size_t bytes) {
    void* p = ws + off;
    off += (bytes + 255) & ~(size_t)255;
    return p;
  };
  unsigned short* xb     = (unsigned short*)alloc((size_t)M_ * EMB_ * 2);
  unsigned short* WqkvT  = (unsigned short*)alloc((size_t)NTOT_ * EMB_ * 2);
  unsigned short* WoT    = (unsigned short*)alloc((size_t)EMB_ * EMB_ * 2);
  float*          bcat   = (float*)alloc((size_t)NTOT_ * 4);
  unsigned short* QKVlin = (unsigned short*)alloc((size_t)M_ * NTOT_ * 2);
  unsigned short* Qh     = (unsigned short*)alloc((size_t)B_ * NQ_ * T_ * HEAD_ * 2);
  unsigned short* Kh     = (unsigned short*)alloc((size_t)B_ * NKV_ * T_ * HEAD_ * 2);
  unsigned short* Vt     = (unsigned short*)alloc((size_t)B_ * NKV_ * HEAD_ * T_ * 2);
  unsigned short* Yb     = (unsigned short*)alloc((size_t)M_ * EMB_ * 2);

  cvt_bf16_kernel<<<(M_ * EMB_ / 4 + 255) / 256, 256, 0, stream>>>(x, xb, M_ * EMB_ / 4);

  dim3 tb(32, 8);
  transpose_cvt_kernel<<<dim3(EMB_ / 32, EMB_ / 32), tb, 0, stream>>>(Wq, WqkvT, EMB_, EMB_);
  transpose_cvt_kernel<<<dim3(512 / 32, EMB_ / 32), tb, 0, stream>>>(Wk, WqkvT + (size_t)2048 * 2048, EMB_, 512);
  transpose_cvt_kernel<<<dim3(512 / 32, EMB_ / 32), tb, 0, stream>>>(Wv, WqkvT + (size_t)2560 * 2048, EMB_, 512);
  transpose_cvt_kernel<<<dim3(EMB_ / 32, EMB_ / 32), tb, 0, stream>>>(Wo, WoT, EMB_, EMB_);
  concat_bias_kernel<<<(NTOT_ + 255) / 256, 256, 0, stream>>>(bq, bk, bv, bcat);

  // QKV projection: 128^2, 768 blocks, bf16 out  (A/B vs round-5's 8-phase)
  gemm_bt_bias<unsigned short><<<dim3(M_ / 128, NTOT_ / 128), 256, 0, stream>>>(
      xb, WqkvT, bcat, QKVlin, NTOT_, EMB_);

  rope_q_kernel<<<(B_ * T_ * NQ_ * 32) / 256, 256, 0, stream>>>(QKVlin, Qh);
  rope_k_kernel<<<(B_ * T_ * NKV_ * 32) / 256, 256, 0, stream>>>(QKVlin, Kh);
  vt_kernel<<<(B_ * NKV_ * HEAD_ * T_) / 256, 256, 0, stream>>>(QKVlin, Vt);

  flash_attn_kernel<<<dim3(8, NQ_, B_), 256, 0, stream>>>(Qh, Kh, Vt, Yb);

  // output projection: 128^2, 512 blocks, fp32 out
  gemm_bt_bias<float><<<dim3(M_ / 128, EMB_ / 128), 256, 0, stream>>>(
      Yb, WoT, bo, out, EMB_, EMB_);

  (void)in_sizes; (void)n_in; (void)out_size; (void)ws_size;
}

// Round 7
// 223.816 us; speedup vs baseline: 1.2404x; 1.0342x over previous
//
#include <hip/hip_runtime.h>
#include <hip/hip_bf16.h>
#include <cstdint>
#include <cstddef>

typedef __attribute__((ext_vector_type(4))) float f32x4;
typedef __attribute__((ext_vector_type(8))) short bf16x8;

#define B_    2
#define T_    2048
#define EMB_  2048
#define NQ_   32
#define NKV_  8
#define HEAD_ 64
#define NTOT_ 3072
#define M_    (B_ * T_)     // 4096
#define QBLK_ 128
#define NK_   32            // K=2048 / BK=64

#define MFMA_ __builtin_amdgcn_mfma_f32_16x16x32_bf16

__device__ __forceinline__ unsigned short f2bf(float f) {
  union { float f; unsigned int u; } v; v.f = f;
  unsigned int r = v.u + 0x7fffu + ((v.u >> 16) & 1u);
  return (unsigned short)(r >> 16);
}

__device__ __forceinline__ float bf2f(unsigned short u) {
  union { unsigned int u; float f; } v; v.u = (unsigned int)u << 16; return v.f;
}

__device__ __forceinline__ unsigned int pk_bf16(float lo, float hi) {
  __hip_bfloat162 h = __float22bfloat162_rn(make_float2(lo, hi));
  union { __hip_bfloat162 h; unsigned int u; } c; c.h = h;
  return c.u;
}

// raw v_exp_f32 (2^x) — libm exp2f takes the slow OCML fixup path
__device__ __forceinline__ float ex2(float x) {
  float r;
  asm("v_exp_f32 %0, %1" : "=v"(r) : "v"(x));
  return r;
}

__device__ __forceinline__ void gload_lds16(const void* g, void* l) {
  __builtin_amdgcn_global_load_lds(
      (const __attribute__((address_space(1))) void*)g,
      (__attribute__((address_space(3))) void*)l, 16, 0, 0);
}

// ---------------- elementwise converts / relayouts ----------------

__global__ void cvt_bf16_kernel(const float* __restrict__ src,
                                unsigned short* __restrict__ dst, int n4) {
  int i = blockIdx.x * blockDim.x + threadIdx.x;
  if (i >= n4) return;
  float4 v = ((const float4*)src)[i];
  unsigned long long pk =
      (unsigned long long)f2bf(v.x) |
      ((unsigned long long)f2bf(v.y) << 16) |
      ((unsigned long long)f2bf(v.z) << 32) |
      ((unsigned long long)f2bf(v.w) << 48);
  *(unsigned long long*)(dst + (size_t)i * 4) = pk;
}

// src fp32 [R][C]  ->  dst bf16 [C][R]
__global__ void transpose_cvt_kernel(const float* __restrict__ src,
                                     unsigned short* __restrict__ dst,
                                     int R, int C) {
  __shared__ float tile[32][33];
  int c0 = blockIdx.x * 32, r0 = blockIdx.y * 32;
  int tx = threadIdx.x, ty = threadIdx.y;
#pragma unroll
  for (int k = 0; k < 4; ++k)
    tile[ty + 8 * k][tx] = src[(size_t)(r0 + ty + 8 * k) * C + c0 + tx];
  __syncthreads();
#pragma unroll
  for (int k = 0; k < 4; ++k)
    dst[(size_t)(c0 + ty + 8 * k) * R + r0 + tx] = f2bf(tile[tx][ty + 8 * k]);
}

__global__ void concat_bias_kernel(const float* __restrict__ bq,
                                   const float* __restrict__ bk,
                                   const float* __restrict__ bv,
                                   float* __restrict__ dst) {
  int i = blockIdx.x * 256 + threadIdx.x;
  if (i < 2048) dst[i] = bq[i];
  else if (i < 2560) dst[i] = bk[i - 2048];
  else if (i < 3072) dst[i] = bv[i - 2560];
}

#define L2_10000 13.2877123795494f
#define QSCALE_  0.18033688011112043f   // 0.125 * log2(e) -> softmax in exp2

// QKVlin bf16 [4096][3072] -> Qh bf16 [b][h][t][64] with RoPE; QSCALE folded.
__global__ void rope_q_kernel(const unsigned short* __restrict__ qkv,
                              unsigned short* __restrict__ Qh) {
  int idx = blockIdx.x * 256 + threadIdx.x;   // B*T*NQ*32
  int i  = idx & 31;
  int h  = (idx >> 5) & 31;
  int bt = idx >> 10;
  int t  = bt & (T_ - 1);
  int b  = bt >> 11;
  float invf = exp2f(-(float)i * (L2_10000 / 32.f));
  float ang = (float)t * invf;
  float s, c; sincosf(ang, &s, &c);
  const unsigned short* row = qkv + (size_t)bt * NTOT_ + h * 64;
  float x1 = bf2f(row[i]), x2 = bf2f(row[i + 32]);
  unsigned short* q = Qh + ((size_t)(b * NQ_ + h) * T_ + t) * HEAD_;
  q[i]      = f2bf((x1 * c - x2 * s) * QSCALE_);
  q[i + 32] = f2bf((x2 * c + x1 * s) * QSCALE_);
}

__global__ void rope_k_kernel(const unsigned short* __restrict__ qkv,
                              unsigned short* __restrict__ Kh) {
  int idx = blockIdx.x * 256 + threadIdx.x;   // B*T*NKV*32
  int i  = idx & 31;
  int kh = (idx >> 5) & 7;
  int bt = idx >> 8;
  int t  = bt & (T_ - 1);
  int b  = bt >> 11;
  float invf = exp2f(-(float)i * (L2_10000 / 32.f));
  float ang = (float)t * invf;
  float s, c; sincosf(ang, &s, &c);
  const unsigned short* row = qkv + (size_t)bt * NTOT_ + 2048 + kh * 64;
  float x1 = bf2f(row[i]), x2 = bf2f(row[i + 32]);
  unsigned short* kp = Kh + ((size_t)(b * NKV_ + kh) * T_ + t) * HEAD_;
  kp[i]      = f2bf(x1 * c - x2 * s);
  kp[i + 32] = f2bf(x2 * c + x1 * s);
}

// V (bf16 in QKVlin) -> Vt bf16 [b][kh][d][t]
__global__ void vt_kernel(const unsigned short* __restrict__ qkv,
                          unsigned short* __restrict__ Vt) {
  int idx = blockIdx.x * 256 + threadIdx.x;   // B*NKV*HEAD*T
  int t  = idx & (T_ - 1);
  int d  = (idx >> 11) & 63;
  int kh = (idx >> 17) & 7;
  int b  = idx >> 20;
  Vt[((size_t)((b * NKV_ + kh) * 64 + d)) * T_ + t] =
      qkv[(size_t)(b * T_ + t) * NTOT_ + 2560 + kh * 64 + d];
}

// ---------------- QKV GEMM: 128x192 tile, 3-phase, K=2048 ----------------
// C bf16[4096][3072] = A[4096][2048] x BT[3072][2048]^T + bias.
// 512 threads = 8 waves (2M x 4N); per-wave 64x48 = acc[4][3].
// grid 32x16 = 512 blocks = exactly 2/CU (LDS 80KB dbuf).
// A-frags read once per tile (ph1) and register-held -> A LDS region free
// after ph1's closing barrier (staging t+2's A into live buffer is safe by
// barrier ordering). 5 units/tile (A0,A1,B0,B1,B2; 8KB each = 1 gload/thr);
// issue schedule u=7+5t..11+5t at phases (1,1,2,2,3); vmcnt(2) per tile.

__launch_bounds__(512, 4)
__global__ void gemm_qkv_3ph(const unsigned short* __restrict__ A,
                             const unsigned short* __restrict__ BT,
                             const float* __restrict__ bias,
                             unsigned short* __restrict__ C) {
  __shared__ unsigned short sh[2 * 20480];   // 80 KiB: per buf A 16KB + B 24KB
  const int tid = threadIdx.x;
  const int lane = tid & 63, l16 = lane & 15, lg = lane >> 4;
  const int wave = tid >> 6, wm = wave >> 2, wn = wave & 3;
  const int bid = blockIdx.x;
  const int sw = (bid & 7) * 64 + (bid >> 3);   // XCD swizzle, 512 blocks
  const int mt = sw & 31, nt = sw >> 5;
  const int m0 = mt * 128, n0 = nt * 192;
  const int arow = tid >> 3;
  const int usrc = (tid & 7) ^ (arow & 7);
  const int swz = l16 & 7;
  const int uo0 = (lg ^ swz) << 3;
  const int uo1 = ((4 + lg) ^ swz) << 3;

  f32x4 acc[4][3];
#pragma unroll
  for (int i = 0; i < 4; ++i)
#pragma unroll
    for (int j = 0; j < 3; ++j) acc[i][j] = (f32x4){0.f, 0.f, 0.f, 0.f};

  auto STG = [&](int u) {
    if (u >= 5 * NK_) return;
    const int kt = u / 5, j = u % 5;
    char* bufb = (char*)sh + (kt & 1) * 40960;
    if (j < 2) {
      gload_lds16(A + (size_t)(m0 + j * 64 + arow) * 2048 + kt * 64 + usrc * 8,
                  bufb + j * 8192 + tid * 16);
    } else {
      const int jj = j - 2;
      gload_lds16(BT + (size_t)(n0 + jj * 64 + arow) * 2048 + kt * 64 + usrc * 8,
                  bufb + 16384 + jj * 8192 + tid * 16);
    }
  };

  // prologue: tile0 all 5 + tile1 {A0,A1}
#pragma unroll
  for (int u = 0; u < 7; ++u) STG(u);
  asm volatile("s_waitcnt vmcnt(2)" ::: "memory");
  __builtin_amdgcn_s_barrier();

  for (int t = 0; t < NK_; ++t) {
    const unsigned short* Ab = sh + (t & 1) * 20480;
    const unsigned short* Bb = Ab + 8192;

    bf16x8 af[4][2], bfr[2];
    // ---- phase 1 (fj=0): read ALL A frags + B0 ----
#pragma unroll
    for (int fi = 0; fi < 4; ++fi) {
      const int ro = (fi * 32 + wm * 16 + l16) * 64;
      af[fi][0] = *(const bf16x8*)(Ab + ro + uo0);
      af[fi][1] = *(const bf16x8*)(Ab + ro + uo1);
    }
    {
      const int ro = (wn * 16 + l16) * 64;
      bfr[0] = *(const bf16x8*)(Bb + ro + uo0);
      bfr[1] = *(const bf16x8*)(Bb + ro + uo1);
    }
    STG(7 + 5 * t);  STG(8 + 5 * t);          // t+1 B0, B1
    __builtin_amdgcn_s_barrier();
    asm volatile("s_waitcnt lgkmcnt(0)" ::: "memory");
    __builtin_amdgcn_sched_barrier(0);
    __builtin_amdgcn_s_setprio(1);
#pragma unroll
    for (int fi = 0; fi < 4; ++fi) {
      acc[fi][0] = MFMA_(af[fi][0], bfr[0], acc[fi][0], 0, 0, 0);
      acc[fi][0] = MFMA_(af[fi][1], bfr[1], acc[fi][0], 0, 0, 0);
    }
    __builtin_amdgcn_s_setprio(0);
    __builtin_amdgcn_s_barrier();

    // ---- phase 2 (fj=1) ----
    {
      const int ro = (64 + wn * 16 + l16) * 64;
      bfr[0] = *(const bf16x8*)(Bb + ro + uo0);
      bfr[1] = *(const bf16x8*)(Bb + ro + uo1);
    }
    STG(9 + 5 * t);  STG(10 + 5 * t);         // t+1 B2, t+2 A0 (A free after ph1)
    __builtin_amdgcn_s_barrier();
    asm volatile("s_waitcnt lgkmcnt(0)" ::: "memory");
    __builtin_amdgcn_sched_barrier(0);
    __builtin_amdgcn_s_setprio(1);
#pragma unroll
    for (int fi = 0; fi < 4; ++fi) {
      acc[fi][1] = MFMA_(af[fi][0], bfr[0], acc[fi][1], 0, 0, 0);
      acc[fi][1] = MFMA_(af[fi][1], bfr[1], acc[fi][1], 0, 0, 0);
    }
    __builtin_amdgcn_s_setprio(0);
    __builtin_amdgcn_s_barrier();

    // ---- phase 3 (fj=2) ----
    {
      const int ro = (128 + wn * 16 + l16) * 64;
      bfr[0] = *(const bf16x8*)(Bb + ro + uo0);
      bfr[1] = *(const bf16x8*)(Bb + ro + uo1);
    }
    STG(11 + 5 * t);                          // t+2 A1
    __builtin_amdgcn_s_barrier();
    asm volatile("s_waitcnt lgkmcnt(0)" ::: "memory");
    __builtin_amdgcn_sched_barrier(0);
    __builtin_amdgcn_s_setprio(1);
#pragma unroll
    for (int fi = 0; fi < 4; ++fi) {
      acc[fi][2] = MFMA_(af[fi][0], bfr[0], acc[fi][2], 0, 0, 0);
      acc[fi][2] = MFMA_(af[fi][1], bfr[1], acc[fi][2], 0, 0, 0);
    }
    __builtin_amdgcn_s_setprio(0);
    if (t < NK_ - 2)       asm volatile("s_waitcnt vmcnt(2)" ::: "memory");
    else if (t == NK_ - 2) asm volatile("s_waitcnt vmcnt(0)" ::: "memory");
    __builtin_amdgcn_s_barrier();
  }

  // ---- epilogue (bf16) ----
#pragma unroll
  for (int fj = 0; fj < 3; ++fj) {
    const int col = n0 + fj * 64 + wn * 16 + l16;
    const float bv = bias[col];
#pragma unroll
    for (int fi = 0; fi < 4; ++fi) {
      const int row0 = m0 + fi * 32 + wm * 16 + lg * 4;
#pragma unroll
      for (int r = 0; r < 4; ++r)
        C[(size_t)(row0 + r) * NTOT_ + col] = f2bf(acc[fi][fj][r] + bv);
    }
  }
}

// ---------------- out GEMM: 128x256 tile, 2-phase, K=2048 ----------------
// C fp32[4096][2048]; grid 32x8 = 256 blocks = exactly 1/CU. 512 threads,
// per-wave 64x64 = acc[4][4]. 6 gloads/tile (Alo,Ahi,b0..b3); issue
// u=9+6t..11+6t at ph1, 12+6t..14+6t at ph2; vmcnt(3) per tile. LDS 96KB.

__launch_bounds__(512, 2)
__global__ void gemm_o_2ph(const unsigned short* __restrict__ A,
                           const unsigned short* __restrict__ BT,
                           const float* __restrict__ bias,
                           float* __restrict__ C) {
  __shared__ unsigned short sh[2 * 24576];   // 96 KiB: per buf A 16KB + B 32KB
  const int tid = threadIdx.x;
  const int lane = tid & 63, l16 = lane & 15, lg = lane >> 4;
  const int wave = tid >> 6, wm = wave >> 2, wn = wave & 3;
  const int bid = blockIdx.x;
  const int sw = (bid & 7) * 32 + (bid >> 3);   // XCD swizzle, 256 blocks
  const int mt = sw & 31, nt = sw >> 5;
  const int m0 = mt * 128, n0 = nt * 256;
  const int arow = tid >> 3;
  const int usrc = (tid & 7) ^ (arow & 7);
  const int swz = l16 & 7;
  const int uo0 = (lg ^ swz) << 3;
  const int uo1 = ((4 + lg) ^ swz) << 3;

  f32x4 acc[4][4];
#pragma unroll
  for (int i = 0; i < 4; ++i)
#pragma unroll
    for (int j = 0; j < 4; ++j) acc[i][j] = (f32x4){0.f, 0.f, 0.f, 0.f};

  auto STG = [&](int u) {
    if (u >= 6 * NK_) return;
    const int kt = u / 6, j = u % 6;
    char* bufb = (char*)sh + (kt & 1) * 49152;
    if (j < 2) {
      gload_lds16(A + (size_t)(m0 + j * 64 + arow) * 2048 + kt * 64 + usrc * 8,
                  bufb + j * 8192 + tid * 16);
    } else {
      const int jj = j - 2;
      gload_lds16(BT + (size_t)(n0 + jj * 64 + arow) * 2048 + kt * 64 + usrc * 8,
                  bufb + 16384 + jj * 8192 + tid * 16);
    }
  };

  // prologue: tile0 all 6 + tile1 {Alo,Ahi,b0}
#pragma unroll
  for (int u = 0; u < 9; ++u) STG(u);
  asm volatile("s_waitcnt vmcnt(3)" ::: "memory");
  __builtin_amdgcn_s_barrier();

  for (int t = 0; t < NK_; ++t) {
    const unsigned short* Ab = sh + (t & 1) * 24576;
    const unsigned short* Bb = Ab + 8192;

    bf16x8 af[4][2], bfr[2][2];
    // ---- phase 1 (fj 0,1): read ALL A frags + B-lo ----
#pragma unroll
    for (int fi = 0; fi < 4; ++fi) {
      const int ro = (fi * 32 + wm * 16 + l16) * 64;
      af[fi][0] = *(const bf16x8*)(Ab + ro + uo0);
      af[fi][1] = *(const bf16x8*)(Ab + ro + uo1);
    }
#pragma unroll
    for (int fj = 0; fj < 2; ++fj) {
      const int ro = (fj * 64 + wn * 16 + l16) * 64;
      bfr[fj][0] = *(const bf16x8*)(Bb + ro + uo0);
      bfr[fj][1] = *(const bf16x8*)(Bb + ro + uo1);
    }
    STG(9 + 6 * t);  STG(10 + 6 * t);  STG(11 + 6 * t);   // t+1 b1,b2,b3
    __builtin_amdgcn_s_barrier();
    asm volatile("s_waitcnt lgkmcnt(0)" ::: "memory");
    __builtin_amdgcn_sched_barrier(0);
    __builtin_amdgcn_s_setprio(1);
#pragma unroll
    for (int fi = 0; fi < 4; ++fi)
#pragma unroll
      for (int fj = 0; fj < 2; ++fj) {
        acc[fi][fj] = MFMA_(af[fi][0], bfr[fj][0], acc[fi][fj], 0, 0, 0);
        acc[fi][fj] = MFMA_(af[fi][1], bfr[fj][1], acc[fi][fj], 0, 0, 0);
      }
    __builtin_amdgcn_s_setprio(0);
    __builtin_amdgcn_s_barrier();

    // ---- phase 2 (fj 2,3) ----
#pragma unroll
    for (int fj = 0; fj < 2; ++fj) {
      const int ro = ((2 + fj) * 64 + wn * 16 + l16) * 64;
      bfr[fj][0] = *(const bf16x8*)(Bb + ro + uo0);
      bfr[fj][1] = *(const bf16x8*)(Bb + ro + uo1);
    }
    STG(12 + 6 * t);  STG(13 + 6 * t);  STG(14 + 6 * t);  // t+2 Alo,Ahi,b0
    __builtin_amdgcn_s_barrier();
    asm volatile("s_waitcnt lgkmcnt(0)" ::: "memory");
    __builtin_amdgcn_sched_barrier(0);
    __builtin_amdgcn_s_setprio(1);
#pragma unroll
    for (int fi = 0; fi < 4; ++fi)
#pragma unroll
      for (int fj = 0; fj < 2; ++fj) {
        acc[fi][2 + fj] = MFMA_(af[fi][0], bfr[fj][0], acc[fi][2 + fj], 0, 0, 0);
        acc[fi][2 + fj] = MFMA_(af[fi][1], bfr[fj][1], acc[fi][2 + fj], 0, 0, 0);
      }
    __builtin_amdgcn_s_setprio(0);
    if (t < NK_ - 2)       asm volatile("s_waitcnt vmcnt(3)" ::: "memory");
    else if (t == NK_ - 2) asm volatile("s_waitcnt vmcnt(0)" ::: "memory");
    __builtin_amdgcn_s_barrier();
  }

  // ---- epilogue (fp32) ----
#pragma unroll
  for (int fj = 0; fj < 4; ++fj) {
    const int col = n0 + fj * 64 + wn * 16 + l16;
    const float bv = bias[col];
#pragma unroll
    for (int fi = 0; fi < 4; ++fi) {
      const int row0 = m0 + fi * 32 + wm * 16 + lg * 4;
#pragma unroll
      for (int r = 0; r < 4; ++r)
        C[(size_t)(row0 + r) * EMB_ + col] = acc[fi][fj][r] + bv;
    }
  }
}

// ---------------- flash attention (round-6, unchanged) ----------------

__launch_bounds__(256, 2)
__global__ void flash_attn_kernel(const unsigned short* __restrict__ Qh,
                                  const unsigned short* __restrict__ Kh,
                                  const unsigned short* __restrict__ Vt,
                                  unsigned short* __restrict__ Y) {
  __shared__ unsigned short Klds[2][64 * 64];
  __shared__ unsigned short Vlds[2][64 * 64];
  __shared__ unsigned short Plds[4][32 * 64];
  const int tid = threadIdx.x;
  const int wave = tid >> 6, lane = tid & 63;
  const int l16 = lane & 15, lg = lane >> 4;
  const int h = blockIdx.y, b = blockIdx.z;
  const int kh = h >> 2;

  const size_t kbase = (size_t)(b * NKV_ + kh) * T_ * HEAD_;
  const size_t vbase = (size_t)(b * NKV_ + kh) * HEAD_ * T_;
  const int srow = tid >> 3;
  const int csrc = (tid & 7) ^ (srow & 7);
  unsigned short* pl = Plds[wave];
  const f32x4 zero4 = {0.f, 0.f, 0.f, 0.f};
  const short one_bf = (short)0x3F80;
  const bf16x8 onesv = {one_bf, one_bf, one_bf, one_bf,
                        one_bf, one_bf, one_bf, one_bf};

#define STAGE(bi, kv0) do {                                                         \
    gload_lds16(Kh + kbase + (size_t)((kv0) + srow) * HEAD_ + csrc * 8,             \
                (char*)Klds[bi] + tid * 16);                                        \
    gload_lds16(Kh + kbase + (size_t)((kv0) + srow + 32) * HEAD_ + csrc * 8,        \
                (char*)Klds[bi] + 4096 + tid * 16);                                 \
    gload_lds16(Vt + vbase + (size_t)srow * T_ + (kv0) + csrc * 8,                  \
                (char*)Vlds[bi] + tid * 16);                                        \
    gload_lds16(Vt + vbase + (size_t)(srow + 32) * T_ + (kv0) + csrc * 8,           \
                (char*)Vlds[bi] + 4096 + tid * 16);                                 \
  } while (0)

  for (int seg = 0; seg < 2; ++seg) {
    const int qt = seg ? (15 - (int)blockIdx.x) : (int)blockIdx.x;
    const int q0 = qt * QBLK_;
    const int nt = (q0 >> 6) + 2;

    bf16x8 aq[2][2];
#pragma unroll
    for (int qh = 0; qh < 2; ++qh) {
      const unsigned short* qp =
          Qh + ((size_t)(b * NQ_ + h) * T_ + q0 + wave * 32 + qh * 16 + l16) * HEAD_;
      aq[qh][0] = *(const bf16x8*)(qp + lg * 8);
      aq[qh][1] = *(const bf16x8*)(qp + 32 + lg * 8);
    }

    f32x4 oacc[2][4];
    f32x4 lsum[2];
#pragma unroll
    for (int qh = 0; qh < 2; ++qh) {
      lsum[qh] = zero4;
#pragma unroll
      for (int df = 0; df < 4; ++df) oacc[qh][df] = zero4;
    }
    float mreg[2] = {-1e30f, -1e30f};

    STAGE(0, 0);

    for (int t = 0; t < nt; ++t) {
      if (t + 1 < nt) {
        STAGE((t + 1) & 1, (t + 1) * 64);
        asm volatile("s_waitcnt vmcnt(4)" ::: "memory");
      } else {
        asm volatile("s_waitcnt vmcnt(0)" ::: "memory");
      }
      __builtin_amdgcn_s_barrier();
      __builtin_amdgcn_sched_barrier(0);

      const unsigned short* Kb = Klds[t & 1];
      const unsigned short* Vb = Vlds[t & 1];
      const int kv0 = t * 64;

      float p[2][4][4];
#pragma unroll
      for (int cf = 0; cf < 4; ++cf) {
        const int krow = cf * 16 + l16;
        const bf16x8 k0 = *(const bf16x8*)(Kb + krow * 64 + ((lg ^ (krow & 7)) << 3));
        const bf16x8 k1 = *(const bf16x8*)(Kb + krow * 64 + (((4 + lg) ^ (krow & 7)) << 3));
#pragma unroll
        for (int qh = 0; qh < 2; ++qh) {
          f32x4 z = zero4;
          z = MFMA_(k0, aq[qh][0], z, 0, 0, 0);
          z = MFMA_(k1, aq[qh][1], z, 0, 0, 0);
#pragma unroll
          for (int r = 0; r < 4; ++r) p[qh][cf][r] = z[r];
        }
      }

      if (t >= nt - 2) {
#pragma unroll
        for (int qh = 0; qh < 2; ++qh) {
          const int qg = q0 + wave * 32 + qh * 16 + l16;
#pragma unroll
          for (int cf = 0; cf < 4; ++cf)
#pragma unroll
            for (int r = 0; r < 4; ++r)
              if (kv0 + cf * 16 + lg * 4 + r > qg) p[qh][cf][r] = -1e30f;
        }
      }

      float mn[2];
#pragma unroll
      for (int qh = 0; qh < 2; ++qh) {
        float m = mreg[qh];
#pragma unroll
        for (int cf = 0; cf < 4; ++cf) {
          m = fmaxf(m, fmaxf(p[qh][cf][0], p[qh][cf][1]));
          m = fmaxf(m, fmaxf(p[qh][cf][2], p[qh][cf][3]));
        }
        m = fmaxf(m, __shfl_xor(m, 16, 64));
        m = fmaxf(m, __shfl_xor(m, 32, 64));
        mn[qh] = m;
      }

      const float dmax = fmaxf(mn[0] - mreg[0], mn[1] - mreg[1]);
      if (!__all(dmax <= 8.f)) {
#pragma unroll
        for (int qh = 0; qh < 2; ++qh) {
          const float corr = ex2(mreg[qh] - mn[qh]);
          mreg[qh] = mn[qh];
          lsum[qh][0] *= corr;
#pragma unroll
          for (int df = 0; df < 4; ++df)
#pragma unroll
            for (int r = 0; r < 4; ++r) oacc[qh][df][r] *= corr;
        }
      }

#pragma unroll
      for (int qh = 0; qh < 2; ++qh)
#pragma unroll
        for (int cf = 0; cf < 4; ++cf)
#pragma unroll
          for (int r = 0; r < 4; ++r)
            p[qh][cf][r] = ex2(p[qh][cf][r] - mreg[qh]);

#pragma unroll
      for (int qh = 0; qh < 2; ++qh) {
        const int row = qh * 16 + l16;
#pragma unroll
        for (int cf = 0; cf < 4; ++cf) {
          const unsigned int w0 = pk_bf16(p[qh][cf][0], p[qh][cf][1]);
          const unsigned int w1 = pk_bf16(p[qh][cf][2], p[qh][cf][3]);
          const int u = cf * 2 + (lg >> 1);
          char* ad = (char*)pl + row * 128 + ((u ^ (row & 7)) << 4) + ((lg & 1) << 3);
          *(unsigned long long*)ad =
              (unsigned long long)w0 | ((unsigned long long)w1 << 32);
        }
      }
      bf16x8 pf[2][2];
#pragma unroll
      for (int qh = 0; qh < 2; ++qh) {
        const int row = qh * 16 + l16;
#pragma unroll
        for (int k2 = 0; k2 < 2; ++k2) {
          const int u = k2 * 4 + lg;
          pf[qh][k2] = *(const bf16x8*)((char*)pl + row * 128 + ((u ^ (row & 7)) << 4));
        }
      }

#pragma unroll
      for (int qh = 0; qh < 2; ++qh) {
        lsum[qh] = MFMA_(onesv, pf[qh][0], lsum[qh], 0, 0, 0);
        lsum[qh] = MFMA_(onesv, pf[qh][1], lsum[qh], 0, 0, 0);
      }
#pragma unroll
      for (int df = 0; df < 4; ++df) {
        const int vrow = df * 16 + l16;
        const bf16x8 v0 = *(const bf16x8*)(Vb + vrow * 64 + ((lg ^ (vrow & 7)) << 3));
        const bf16x8 v1 = *(const bf16x8*)(Vb + vrow * 64 + (((4 + lg) ^ (vrow & 7)) << 3));
#pragma unroll
        for (int qh = 0; qh < 2; ++qh) {
          oacc[qh][df] = MFMA_(v0, pf[qh][0], oacc[qh][df], 0, 0, 0);
          oacc[qh][df] = MFMA_(v1, pf[qh][1], oacc[qh][df], 0, 0, 0);
        }
      }

      asm volatile("s_waitcnt lgkmcnt(0)" ::: "memory");
      __builtin_amdgcn_sched_barrier(0);
      __builtin_amdgcn_s_barrier();
    }

#pragma unroll
    for (int qh = 0; qh < 2; ++qh) {
      const float inv = 1.f / lsum[qh][0];
      const int tq = q0 + wave * 32 + qh * 16 + l16;
      unsigned short* yp = Y + ((size_t)(b * T_ + tq)) * EMB_ + h * HEAD_;
#pragma unroll
      for (int df = 0; df < 4; ++df) {
        const unsigned int w0 = pk_bf16(oacc[qh][df][0] * inv, oacc[qh][df][1] * inv);
        const unsigned int w1 = pk_bf16(oacc[qh][df][2] * inv, oacc[qh][df][3] * inv);
        *(unsigned long long*)(yp + df * 16 + lg * 4) =
            (unsigned long long)w0 | ((unsigned long long)w1 << 32);
      }
    }
  }
#undef STAGE
}

// ---------------- launch ----------------

extern "C" void kernel_launch(void* const* d_in, const int* in_sizes, int n_in,
                              void* d_out, int out_size, void* d_ws, size_t ws_size,
                              hipStream_t stream) {
  const float* x  = (const float*)d_in[0];
  const float* Wq = (const float*)d_in[1];
  const float* bq = (const float*)d_in[2];
  const float* Wk = (const float*)d_in[3];
  const float* bk = (const float*)d_in[4];
  const float* Wv = (const float*)d_in[5];
  const float* bv = (const float*)d_in[6];
  const float* Wo = (const float*)d_in[7];
  const float* bo = (const float*)d_in[8];
  float* out = (float*)d_out;

  char* ws = (char*)d_ws;
  size_t off = 0;
  auto alloc = [&](size_t bytes) {
    void* p = ws + off;
    off += (bytes + 255) & ~(size_t)255;
    return p;
  };
  unsigned short* xb     = (unsigned short*)alloc((size_t)M_ * EMB_ * 2);
  unsigned short* WqkvT  = (unsigned short*)alloc((size_t)NTOT_ * EMB_ * 2);
  unsigned short* WoT    = (unsigned short*)alloc((size_t)EMB_ * EMB_ * 2);
  float*          bcat   = (float*)alloc((size_t)NTOT_ * 4);
  unsigned short* QKVlin = (unsigned short*)alloc((size_t)M_ * NTOT_ * 2);
  unsigned short* Qh     = (unsigned short*)alloc((size_t)B_ * NQ_ * T_ * HEAD_ * 2);
  unsigned short* Kh     = (unsigned short*)alloc((size_t)B_ * NKV_ * T_ * HEAD_ * 2);
  unsigned short* Vt     = (unsigned short*)alloc((size_t)B_ * NKV_ * HEAD_ * T_ * 2);
  unsigned short* Yb     = (unsigned short*)alloc((size_t)M_ * EMB_ * 2);

  cvt_bf16_kernel<<<(M_ * EMB_ / 4 + 255) / 256, 256, 0, stream>>>(x, xb, M_ * EMB_ / 4);

  dim3 tb(32, 8);
  transpose_cvt_kernel<<<dim3(EMB_ / 32, EMB_ / 32), tb, 0, stream>>>(Wq, WqkvT, EMB_, EMB_);
  transpose_cvt_kernel<<<dim3(512 / 32, EMB_ / 32), tb, 0, stream>>>(Wk, WqkvT + (size_t)2048 * 2048, EMB_, 512);
  transpose_cvt_kernel<<<dim3(512 / 32, EMB_ / 32), tb, 0, stream>>>(Wv, WqkvT + (size_t)2560 * 2048, EMB_, 512);
  transpose_cvt_kernel<<<dim3(EMB_ / 32, EMB_ / 32), tb, 0, stream>>>(Wo, WoT, EMB_, EMB_);
  concat_bias_kernel<<<(NTOT_ + 255) / 256, 256, 0, stream>>>(bq, bk, bv, bcat);

  // QKV projection: 128x192 3-phase, 512 blocks = 2/CU, bf16 out
  gemm_qkv_3ph<<<512, 512, 0, stream>>>(xb, WqkvT, bcat, QKVlin);

  rope_q_kernel<<<(B_ * T_ * NQ_ * 32) / 256, 256, 0, stream>>>(QKVlin, Qh);
  rope_k_kernel<<<(B_ * T_ * NKV_ * 32) / 256, 256, 0, stream>>>(QKVlin, Kh);
  vt_kernel<<<(B_ * NKV_ * HEAD_ * T_) / 256, 256, 0, stream>>>(QKVlin, Vt);

  flash_attn_kernel<<<dim3(8, NQ_, B_), 256, 0, stream>>>(Qh, Kh, Vt, Yb);

  // output projection: 128x256 2-phase, 256 blocks = 1/CU, fp32 out
  gemm_o_2ph<<<256, 512, 0, stream>>>(Yb, WoT, bo, out);

  (void)in_sizes; (void)n_in; (void)out_size; (void)ws_size;
}

// Round 8
// 220.215 us; speedup vs baseline: 1.2607x; 1.0164x over previous
//
#include <hip/hip_runtime.h>
#include <hip/hip_bf16.h>
#include <cstdint>
#include <cstddef>

typedef __attribute__((ext_vector_type(4))) float f32x4;
typedef __attribute__((ext_vector_type(8))) short bf16x8;

#define B_    2
#define T_    2048
#define EMB_  2048
#define NQ_   32
#define NKV_  8
#define HEAD_ 64
#define NTOT_ 3072
#define M_    (B_ * T_)     // 4096
#define QBLK_ 64
#define NK_   32            // K=2048 / BK=64

#define MFMA_ __builtin_amdgcn_mfma_f32_16x16x32_bf16

__device__ __forceinline__ unsigned short f2bf(float f) {
  union { float f; unsigned int u; } v; v.f = f;
  unsigned int r = v.u + 0x7fffu + ((v.u >> 16) & 1u);
  return (unsigned short)(r >> 16);
}

__device__ __forceinline__ float bf2f(unsigned short u) {
  union { unsigned int u; float f; } v; v.u = (unsigned int)u << 16; return v.f;
}

__device__ __forceinline__ unsigned int pk_bf16(float lo, float hi) {
  __hip_bfloat162 h = __float22bfloat162_rn(make_float2(lo, hi));
  union { __hip_bfloat162 h; unsigned int u; } c; c.h = h;
  return c.u;
}

// raw v_exp_f32 (2^x) — libm exp2f takes the slow OCML fixup path
__device__ __forceinline__ float ex2(float x) {
  float r;
  asm("v_exp_f32 %0, %1" : "=v"(r) : "v"(x));
  return r;
}

__device__ __forceinline__ void gload_lds16(const void* g, void* l) {
  __builtin_amdgcn_global_load_lds(
      (const __attribute__((address_space(1))) void*)g,
      (__attribute__((address_space(3))) void*)l, 16, 0, 0);
}

// ---------------- elementwise converts / relayouts ----------------

__global__ void cvt_bf16_kernel(const float* __restrict__ src,
                                unsigned short* __restrict__ dst, int n4) {
  int i = blockIdx.x * blockDim.x + threadIdx.x;
  if (i >= n4) return;
  float4 v = ((const float4*)src)[i];
  unsigned long long pk =
      (unsigned long long)f2bf(v.x) |
      ((unsigned long long)f2bf(v.y) << 16) |
      ((unsigned long long)f2bf(v.z) << 32) |
      ((unsigned long long)f2bf(v.w) << 48);
  *(unsigned long long*)(dst + (size_t)i * 4) = pk;
}

// src fp32 [R][C]  ->  dst bf16 [C][R]
__global__ void transpose_cvt_kernel(const float* __restrict__ src,
                                     unsigned short* __restrict__ dst,
                                     int R, int C) {
  __shared__ float tile[32][33];
  int c0 = blockIdx.x * 32, r0 = blockIdx.y * 32;
  int tx = threadIdx.x, ty = threadIdx.y;
#pragma unroll
  for (int k = 0; k < 4; ++k)
    tile[ty + 8 * k][tx] = src[(size_t)(r0 + ty + 8 * k) * C + c0 + tx];
  __syncthreads();
#pragma unroll
  for (int k = 0; k < 4; ++k)
    dst[(size_t)(c0 + ty + 8 * k) * R + r0 + tx] = f2bf(tile[tx][ty + 8 * k]);
}

__global__ void concat_bias_kernel(const float* __restrict__ bq,
                                   const float* __restrict__ bk,
                                   const float* __restrict__ bv,
                                   float* __restrict__ dst) {
  int i = blockIdx.x * 256 + threadIdx.x;
  if (i < 2048) dst[i] = bq[i];
  else if (i < 2560) dst[i] = bk[i - 2048];
  else if (i < 3072) dst[i] = bv[i - 2560];
}

#define L2_10000 13.2877123795494f
#define QSCALE_  0.18033688011112043f   // 0.125 * log2(e) -> softmax in exp2

// QKVlin bf16 [4096][3072] -> Qh bf16 [b][h][t][64] with RoPE; QSCALE folded.
__global__ void rope_q_kernel(const unsigned short* __restrict__ qkv,
                              unsigned short* __restrict__ Qh) {
  int idx = blockIdx.x * 256 + threadIdx.x;   // B*T*NQ*32
  int i  = idx & 31;
  int h  = (idx >> 5) & 31;
  int bt = idx >> 10;
  int t  = bt & (T_ - 1);
  int b  = bt >> 11;
  float invf = exp2f(-(float)i * (L2_10000 / 32.f));
  float ang = (float)t * invf;
  float s, c; sincosf(ang, &s, &c);
  const unsigned short* row = qkv + (size_t)bt * NTOT_ + h * 64;
  float x1 = bf2f(row[i]), x2 = bf2f(row[i + 32]);
  unsigned short* q = Qh + ((size_t)(b * NQ_ + h) * T_ + t) * HEAD_;
  q[i]      = f2bf((x1 * c - x2 * s) * QSCALE_);
  q[i + 32] = f2bf((x2 * c + x1 * s) * QSCALE_);
}

__global__ void rope_k_kernel(const unsigned short* __restrict__ qkv,
                              unsigned short* __restrict__ Kh) {
  int idx = blockIdx.x * 256 + threadIdx.x;   // B*T*NKV*32
  int i  = idx & 31;
  int kh = (idx >> 5) & 7;
  int bt = idx >> 8;
  int t  = bt & (T_ - 1);
  int b  = bt >> 11;
  float invf = exp2f(-(float)i * (L2_10000 / 32.f));
  float ang = (float)t * invf;
  float s, c; sincosf(ang, &s, &c);
  const unsigned short* row = qkv + (size_t)bt * NTOT_ + 2048 + kh * 64;
  float x1 = bf2f(row[i]), x2 = bf2f(row[i + 32]);
  unsigned short* kp = Kh + ((size_t)(b * NKV_ + kh) * T_ + t) * HEAD_;
  kp[i]      = f2bf(x1 * c - x2 * s);
  kp[i + 32] = f2bf(x2 * c + x1 * s);
}

// V (bf16 in QKVlin) -> Vt bf16 [b][kh][d][t]
__global__ void vt_kernel(const unsigned short* __restrict__ qkv,
                          unsigned short* __restrict__ Vt) {
  int idx = blockIdx.x * 256 + threadIdx.x;   // B*NKV*HEAD*T
  int t  = idx & (T_ - 1);
  int d  = (idx >> 11) & 63;
  int kh = (idx >> 17) & 7;
  int b  = idx >> 20;
  Vt[((size_t)((b * NKV_ + kh) * 64 + d)) * T_ + t] =
      qkv[(size_t)(b * T_ + t) * NTOT_ + 2560 + kh * 64 + d];
}

// ---------------- QKV GEMM: 128x192 tile, 3-phase, K=2048 (round-7) ----------------

__launch_bounds__(512, 4)
__global__ void gemm_qkv_3ph(const unsigned short* __restrict__ A,
                             const unsigned short* __restrict__ BT,
                             const float* __restrict__ bias,
                             unsigned short* __restrict__ C) {
  __shared__ unsigned short sh[2 * 20480];   // 80 KiB
  const int tid = threadIdx.x;
  const int lane = tid & 63, l16 = lane & 15, lg = lane >> 4;
  const int wave = tid >> 6, wm = wave >> 2, wn = wave & 3;
  const int bid = blockIdx.x;
  const int sw = (bid & 7) * 64 + (bid >> 3);
  const int mt = sw & 31, nt = sw >> 5;
  const int m0 = mt * 128, n0 = nt * 192;
  const int arow = tid >> 3;
  const int usrc = (tid & 7) ^ (arow & 7);
  const int swz = l16 & 7;
  const int uo0 = (lg ^ swz) << 3;
  const int uo1 = ((4 + lg) ^ swz) << 3;

  f32x4 acc[4][3];
#pragma unroll
  for (int i = 0; i < 4; ++i)
#pragma unroll
    for (int j = 0; j < 3; ++j) acc[i][j] = (f32x4){0.f, 0.f, 0.f, 0.f};

  auto STG = [&](int u) {
    if (u >= 5 * NK_) return;
    const int kt = u / 5, j = u % 5;
    char* bufb = (char*)sh + (kt & 1) * 40960;
    if (j < 2) {
      gload_lds16(A + (size_t)(m0 + j * 64 + arow) * 2048 + kt * 64 + usrc * 8,
                  bufb + j * 8192 + tid * 16);
    } else {
      const int jj = j - 2;
      gload_lds16(BT + (size_t)(n0 + jj * 64 + arow) * 2048 + kt * 64 + usrc * 8,
                  bufb + 16384 + jj * 8192 + tid * 16);
    }
  };

#pragma unroll
  for (int u = 0; u < 7; ++u) STG(u);
  asm volatile("s_waitcnt vmcnt(2)" ::: "memory");
  __builtin_amdgcn_s_barrier();

  for (int t = 0; t < NK_; ++t) {
    const unsigned short* Ab = sh + (t & 1) * 20480;
    const unsigned short* Bb = Ab + 8192;

    bf16x8 af[4][2], bfr[2];
#pragma unroll
    for (int fi = 0; fi < 4; ++fi) {
      const int ro = (fi * 32 + wm * 16 + l16) * 64;
      af[fi][0] = *(const bf16x8*)(Ab + ro + uo0);
      af[fi][1] = *(const bf16x8*)(Ab + ro + uo1);
    }
    {
      const int ro = (wn * 16 + l16) * 64;
      bfr[0] = *(const bf16x8*)(Bb + ro + uo0);
      bfr[1] = *(const bf16x8*)(Bb + ro + uo1);
    }
    STG(7 + 5 * t);  STG(8 + 5 * t);
    __builtin_amdgcn_s_barrier();
    asm volatile("s_waitcnt lgkmcnt(0)" ::: "memory");
    __builtin_amdgcn_sched_barrier(0);
    __builtin_amdgcn_s_setprio(1);
#pragma unroll
    for (int fi = 0; fi < 4; ++fi) {
      acc[fi][0] = MFMA_(af[fi][0], bfr[0], acc[fi][0], 0, 0, 0);
      acc[fi][0] = MFMA_(af[fi][1], bfr[1], acc[fi][0], 0, 0, 0);
    }
    __builtin_amdgcn_s_setprio(0);
    __builtin_amdgcn_s_barrier();

    {
      const int ro = (64 + wn * 16 + l16) * 64;
      bfr[0] = *(const bf16x8*)(Bb + ro + uo0);
      bfr[1] = *(const bf16x8*)(Bb + ro + uo1);
    }
    STG(9 + 5 * t);  STG(10 + 5 * t);
    __builtin_amdgcn_s_barrier();
    asm volatile("s_waitcnt lgkmcnt(0)" ::: "memory");
    __builtin_amdgcn_sched_barrier(0);
    __builtin_amdgcn_s_setprio(1);
#pragma unroll
    for (int fi = 0; fi < 4; ++fi) {
      acc[fi][1] = MFMA_(af[fi][0], bfr[0], acc[fi][1], 0, 0, 0);
      acc[fi][1] = MFMA_(af[fi][1], bfr[1], acc[fi][1], 0, 0, 0);
    }
    __builtin_amdgcn_s_setprio(0);
    __builtin_amdgcn_s_barrier();

    {
      const int ro = (128 + wn * 16 + l16) * 64;
      bfr[0] = *(const bf16x8*)(Bb + ro + uo0);
      bfr[1] = *(const bf16x8*)(Bb + ro + uo1);
    }
    STG(11 + 5 * t);
    __builtin_amdgcn_s_barrier();
    asm volatile("s_waitcnt lgkmcnt(0)" ::: "memory");
    __builtin_amdgcn_sched_barrier(0);
    __builtin_amdgcn_s_setprio(1);
#pragma unroll
    for (int fi = 0; fi < 4; ++fi) {
      acc[fi][2] = MFMA_(af[fi][0], bfr[0], acc[fi][2], 0, 0, 0);
      acc[fi][2] = MFMA_(af[fi][1], bfr[1], acc[fi][2], 0, 0, 0);
    }
    __builtin_amdgcn_s_setprio(0);
    if (t < NK_ - 2)       asm volatile("s_waitcnt vmcnt(2)" ::: "memory");
    else if (t == NK_ - 2) asm volatile("s_waitcnt vmcnt(0)" ::: "memory");
    __builtin_amdgcn_s_barrier();
  }

#pragma unroll
  for (int fj = 0; fj < 3; ++fj) {
    const int col = n0 + fj * 64 + wn * 16 + l16;
    const float bv = bias[col];
#pragma unroll
    for (int fi = 0; fi < 4; ++fi) {
      const int row0 = m0 + fi * 32 + wm * 16 + lg * 4;
#pragma unroll
      for (int r = 0; r < 4; ++r)
        C[(size_t)(row0 + r) * NTOT_ + col] = f2bf(acc[fi][fj][r] + bv);
    }
  }
}

// ---------------- out GEMM: 128x256 tile, 2-phase, K=2048 (round-7) ----------------

__launch_bounds__(512, 2)
__global__ void gemm_o_2ph(const unsigned short* __restrict__ A,
                           const unsigned short* __restrict__ BT,
                           const float* __restrict__ bias,
                           float* __restrict__ C) {
  __shared__ unsigned short sh[2 * 24576];   // 96 KiB
  const int tid = threadIdx.x;
  const int lane = tid & 63, l16 = lane & 15, lg = lane >> 4;
  const int wave = tid >> 6, wm = wave >> 2, wn = wave & 3;
  const int bid = blockIdx.x;
  const int sw = (bid & 7) * 32 + (bid >> 3);
  const int mt = sw & 31, nt = sw >> 5;
  const int m0 = mt * 128, n0 = nt * 256;
  const int arow = tid >> 3;
  const int usrc = (tid & 7) ^ (arow & 7);
  const int swz = l16 & 7;
  const int uo0 = (lg ^ swz) << 3;
  const int uo1 = ((4 + lg) ^ swz) << 3;

  f32x4 acc[4][4];
#pragma unroll
  for (int i = 0; i < 4; ++i)
#pragma unroll
    for (int j = 0; j < 4; ++j) acc[i][j] = (f32x4){0.f, 0.f, 0.f, 0.f};

  auto STG = [&](int u) {
    if (u >= 6 * NK_) return;
    const int kt = u / 6, j = u % 6;
    char* bufb = (char*)sh + (kt & 1) * 49152;
    if (j < 2) {
      gload_lds16(A + (size_t)(m0 + j * 64 + arow) * 2048 + kt * 64 + usrc * 8,
                  bufb + j * 8192 + tid * 16);
    } else {
      const int jj = j - 2;
      gload_lds16(BT + (size_t)(n0 + jj * 64 + arow) * 2048 + kt * 64 + usrc * 8,
                  bufb + 16384 + jj * 8192 + tid * 16);
    }
  };

#pragma unroll
  for (int u = 0; u < 9; ++u) STG(u);
  asm volatile("s_waitcnt vmcnt(3)" ::: "memory");
  __builtin_amdgcn_s_barrier();

  for (int t = 0; t < NK_; ++t) {
    const unsigned short* Ab = sh + (t & 1) * 24576;
    const unsigned short* Bb = Ab + 8192;

    bf16x8 af[4][2], bfr[2][2];
#pragma unroll
    for (int fi = 0; fi < 4; ++fi) {
      const int ro = (fi * 32 + wm * 16 + l16) * 64;
      af[fi][0] = *(const bf16x8*)(Ab + ro + uo0);
      af[fi][1] = *(const bf16x8*)(Ab + ro + uo1);
    }
#pragma unroll
    for (int fj = 0; fj < 2; ++fj) {
      const int ro = (fj * 64 + wn * 16 + l16) * 64;
      bfr[fj][0] = *(const bf16x8*)(Bb + ro + uo0);
      bfr[fj][1] = *(const bf16x8*)(Bb + ro + uo1);
    }
    STG(9 + 6 * t);  STG(10 + 6 * t);  STG(11 + 6 * t);
    __builtin_amdgcn_s_barrier();
    asm volatile("s_waitcnt lgkmcnt(0)" ::: "memory");
    __builtin_amdgcn_sched_barrier(0);
    __builtin_amdgcn_s_setprio(1);
#pragma unroll
    for (int fi = 0; fi < 4; ++fi)
#pragma unroll
      for (int fj = 0; fj < 2; ++fj) {
        acc[fi][fj] = MFMA_(af[fi][0], bfr[fj][0], acc[fi][fj], 0, 0, 0);
        acc[fi][fj] = MFMA_(af[fi][1], bfr[fj][1], acc[fi][fj], 0, 0, 0);
      }
    __builtin_amdgcn_s_setprio(0);
    __builtin_amdgcn_s_barrier();

#pragma unroll
    for (int fj = 0; fj < 2; ++fj) {
      const int ro = ((2 + fj) * 64 + wn * 16 + l16) * 64;
      bfr[fj][0] = *(const bf16x8*)(Bb + ro + uo0);
      bfr[fj][1] = *(const bf16x8*)(Bb + ro + uo1);
    }
    STG(12 + 6 * t);  STG(13 + 6 * t);  STG(14 + 6 * t);
    __builtin_amdgcn_s_barrier();
    asm volatile("s_waitcnt lgkmcnt(0)" ::: "memory");
    __builtin_amdgcn_sched_barrier(0);
    __builtin_amdgcn_s_setprio(1);
#pragma unroll
    for (int fi = 0; fi < 4; ++fi)
#pragma unroll
      for (int fj = 0; fj < 2; ++fj) {
        acc[fi][2 + fj] = MFMA_(af[fi][0], bfr[fj][0], acc[fi][2 + fj], 0, 0, 0);
        acc[fi][2 + fj] = MFMA_(af[fi][1], bfr[fj][1], acc[fi][2 + fj], 0, 0, 0);
      }
    __builtin_amdgcn_s_setprio(0);
    if (t < NK_ - 2)       asm volatile("s_waitcnt vmcnt(3)" ::: "memory");
    else if (t == NK_ - 2) asm volatile("s_waitcnt vmcnt(0)" ::: "memory");
    __builtin_amdgcn_s_barrier();
  }

#pragma unroll
  for (int fj = 0; fj < 4; ++fj) {
    const int col = n0 + fj * 64 + wn * 16 + l16;
    const float bv = bias[col];
#pragma unroll
    for (int fi = 0; fi < 4; ++fi) {
      const int row0 = m0 + fi * 32 + wm * 16 + lg * 4;
#pragma unroll
      for (int r = 0; r < 4; ++r)
        C[(size_t)(row0 + r) * EMB_ + col] = acc[fi][fj][r] + bv;
    }
  }
}

// ---------------- flash attention: QBLK=64, 4 blocks/CU ----------------
// grid (16, NQ, B); block handles q-tiles x and 31-x (33 KV-tiles, balanced).
// 4 waves x 16 q rows. LDS 40KB -> 4 blocks/CU (vs 2 grid-limited before).

__launch_bounds__(256, 2)
__global__ void flash_attn_kernel(const unsigned short* __restrict__ Qh,
                                  const unsigned short* __restrict__ Kh,
                                  const unsigned short* __restrict__ Vt,
                                  unsigned short* __restrict__ Y) {
  __shared__ unsigned short Klds[2][64 * 64];
  __shared__ unsigned short Vlds[2][64 * 64];
  __shared__ unsigned short Plds[4][16 * 64];
  const int tid = threadIdx.x;
  const int wave = tid >> 6, lane = tid & 63;
  const int l16 = lane & 15, lg = lane >> 4;
  const int h = blockIdx.y, b = blockIdx.z;
  const int kh = h >> 2;

  const size_t kbase = (size_t)(b * NKV_ + kh) * T_ * HEAD_;
  const size_t vbase = (size_t)(b * NKV_ + kh) * HEAD_ * T_;
  const int srow = tid >> 3;
  const int csrc = (tid & 7) ^ (srow & 7);
  unsigned short* pl = Plds[wave];
  const f32x4 zero4 = {0.f, 0.f, 0.f, 0.f};
  const short one_bf = (short)0x3F80;
  const bf16x8 onesv = {one_bf, one_bf, one_bf, one_bf,
                        one_bf, one_bf, one_bf, one_bf};

#define STAGE(bi, kv0) do {                                                         \
    gload_lds16(Kh + kbase + (size_t)((kv0) + srow) * HEAD_ + csrc * 8,             \
                (char*)Klds[bi] + tid * 16);                                        \
    gload_lds16(Kh + kbase + (size_t)((kv0) + srow + 32) * HEAD_ + csrc * 8,        \
                (char*)Klds[bi] + 4096 + tid * 16);                                 \
    gload_lds16(Vt + vbase + (size_t)srow * T_ + (kv0) + csrc * 8,                  \
                (char*)Vlds[bi] + tid * 16);                                        \
    gload_lds16(Vt + vbase + (size_t)(srow + 32) * T_ + (kv0) + csrc * 8,           \
                (char*)Vlds[bi] + 4096 + tid * 16);                                 \
  } while (0)

  for (int seg = 0; seg < 2; ++seg) {
    const int qt = seg ? (31 - (int)blockIdx.x) : (int)blockIdx.x;
    const int q0 = qt * QBLK_;
    const int nt = qt + 1;

    // Q fragments: wave handles rows q0 + wave*16 + {0..15}
    bf16x8 aq0, aq1;
    {
      const unsigned short* qp =
          Qh + ((size_t)(b * NQ_ + h) * T_ + q0 + wave * 16 + l16) * HEAD_;
      aq0 = *(const bf16x8*)(qp + lg * 8);
      aq1 = *(const bf16x8*)(qp + 32 + lg * 8);
    }

    f32x4 oacc[4];
    f32x4 lsum = zero4;
#pragma unroll
    for (int df = 0; df < 4; ++df) oacc[df] = zero4;
    float mreg = -1e30f;

    STAGE(0, 0);

    for (int t = 0; t < nt; ++t) {
      if (t + 1 < nt) {
        STAGE((t + 1) & 1, (t + 1) * 64);
        asm volatile("s_waitcnt vmcnt(4)" ::: "memory");
      } else {
        asm volatile("s_waitcnt vmcnt(0)" ::: "memory");
      }
      __builtin_amdgcn_s_barrier();
      __builtin_amdgcn_sched_barrier(0);

      const unsigned short* Kb = Klds[t & 1];
      const unsigned short* Vb = Vlds[t & 1];
      const int kv0 = t * 64;

      // ---- S^T = K Q^T : lane owns q=l16, kv=cf*16+lg*4+r ----
      float p[4][4];
#pragma unroll
      for (int cf = 0; cf < 4; ++cf) {
        const int krow = cf * 16 + l16;
        const bf16x8 k0 = *(const bf16x8*)(Kb + krow * 64 + ((lg ^ (krow & 7)) << 3));
        const bf16x8 k1 = *(const bf16x8*)(Kb + krow * 64 + (((4 + lg) ^ (krow & 7)) << 3));
        f32x4 z = zero4;
        z = MFMA_(k0, aq0, z, 0, 0, 0);
        z = MFMA_(k1, aq1, z, 0, 0, 0);
#pragma unroll
        for (int r = 0; r < 4; ++r) p[cf][r] = z[r];
      }

      // causal mask only on the final (diagonal) tile
      if (t == nt - 1) {
        const int qg = q0 + wave * 16 + l16;
#pragma unroll
        for (int cf = 0; cf < 4; ++cf)
#pragma unroll
          for (int r = 0; r < 4; ++r)
            if (kv0 + cf * 16 + lg * 4 + r > qg) p[cf][r] = -1e30f;
      }

      // ---- tile max ----
      float m = mreg;
#pragma unroll
      for (int cf = 0; cf < 4; ++cf) {
        m = fmaxf(m, fmaxf(p[cf][0], p[cf][1]));
        m = fmaxf(m, fmaxf(p[cf][2], p[cf][3]));
      }
      m = fmaxf(m, __shfl_xor(m, 16, 64));
      m = fmaxf(m, __shfl_xor(m, 32, 64));

      // ---- T13: rescale only when max grew past THR ----
      if (!__all(m - mreg <= 8.f)) {
        const float corr = ex2(mreg - m);
        mreg = m;
        lsum[0] *= corr;
#pragma unroll
        for (int df = 0; df < 4; ++df)
#pragma unroll
          for (int r = 0; r < 4; ++r) oacc[df][r] *= corr;
      }

      // ---- exp ----
#pragma unroll
      for (int cf = 0; cf < 4; ++cf)
#pragma unroll
        for (int r = 0; r < 4; ++r)
          p[cf][r] = ex2(p[cf][r] - mreg);

      // ---- P -> LDS (swizzled b64), read back as B-frags ----
      const int row = l16;
#pragma unroll
      for (int cf = 0; cf < 4; ++cf) {
        const unsigned int w0 = pk_bf16(p[cf][0], p[cf][1]);
        const unsigned int w1 = pk_bf16(p[cf][2], p[cf][3]);
        const int u = cf * 2 + (lg >> 1);
        char* ad = (char*)pl + row * 128 + ((u ^ (row & 7)) << 4) + ((lg & 1) << 3);
        *(unsigned long long*)ad =
            (unsigned long long)w0 | ((unsigned long long)w1 << 32);
      }
      bf16x8 pf[2];
#pragma unroll
      for (int k2 = 0; k2 < 2; ++k2) {
        const int u = k2 * 4 + lg;
        pf[k2] = *(const bf16x8*)((char*)pl + row * 128 + ((u ^ (row & 7)) << 4));
      }

      // ---- row-sum via ones-MFMA; O^T += V^T P^T ----
      lsum = MFMA_(onesv, pf[0], lsum, 0, 0, 0);
      lsum = MFMA_(onesv, pf[1], lsum, 0, 0, 0);
#pragma unroll
      for (int df = 0; df < 4; ++df) {
        const int vrow = df * 16 + l16;
        const bf16x8 v0 = *(const bf16x8*)(Vb + vrow * 64 + ((lg ^ (vrow & 7)) << 3));
        const bf16x8 v1 = *(const bf16x8*)(Vb + vrow * 64 + (((4 + lg) ^ (vrow & 7)) << 3));
        oacc[df] = MFMA_(v0, pf[0], oacc[df], 0, 0, 0);
        oacc[df] = MFMA_(v1, pf[1], oacc[df], 0, 0, 0);
      }

      asm volatile("s_waitcnt lgkmcnt(0)" ::: "memory");
      __builtin_amdgcn_sched_barrier(0);
      __builtin_amdgcn_s_barrier();
    }

    // ---- epilogue: lsum[0] holds the full row sum ----
    {
      const float inv = 1.f / lsum[0];
      const int tq = q0 + wave * 16 + l16;
      unsigned short* yp = Y + ((size_t)(b * T_ + tq)) * EMB_ + h * HEAD_;
#pragma unroll
      for (int df = 0; df < 4; ++df) {
        const unsigned int w0 = pk_bf16(oacc[df][0] * inv, oacc[df][1] * inv);
        const unsigned int w1 = pk_bf16(oacc[df][2] * inv, oacc[df][3] * inv);
        *(unsigned long long*)(yp + df * 16 + lg * 4) =
            (unsigned long long)w0 | ((unsigned long long)w1 << 32);
      }
    }
  }
#undef STAGE
}

// ---------------- launch ----------------

extern "C" void kernel_launch(void* const* d_in, const int* in_sizes, int n_in,
                              void* d_out, int out_size, void* d_ws, size_t ws_size,
                              hipStream_t stream) {
  const float* x  = (const float*)d_in[0];
  const float* Wq = (const float*)d_in[1];
  const float* bq = (const float*)d_in[2];
  const float* Wk = (const float*)d_in[3];
  const float* bk = (const float*)d_in[4];
  const float* Wv = (const float*)d_in[5];
  const float* bv = (const float*)d_in[6];
  const float* Wo = (const float*)d_in[7];
  const float* bo = (const float*)d_in[8];
  float* out = (float*)d_out;

  char* ws = (char*)d_ws;
  size_t off = 0;
  auto alloc = [&](size_t bytes) {
    void* p = ws + off;
    off += (bytes + 255) & ~(size_t)255;
    return p;
  };
  unsigned short* xb     = (unsigned short*)alloc((size_t)M_ * EMB_ * 2);
  unsigned short* WqkvT  = (unsigned short*)alloc((size_t)NTOT_ * EMB_ * 2);
  unsigned short* WoT    = (unsigned short*)alloc((size_t)EMB_ * EMB_ * 2);
  float*          bcat   = (float*)alloc((size_t)NTOT_ * 4);
  unsigned short* QKVlin = (unsigned short*)alloc((size_t)M_ * NTOT_ * 2);
  unsigned short* Qh     = (unsigned short*)alloc((size_t)B_ * NQ_ * T_ * HEAD_ * 2);
  unsigned short* Kh     = (unsigned short*)alloc((size_t)B_ * NKV_ * T_ * HEAD_ * 2);
  unsigned short* Vt     = (unsigned short*)alloc((size_t)B_ * NKV_ * HEAD_ * T_ * 2);
  unsigned short* Yb     = (unsigned short*)alloc((size_t)M_ * EMB_ * 2);

  cvt_bf16_kernel<<<(M_ * EMB_ / 4 + 255) / 256, 256, 0, stream>>>(x, xb, M_ * EMB_ / 4);

  dim3 tb(32, 8);
  transpose_cvt_kernel<<<dim3(EMB_ / 32, EMB_ / 32), tb, 0, stream>>>(Wq, WqkvT, EMB_, EMB_);
  transpose_cvt_kernel<<<dim3(512 / 32, EMB_ / 32), tb, 0, stream>>>(Wk, WqkvT + (size_t)2048 * 2048, EMB_, 512);
  transpose_cvt_kernel<<<dim3(512 / 32, EMB_ / 32), tb, 0, stream>>>(Wv, WqkvT + (size_t)2560 * 2048, EMB_, 512);
  transpose_cvt_kernel<<<dim3(EMB_ / 32, EMB_ / 32), tb, 0, stream>>>(Wo, WoT, EMB_, EMB_);
  concat_bias_kernel<<<(NTOT_ + 255) / 256, 256, 0, stream>>>(bq, bk, bv, bcat);

  // QKV projection: 128x192 3-phase, 512 blocks, bf16 out
  gemm_qkv_3ph<<<512, 512, 0, stream>>>(xb, WqkvT, bcat, QKVlin);

  rope_q_kernel<<<(B_ * T_ * NQ_ * 32) / 256, 256, 0, stream>>>(QKVlin, Qh);
  rope_k_kernel<<<(B_ * T_ * NKV_ * 32) / 256, 256, 0, stream>>>(QKVlin, Kh);
  vt_kernel<<<(B_ * NKV_ * HEAD_ * T_) / 256, 256, 0, stream>>>(QKVlin, Vt);

  // flash attention: QBLK=64, paired (x, 31-x), 1024 blocks = 4/CU
  flash_attn_kernel<<<dim3(16, NQ_, B_), 256, 0, stream>>>(Qh, Kh, Vt, Yb);

  // output projection: 128x256 2-phase, 256 blocks, fp32 out
  gemm_o_2ph<<<256, 512, 0, stream>>>(Yb, WoT, bo, out);

  (void)in_sizes; (void)n_in; (void)out_size; (void)ws_size;
}

// Round 13
// 210.395 us; speedup vs baseline: 1.3196x; 1.0467x over previous
//
#include <hip/hip_runtime.h>
#include <hip/hip_bf16.h>
#include <cstdint>
#include <cstddef>

typedef __attribute__((ext_vector_type(4))) float f32x4;
typedef __attribute__((ext_vector_type(8))) short bf16x8;

#define B_    2
#define T_    2048
#define EMB_  2048
#define NQ_   32
#define NKV_  8
#define HEAD_ 64
#define NTOT_ 3072
#define M_    (B_ * T_)     // 4096
#define QBLK_ 64
#define NK_   32            // K=2048 / BK=64

#define MFMA_ __builtin_amdgcn_mfma_f32_16x16x32_bf16

__device__ __forceinline__ unsigned short f2bf(float f) {
  union { float f; unsigned int u; } v; v.f = f;
  unsigned int r = v.u + 0x7fffu + ((v.u >> 16) & 1u);
  return (unsigned short)(r >> 16);
}

__device__ __forceinline__ float bf2f(unsigned short u) {
  union { unsigned int u; float f; } v; v.u = (unsigned int)u << 16; return v.f;
}

__device__ __forceinline__ unsigned int pk_bf16(float lo, float hi) {
  __hip_bfloat162 h = __float22bfloat162_rn(make_float2(lo, hi));
  union { __hip_bfloat162 h; unsigned int u; } c; c.h = h;
  return c.u;
}

// raw v_exp_f32 (2^x) — libm exp2f takes the slow OCML fixup path
__device__ __forceinline__ float ex2(float x) {
  float r;
  asm("v_exp_f32 %0, %1" : "=v"(r) : "v"(x));
  return r;
}

__device__ __forceinline__ void gload_lds16(const void* g, void* l) {
  __builtin_amdgcn_global_load_lds(
      (const __attribute__((address_space(1))) void*)g,
      (__attribute__((address_space(3))) void*)l, 16, 0, 0);
}

// ---------------- prep kernels (consolidated) ----------------

__global__ void cvt_bf16_kernel(const float* __restrict__ src,
                                unsigned short* __restrict__ dst, int n4) {
  int i = blockIdx.x * blockDim.x + threadIdx.x;
  if (i >= n4) return;
  float4 v = ((const float4*)src)[i];
  unsigned long long pk =
      (unsigned long long)f2bf(v.x) |
      ((unsigned long long)f2bf(v.y) << 16) |
      ((unsigned long long)f2bf(v.z) << 32) |
      ((unsigned long long)f2bf(v.w) << 48);
  *(unsigned long long*)(dst + (size_t)i * 4) = pk;
}

#define L2_10000 13.2877123795494f
#define QSCALE_  0.18033688011112043f   // 0.125 * log2(e) -> softmax in exp2

// cos/sin table: tab[t][i] for t in [0,2048), i in [0,32)
__global__ void cs_table_kernel(float2* __restrict__ tab) {
  int idx = blockIdx.x * 256 + threadIdx.x;   // 65536
  int t = idx >> 5, i = idx & 31;
  float invf = exp2f(-(float)i * (L2_10000 / 32.f));
  float ang = (float)t * invf;
  float s, c; sincosf(ang, &s, &c);
  tab[idx] = make_float2(c, s);
}

// All 4 weight transposes (fp32 [R][C] -> bf16 [C][R]) + bias concat, 1 launch.
__global__ void prep_weights_kernel(const float* __restrict__ Wq,
                                    const float* __restrict__ Wk,
                                    const float* __restrict__ Wv,
                                    const float* __restrict__ Wo,
                                    const float* __restrict__ bq,
                                    const float* __restrict__ bk,
                                    const float* __restrict__ bv,
                                    unsigned short* __restrict__ WqkvT,
                                    unsigned short* __restrict__ WoT,
                                    float* __restrict__ bcat) {
  const int bid = blockIdx.x;
  const int tx = threadIdx.x & 31, ty = threadIdx.x >> 5;   // 256 thr = (32,8)
  if (bid >= 10240) {   // bias concat
    const int t0 = threadIdx.x;
#pragma unroll
    for (int k = 0; k < 12; ++k) {
      const int i = k * 256 + t0;
      float v;
      if (i < 2048) v = bq[i];
      else if (i < 2560) v = bk[i - 2048];
      else v = bv[i - 2560];
      bcat[i] = v;
    }
    return;
  }
  const float* src;
  unsigned short* dst;
  int C, local;
  if (bid < 4096)      { src = Wq; dst = WqkvT;                          C = 2048; local = bid; }
  else if (bid < 5120) { src = Wk; dst = WqkvT + (size_t)2048 * 2048;    C = 512;  local = bid - 4096; }
  else if (bid < 6144) { src = Wv; dst = WqkvT + (size_t)2560 * 2048;    C = 512;  local = bid - 5120; }
  else                 { src = Wo; dst = WoT;                            C = 2048; local = bid - 6144; }
  const int tilesx = C >> 5;
  const int c0 = (local % tilesx) * 32, r0 = (local / tilesx) * 32;

  __shared__ float tile[32][33];
#pragma unroll
  for (int k = 0; k < 4; ++k)
    tile[ty + 8 * k][tx] = src[(size_t)(r0 + ty + 8 * k) * C + c0 + tx];
  __syncthreads();
#pragma unroll
  for (int k = 0; k < 4; ++k)
    dst[(size_t)(c0 + ty + 8 * k) * 2048 + r0 + tx] = f2bf(tile[tx][ty + 8 * k]);
}

// Fused RoPE(Q) + RoPE(K) + V-relayout, one pass over QKVlin (bf16), 1 launch.
// Segment 0: idx < 4194304             -> Q rope (B*T*NQ*32)
// Segment 1: 4194304 <= idx < 5242880  -> K rope (B*T*NKV*32 = 1048576)
// Segment 2: 5242880 <= idx < 7340032  -> V relayout (B*NKV*HEAD*T = 2097152)
__global__ void rope_fused_kernel(const unsigned short* __restrict__ qkv,
                                  const float2* __restrict__ tab,
                                  unsigned short* __restrict__ Qh,
                                  unsigned short* __restrict__ Kh,
                                  unsigned short* __restrict__ Vt) {
  int idx = blockIdx.x * 256 + threadIdx.x;
  if (idx < 4194304) {
    int i  = idx & 31;
    int h  = (idx >> 5) & 31;
    int bt = idx >> 10;
    int t  = bt & (T_ - 1);
    int b  = bt >> 11;
    float2 cs = tab[(t << 5) + i];
    const unsigned short* row = qkv + (size_t)bt * NTOT_ + h * 64;
    float x1 = bf2f(row[i]), x2 = bf2f(row[i + 32]);
    unsigned short* q = Qh + ((size_t)(b * NQ_ + h) * T_ + t) * HEAD_;
    q[i]      = f2bf((x1 * cs.x - x2 * cs.y) * QSCALE_);
    q[i + 32] = f2bf((x2 * cs.x + x1 * cs.y) * QSCALE_);
  } else if (idx < 5242880) {
    int j  = idx - 4194304;
    int i  = j & 31;
    int kh = (j >> 5) & 7;
    int bt = j >> 8;
    int t  = bt & (T_ - 1);
    int b  = bt >> 11;
    float2 cs = tab[(t << 5) + i];
    const unsigned short* row = qkv + (size_t)bt * NTOT_ + 2048 + kh * 64;
    float x1 = bf2f(row[i]), x2 = bf2f(row[i + 32]);
    unsigned short* kp = Kh + ((size_t)(b * NKV_ + kh) * T_ + t) * HEAD_;
    kp[i]      = f2bf(x1 * cs.x - x2 * cs.y);
    kp[i + 32] = f2bf(x2 * cs.x + x1 * cs.y);
  } else {
    int j  = idx - 5242880;   // 0 .. 2097151
    int t  = j & (T_ - 1);
    int d  = (j >> 11) & 63;
    int kh = (j >> 17) & 7;
    int b  = j >> 20;
    Vt[((size_t)((b * NKV_ + kh) * 64 + d)) * T_ + t] =
        qkv[(size_t)(b * T_ + t) * NTOT_ + 2560 + kh * 64 + d];
  }
}

// ---------------- QKV GEMM: 128x192 tile, 3-phase, K=2048 ----------------

__launch_bounds__(512, 4)
__global__ void gemm_qkv_3ph(const unsigned short* __restrict__ A,
                             const unsigned short* __restrict__ BT,
                             const float* __restrict__ bias,
                             unsigned short* __restrict__ C) {
  __shared__ unsigned short sh[2 * 20480];   // 80 KiB
  const int tid = threadIdx.x;
  const int lane = tid & 63, l16 = lane & 15, lg = lane >> 4;
  const int wave = tid >> 6, wm = wave >> 2, wn = wave & 3;
  const int bid = blockIdx.x;
  const int sw = (bid & 7) * 64 + (bid >> 3);
  const int mt = sw & 31, nt = sw >> 5;
  const int m0 = mt * 128, n0 = nt * 192;
  const int arow = tid >> 3;
  const int usrc = (tid & 7) ^ (arow & 7);
  const int swz = l16 & 7;
  const int uo0 = (lg ^ swz) << 3;
  const int uo1 = ((4 + lg) ^ swz) << 3;

  f32x4 acc[4][3];
#pragma unroll
  for (int i = 0; i < 4; ++i)
#pragma unroll
    for (int j = 0; j < 3; ++j) acc[i][j] = (f32x4){0.f, 0.f, 0.f, 0.f};

  auto STG = [&](int u) {
    if (u >= 5 * NK_) return;
    const int kt = u / 5, j = u % 5;
    char* bufb = (char*)sh + (kt & 1) * 40960;
    if (j < 2) {
      gload_lds16(A + (size_t)(m0 + j * 64 + arow) * 2048 + kt * 64 + usrc * 8,
                  bufb + j * 8192 + tid * 16);
    } else {
      const int jj = j - 2;
      gload_lds16(BT + (size_t)(n0 + jj * 64 + arow) * 2048 + kt * 64 + usrc * 8,
                  bufb + 16384 + jj * 8192 + tid * 16);
    }
  };

#pragma unroll
  for (int u = 0; u < 7; ++u) STG(u);
  asm volatile("s_waitcnt vmcnt(2)" ::: "memory");
  __builtin_amdgcn_s_barrier();

  for (int t = 0; t < NK_; ++t) {
    const unsigned short* Ab = sh + (t & 1) * 20480;
    const unsigned short* Bb = Ab + 8192;

    bf16x8 af[4][2], bfr[2];
#pragma unroll
    for (int fi = 0; fi < 4; ++fi) {
      const int ro = (fi * 32 + wm * 16 + l16) * 64;
      af[fi][0] = *(const bf16x8*)(Ab + ro + uo0);
      af[fi][1] = *(const bf16x8*)(Ab + ro + uo1);
    }
    {
      const int ro = (wn * 16 + l16) * 64;
      bfr[0] = *(const bf16x8*)(Bb + ro + uo0);
      bfr[1] = *(const bf16x8*)(Bb + ro + uo1);
    }
    STG(7 + 5 * t);  STG(8 + 5 * t);
    __builtin_amdgcn_s_barrier();
    asm volatile("s_waitcnt lgkmcnt(0)" ::: "memory");
    __builtin_amdgcn_sched_barrier(0);
    __builtin_amdgcn_s_setprio(1);
#pragma unroll
    for (int fi = 0; fi < 4; ++fi) {
      acc[fi][0] = MFMA_(af[fi][0], bfr[0], acc[fi][0], 0, 0, 0);
      acc[fi][0] = MFMA_(af[fi][1], bfr[1], acc[fi][0], 0, 0, 0);
    }
    __builtin_amdgcn_s_setprio(0);
    __builtin_amdgcn_s_barrier();

    {
      const int ro = (64 + wn * 16 + l16) * 64;
      bfr[0] = *(const bf16x8*)(Bb + ro + uo0);
      bfr[1] = *(const bf16x8*)(Bb + ro + uo1);
    }
    STG(9 + 5 * t);  STG(10 + 5 * t);
    __builtin_amdgcn_s_barrier();
    asm volatile("s_waitcnt lgkmcnt(0)" ::: "memory");
    __builtin_amdgcn_sched_barrier(0);
    __builtin_amdgcn_s_setprio(1);
#pragma unroll
    for (int fi = 0; fi < 4; ++fi) {
      acc[fi][1] = MFMA_(af[fi][0], bfr[0], acc[fi][1], 0, 0, 0);
      acc[fi][1] = MFMA_(af[fi][1], bfr[1], acc[fi][1], 0, 0, 0);
    }
    __builtin_amdgcn_s_setprio(0);
    __builtin_amdgcn_s_barrier();

    {
      const int ro = (128 + wn * 16 + l16) * 64;
      bfr[0] = *(const bf16x8*)(Bb + ro + uo0);
      bfr[1] = *(const bf16x8*)(Bb + ro + uo1);
    }
    STG(11 + 5 * t);
    __builtin_amdgcn_s_barrier();
    asm volatile("s_waitcnt lgkmcnt(0)" ::: "memory");
    __builtin_amdgcn_sched_barrier(0);
    __builtin_amdgcn_s_setprio(1);
#pragma unroll
    for (int fi = 0; fi < 4; ++fi) {
      acc[fi][2] = MFMA_(af[fi][0], bfr[0], acc[fi][2], 0, 0, 0);
      acc[fi][2] = MFMA_(af[fi][1], bfr[1], acc[fi][2], 0, 0, 0);
    }
    __builtin_amdgcn_s_setprio(0);
    if (t < NK_ - 2)       asm volatile("s_waitcnt vmcnt(2)" ::: "memory");
    else if (t == NK_ - 2) asm volatile("s_waitcnt vmcnt(0)" ::: "memory");
    __builtin_amdgcn_s_barrier();
  }

#pragma unroll
  for (int fj = 0; fj < 3; ++fj) {
    const int col = n0 + fj * 64 + wn * 16 + l16;
    const float bv = bias[col];
#pragma unroll
    for (int fi = 0; fi < 4; ++fi) {
      const int row0 = m0 + fi * 32 + wm * 16 + lg * 4;
#pragma unroll
      for (int r = 0; r < 4; ++r)
        C[(size_t)(row0 + r) * NTOT_ + col] = f2bf(acc[fi][fj][r] + bv);
    }
  }
}

// ---------------- out GEMM: 128x256 tile, 2-phase, K=2048 ----------------

__launch_bounds__(512, 2)
__global__ void gemm_o_2ph(const unsigned short* __restrict__ A,
                           const unsigned short* __restrict__ BT,
                           const float* __restrict__ bias,
                           float* __restrict__ C) {
  __shared__ unsigned short sh[2 * 24576];   // 96 KiB
  const int tid = threadIdx.x;
  const int lane = tid & 63, l16 = lane & 15, lg = lane >> 4;
  const int wave = tid >> 6, wm = wave >> 2, wn = wave & 3;
  const int bid = blockIdx.x;
  const int sw = (bid & 7) * 32 + (bid >> 3);
  const int mt = sw & 31, nt = sw >> 5;
  const int m0 = mt * 128, n0 = nt * 256;
  const int arow = tid >> 3;
  const int usrc = (tid & 7) ^ (arow & 7);
  const int swz = l16 & 7;
  const int uo0 = (lg ^ swz) << 3;
  const int uo1 = ((4 + lg) ^ swz) << 3;

  f32x4 acc[4][4];
#pragma unroll
  for (int i = 0; i < 4; ++i)
#pragma unroll
    for (int j = 0; j < 4; ++j) acc[i][j] = (f32x4){0.f, 0.f, 0.f, 0.f};

  auto STG = [&](int u) {
    if (u >= 6 * NK_) return;
    const int kt = u / 6, j = u % 6;
    char* bufb = (char*)sh + (kt & 1) * 49152;
    if (j < 2) {
      gload_lds16(A + (size_t)(m0 + j * 64 + arow) * 2048 + kt * 64 + usrc * 8,
                  bufb + j * 8192 + tid * 16);
    } else {
      const int jj = j - 2;
      gload_lds16(BT + (size_t)(n0 + jj * 64 + arow) * 2048 + kt * 64 + usrc * 8,
                  bufb + 16384 + jj * 8192 + tid * 16);
    }
  };

#pragma unroll
  for (int u = 0; u < 9; ++u) STG(u);
  asm volatile("s_waitcnt vmcnt(3)" ::: "memory");
  __builtin_amdgcn_s_barrier();

  for (int t = 0; t < NK_; ++t) {
    const unsigned short* Ab = sh + (t & 1) * 24576;
    const unsigned short* Bb = Ab + 8192;

    bf16x8 af[4][2], bfr[2][2];
#pragma unroll
    for (int fi = 0; fi < 4; ++fi) {
      const int ro = (fi * 32 + wm * 16 + l16) * 64;
      af[fi][0] = *(const bf16x8*)(Ab + ro + uo0);
      af[fi][1] = *(const bf16x8*)(Ab + ro + uo1);
    }
#pragma unroll
    for (int fj = 0; fj < 2; ++fj) {
      const int ro = (fj * 64 + wn * 16 + l16) * 64;
      bfr[fj][0] = *(const bf16x8*)(Bb + ro + uo0);
      bfr[fj][1] = *(const bf16x8*)(Bb + ro + uo1);
    }
    STG(9 + 6 * t);  STG(10 + 6 * t);  STG(11 + 6 * t);
    __builtin_amdgcn_s_barrier();
    asm volatile("s_waitcnt lgkmcnt(0)" ::: "memory");
    __builtin_amdgcn_sched_barrier(0);
    __builtin_amdgcn_s_setprio(1);
#pragma unroll
    for (int fi = 0; fi < 4; ++fi)
#pragma unroll
      for (int fj = 0; fj < 2; ++fj) {
        acc[fi][fj] = MFMA_(af[fi][0], bfr[fj][0], acc[fi][fj], 0, 0, 0);
        acc[fi][fj] = MFMA_(af[fi][1], bfr[fj][1], acc[fi][fj], 0, 0, 0);
      }
    __builtin_amdgcn_s_setprio(0);
    __builtin_amdgcn_s_barrier();

#pragma unroll
    for (int fj = 0; fj < 2; ++fj) {
      const int ro = ((2 + fj) * 64 + wn * 16 + l16) * 64;
      bfr[fj][0] = *(const bf16x8*)(Bb + ro + uo0);
      bfr[fj][1] = *(const bf16x8*)(Bb + ro + uo1);
    }
    STG(12 + 6 * t);  STG(13 + 6 * t);  STG(14 + 6 * t);
    __builtin_amdgcn_s_barrier();
    asm volatile("s_waitcnt lgkmcnt(0)" ::: "memory");
    __builtin_amdgcn_sched_barrier(0);
    __builtin_amdgcn_s_setprio(1);
#pragma unroll
    for (int fi = 0; fi < 4; ++fi)
#pragma unroll
      for (int fj = 0; fj < 2; ++fj) {
        acc[fi][2 + fj] = MFMA_(af[fi][0], bfr[fj][0], acc[fi][2 + fj], 0, 0, 0);
        acc[fi][2 + fj] = MFMA_(af[fi][1], bfr[fj][1], acc[fi][2 + fj], 0, 0, 0);
      }
    __builtin_amdgcn_s_setprio(0);
    if (t < NK_ - 2)       asm volatile("s_waitcnt vmcnt(3)" ::: "memory");
    else if (t == NK_ - 2) asm volatile("s_waitcnt vmcnt(0)" ::: "memory");
    __builtin_amdgcn_s_barrier();
  }

#pragma unroll
  for (int fj = 0; fj < 4; ++fj) {
    const int col = n0 + fj * 64 + wn * 16 + l16;
    const float bv = bias[col];
#pragma unroll
    for (int fi = 0; fi < 4; ++fi) {
      const int row0 = m0 + fi * 32 + wm * 16 + lg * 4;
#pragma unroll
      for (int r = 0; r < 4; ++r)
        C[(size_t)(row0 + r) * EMB_ + col] = acc[fi][fj][r] + bv;
    }
  }
}

// ---------------- flash attention: QBLK=64, 4 blocks/CU ----------------

__launch_bounds__(256, 2)
__global__ void flash_attn_kernel(const unsigned short* __restrict__ Qh,
                                  const unsigned short* __restrict__ Kh,
                                  const unsigned short* __restrict__ Vt,
                                  unsigned short* __restrict__ Y) {
  __shared__ unsigned short Klds[2][64 * 64];
  __shared__ unsigned short Vlds[2][64 * 64];
  __shared__ unsigned short Plds[4][16 * 64];
  const int tid = threadIdx.x;
  const int wave = tid >> 6, lane = tid & 63;
  const int l16 = lane & 15, lg = lane >> 4;
  const int h = blockIdx.y, b = blockIdx.z;
  const int kh = h >> 2;

  const size_t kbase = (size_t)(b * NKV_ + kh) * T_ * HEAD_;
  const size_t vbase = (size_t)(b * NKV_ + kh) * HEAD_ * T_;
  const int srow = tid >> 3;
  const int csrc = (tid & 7) ^ (srow & 7);
  unsigned short* pl = Plds[wave];
  const f32x4 zero4 = {0.f, 0.f, 0.f, 0.f};
  const short one_bf = (short)0x3F80;
  const bf16x8 onesv = {one_bf, one_bf, one_bf, one_bf,
                        one_bf, one_bf, one_bf, one_bf};

#define STAGE(bi, kv0) do {                                                         \
    gload_lds16(Kh + kbase + (size_t)((kv0) + srow) * HEAD_ + csrc * 8,             \
                (char*)Klds[bi] + tid * 16);                                        \
    gload_lds16(Kh + kbase + (size_t)((kv0) + srow + 32) * HEAD_ + csrc * 8,        \
                (char*)Klds[bi] + 4096 + tid * 16);                                 \
    gload_lds16(Vt + vbase + (size_t)srow * T_ + (kv0) + csrc * 8,                  \
                (char*)Vlds[bi] + tid * 16);                                        \
    gload_lds16(Vt + vbase + (size_t)(srow + 32) * T_ + (kv0) + csrc * 8,           \
                (char*)Vlds[bi] + 4096 + tid * 16);                                 \
  } while (0)

  for (int seg = 0; seg < 2; ++seg) {
    const int qt = seg ? (31 - (int)blockIdx.x) : (int)blockIdx.x;
    const int q0 = qt * QBLK_;
    const int nt = qt + 1;

    bf16x8 aq0, aq1;
    {
      const unsigned short* qp =
          Qh + ((size_t)(b * NQ_ + h) * T_ + q0 + wave * 16 + l16) * HEAD_;
      aq0 = *(const bf16x8*)(qp + lg * 8);
      aq1 = *(const bf16x8*)(qp + 32 + lg * 8);
    }

    f32x4 oacc[4];
    f32x4 lsum = zero4;
#pragma unroll
    for (int df = 0; df < 4; ++df) oacc[df] = zero4;
    float mreg = -1e30f;

    STAGE(0, 0);

    for (int t = 0; t < nt; ++t) {
      if (t + 1 < nt) {
        STAGE((t + 1) & 1, (t + 1) * 64);
        asm volatile("s_waitcnt vmcnt(4)" ::: "memory");
      } else {
        asm volatile("s_waitcnt vmcnt(0)" ::: "memory");
      }
      __builtin_amdgcn_s_barrier();
      __builtin_amdgcn_sched_barrier(0);

      const unsigned short* Kb = Klds[t & 1];
      const unsigned short* Vb = Vlds[t & 1];
      const int kv0 = t * 64;

      float p[4][4];
#pragma unroll
      for (int cf = 0; cf < 4; ++cf) {
        const int krow = cf * 16 + l16;
        const bf16x8 k0 = *(const bf16x8*)(Kb + krow * 64 + ((lg ^ (krow & 7)) << 3));
        const bf16x8 k1 = *(const bf16x8*)(Kb + krow * 64 + (((4 + lg) ^ (krow & 7)) << 3));
        f32x4 z = zero4;
        z = MFMA_(k0, aq0, z, 0, 0, 0);
        z = MFMA_(k1, aq1, z, 0, 0, 0);
#pragma unroll
        for (int r = 0; r < 4; ++r) p[cf][r] = z[r];
      }

      if (t == nt - 1) {
        const int qg = q0 + wave * 16 + l16;
#pragma unroll
        for (int cf = 0; cf < 4; ++cf)
#pragma unroll
          for (int r = 0; r < 4; ++r)
            if (kv0 + cf * 16 + lg * 4 + r > qg) p[cf][r] = -1e30f;
      }

      float m = mreg;
#pragma unroll
      for (int cf = 0; cf < 4; ++cf) {
        m = fmaxf(m, fmaxf(p[cf][0], p[cf][1]));
        m = fmaxf(m, fmaxf(p[cf][2], p[cf][3]));
      }
      m = fmaxf(m, __shfl_xor(m, 16, 64));
      m = fmaxf(m, __shfl_xor(m, 32, 64));

      if (!__all(m - mreg <= 8.f)) {
        const float corr = ex2(mreg - m);
        mreg = m;
        lsum[0] *= corr;
#pragma unroll
        for (int df = 0; df < 4; ++df)
#pragma unroll
          for (int r = 0; r < 4; ++r) oacc[df][r] *= corr;
      }

#pragma unroll
      for (int cf = 0; cf < 4; ++cf)
#pragma unroll
        for (int r = 0; r < 4; ++r)
          p[cf][r] = ex2(p[cf][r] - mreg);

      const int row = l16;
#pragma unroll
      for (int cf = 0; cf < 4; ++cf) {
        const unsigned int w0 = pk_bf16(p[cf][0], p[cf][1]);
        const unsigned int w1 = pk_bf16(p[cf][2], p[cf][3]);
        const int u = cf * 2 + (lg >> 1);
        char* ad = (char*)pl + row * 128 + ((u ^ (row & 7)) << 4) + ((lg & 1) << 3);
        *(unsigned long long*)ad =
            (unsigned long long)w0 | ((unsigned long long)w1 << 32);
      }
      bf16x8 pf[2];
#pragma unroll
      for (int k2 = 0; k2 < 2; ++k2) {
        const int u = k2 * 4 + lg;
        pf[k2] = *(const bf16x8*)((char*)pl + row * 128 + ((u ^ (row & 7)) << 4));
      }

      lsum = MFMA_(onesv, pf[0], lsum, 0, 0, 0);
      lsum = MFMA_(onesv, pf[1], lsum, 0, 0, 0);
#pragma unroll
      for (int df = 0; df < 4; ++df) {
        const int vrow = df * 16 + l16;
        const bf16x8 v0 = *(const bf16x8*)(Vb + vrow * 64 + ((lg ^ (vrow & 7)) << 3));
        const bf16x8 v1 = *(const bf16x8*)(Vb + vrow * 64 + (((4 + lg) ^ (vrow & 7)) << 3));
        oacc[df] = MFMA_(v0, pf[0], oacc[df], 0, 0, 0);
        oacc[df] = MFMA_(v1, pf[1], oacc[df], 0, 0, 0);
      }

      asm volatile("s_waitcnt lgkmcnt(0)" ::: "memory");
      __builtin_amdgcn_sched_barrier(0);
      __builtin_amdgcn_s_barrier();
    }

    {
      const float inv = 1.f / lsum[0];
      const int tq = q0 + wave * 16 + l16;
      unsigned short* yp = Y + ((size_t)(b * T_ + tq)) * EMB_ + h * HEAD_;
#pragma unroll
      for (int df = 0; df < 4; ++df) {
        const unsigned int w0 = pk_bf16(oacc[df][0] * inv, oacc[df][1] * inv);
        const unsigned int w1 = pk_bf16(oacc[df][2] * inv, oacc[df][3] * inv);
        *(unsigned long long*)(yp + df * 16 + lg * 4) =
            (unsigned long long)w0 | ((unsigned long long)w1 << 32);
      }
    }
  }
#undef STAGE
}

// ---------------- launch ----------------

extern "C" void kernel_launch(void* const* d_in, const int* in_sizes, int n_in,
                              void* d_out, int out_size, void* d_ws, size_t ws_size,
                              hipStream_t stream) {
  const float* x  = (const float*)d_in[0];
  const float* Wq = (const float*)d_in[1];
  const float* bq = (const float*)d_in[2];
  const float* Wk = (const float*)d_in[3];
  const float* bk = (const float*)d_in[4];
  const float* Wv = (const float*)d_in[5];
  const float* bv = (const float*)d_in[6];
  const float* Wo = (const float*)d_in[7];
  const float* bo = (const float*)d_in[8];
  float* out = (float*)d_out;

  char* ws = (char*)d_ws;
  size_t off = 0;
  auto alloc = [&](size_t bytes) {
    void* p = ws + off;
    off += (bytes + 255) & ~(size_t)255;
    return p;
  };
  unsigned short* xb     = (unsigned short*)alloc((size_t)M_ * EMB_ * 2);
  unsigned short* WqkvT  = (unsigned short*)alloc((size_t)NTOT_ * EMB_ * 2);
  unsigned short* WoT    = (unsigned short*)alloc((size_t)EMB_ * EMB_ * 2);
  float*          bcat   = (float*)alloc((size_t)NTOT_ * 4);
  float2*         cstab  = (float2*)alloc((size_t)T_ * 32 * 8);
  unsigned short* QKVlin = (unsigned short*)alloc((size_t)M_ * NTOT_ * 2);
  unsigned short* Qh     = (unsigned short*)alloc((size_t)B_ * NQ_ * T_ * HEAD_ * 2);
  unsigned short* Kh     = (unsigned short*)alloc((size_t)B_ * NKV_ * T_ * HEAD_ * 2);
  unsigned short* Vt     = (unsigned short*)alloc((size_t)B_ * NKV_ * HEAD_ * T_ * 2);
  unsigned short* Yb     = (unsigned short*)alloc((size_t)M_ * EMB_ * 2);

  // prep: 3 launches
  cvt_bf16_kernel<<<(M_ * EMB_ / 4 + 255) / 256, 256, 0, stream>>>(x, xb, M_ * EMB_ / 4);
  prep_weights_kernel<<<10241, 256, 0, stream>>>(Wq, Wk, Wv, Wo, bq, bk, bv,
                                                 WqkvT, WoT, bcat);
  cs_table_kernel<<<256, 256, 0, stream>>>(cstab);

  // QKV projection: 128x192 3-phase, 512 blocks, bf16 out
  gemm_qkv_3ph<<<512, 512, 0, stream>>>(xb, WqkvT, bcat, QKVlin);

  // fused RoPE(Q,K) + V relayout: Q 4194304 + K 1048576 + V 2097152 = 7340032 thr
  rope_fused_kernel<<<28672, 256, 0, stream>>>(QKVlin, cstab, Qh, Kh, Vt);

  // flash attention: QBLK=64, paired (x, 31-x), 1024 blocks = 4/CU
  flash_attn_kernel<<<dim3(16, NQ_, B_), 256, 0, stream>>>(Qh, Kh, Vt, Yb);

  // output projection: 128x256 2-phase, 256 blocks, fp32 out
  gemm_o_2ph<<<256, 512, 0, stream>>>(Yb, WoT, bo, out);

  (void)in_sizes; (void)n_in; (void)out_size; (void)ws_size;
}

// Round 14
// 205.805 us; speedup vs baseline: 1.3490x; 1.0223x over previous
//
#include <hip/hip_runtime.h>
#include <hip/hip_bf16.h>
#include <cstdint>
#include <cstddef>

typedef __attribute__((ext_vector_type(4))) float f32x4;
typedef __attribute__((ext_vector_type(8))) short bf16x8;

#define B_    2
#define T_    2048
#define EMB_  2048
#define NQ_   32
#define NKV_  8
#define HEAD_ 64
#define NTOT_ 3072
#define M_    (B_ * T_)     // 4096
#define QBLK_ 64
#define NK_   32            // K=2048 / BK=64

#define MFMA_ __builtin_amdgcn_mfma_f32_16x16x32_bf16

__device__ __forceinline__ unsigned short f2bf(float f) {
  union { float f; unsigned int u; } v; v.f = f;
  unsigned int r = v.u + 0x7fffu + ((v.u >> 16) & 1u);
  return (unsigned short)(r >> 16);
}

__device__ __forceinline__ float bf2f(unsigned short u) {
  union { unsigned int u; float f; } v; v.u = (unsigned int)u << 16; return v.f;
}

__device__ __forceinline__ unsigned int pk_bf16(float lo, float hi) {
  __hip_bfloat162 h = __float22bfloat162_rn(make_float2(lo, hi));
  union { __hip_bfloat162 h; unsigned int u; } c; c.h = h;
  return c.u;
}

// raw v_exp_f32 (2^x) — libm exp2f takes the slow OCML fixup path
__device__ __forceinline__ float ex2(float x) {
  float r;
  asm("v_exp_f32 %0, %1" : "=v"(r) : "v"(x));
  return r;
}

__device__ __forceinline__ void gload_lds16(const void* g, void* l) {
  __builtin_amdgcn_global_load_lds(
      (const __attribute__((address_space(1))) void*)g,
      (__attribute__((address_space(3))) void*)l, 16, 0, 0);
}

#define L2_10000 13.2877123795494f
#define QSCALE_  0.18033688011112043f   // 0.125 * log2(e) -> softmax in exp2

// ---------------- single merged prep kernel ----------------
// Segments by blockIdx.x:
//   [0, 8192)        : x fp32 -> bf16 (float4 per thread)
//   [8192, 18432)    : 4 weight transposes (fp32 [R][C] -> bf16 [C][R])
//   18432            : bias concat
//   [18433, 18689)   : cos/sin table (2048 x 32)
__global__ void prep_all_kernel(const float* __restrict__ x,
                                const float* __restrict__ Wq,
                                const float* __restrict__ Wk,
                                const float* __restrict__ Wv,
                                const float* __restrict__ Wo,
                                const float* __restrict__ bq,
                                const float* __restrict__ bk,
                                const float* __restrict__ bv,
                                unsigned short* __restrict__ xb,
                                unsigned short* __restrict__ WqkvT,
                                unsigned short* __restrict__ WoT,
                                float* __restrict__ bcat,
                                float2* __restrict__ cstab) {
  __shared__ float tile[32][33];
  const int bid = blockIdx.x;
  if (bid < 8192) {                       // x -> bf16
    const int i = bid * 256 + threadIdx.x;   // < 2097152
    float4 v = ((const float4*)x)[i];
    unsigned long long pk =
        (unsigned long long)f2bf(v.x) |
        ((unsigned long long)f2bf(v.y) << 16) |
        ((unsigned long long)f2bf(v.z) << 32) |
        ((unsigned long long)f2bf(v.w) << 48);
    *(unsigned long long*)(xb + (size_t)i * 4) = pk;
    return;
  }
  if (bid < 18432) {                      // weight transposes
    const int wb = bid - 8192;
    const int tx = threadIdx.x & 31, ty = threadIdx.x >> 5;
    const float* src;
    unsigned short* dst;
    int C, local;
    if (wb < 4096)      { src = Wq; dst = WqkvT;                       C = 2048; local = wb; }
    else if (wb < 5120) { src = Wk; dst = WqkvT + (size_t)2048 * 2048; C = 512;  local = wb - 4096; }
    else if (wb < 6144) { src = Wv; dst = WqkvT + (size_t)2560 * 2048; C = 512;  local = wb - 5120; }
    else                { src = Wo; dst = WoT;                         C = 2048; local = wb - 6144; }
    const int tilesx = C >> 5;
    const int c0 = (local % tilesx) * 32, r0 = (local / tilesx) * 32;
#pragma unroll
    for (int k = 0; k < 4; ++k)
      tile[ty + 8 * k][tx] = src[(size_t)(r0 + ty + 8 * k) * C + c0 + tx];
    __syncthreads();
#pragma unroll
    for (int k = 0; k < 4; ++k)
      dst[(size_t)(c0 + ty + 8 * k) * 2048 + r0 + tx] = f2bf(tile[tx][ty + 8 * k]);
    return;
  }
  if (bid == 18432) {                     // bias concat
    const int t0 = threadIdx.x;
#pragma unroll
    for (int k = 0; k < 12; ++k) {
      const int i = k * 256 + t0;
      float v;
      if (i < 2048) v = bq[i];
      else if (i < 2560) v = bk[i - 2048];
      else v = bv[i - 2560];
      bcat[i] = v;
    }
    return;
  }
  {                                       // cos/sin table
    const int idx = (bid - 18433) * 256 + threadIdx.x;   // < 65536
    const int t = idx >> 5, i = idx & 31;
    float invf = exp2f(-(float)i * (L2_10000 / 32.f));
    float ang = (float)t * invf;
    float s, c; sincosf(ang, &s, &c);
    cstab[idx] = make_float2(c, s);
  }
}

// Fused RoPE(Q) + RoPE(K) + V-relayout, one pass over QKVlin (bf16), 1 launch.
__global__ void rope_fused_kernel(const unsigned short* __restrict__ qkv,
                                  const float2* __restrict__ tab,
                                  unsigned short* __restrict__ Qh,
                                  unsigned short* __restrict__ Kh,
                                  unsigned short* __restrict__ Vt) {
  int idx = blockIdx.x * 256 + threadIdx.x;
  if (idx < 4194304) {
    int i  = idx & 31;
    int h  = (idx >> 5) & 31;
    int bt = idx >> 10;
    int t  = bt & (T_ - 1);
    int b  = bt >> 11;
    float2 cs = tab[(t << 5) + i];
    const unsigned short* row = qkv + (size_t)bt * NTOT_ + h * 64;
    float x1 = bf2f(row[i]), x2 = bf2f(row[i + 32]);
    unsigned short* q = Qh + ((size_t)(b * NQ_ + h) * T_ + t) * HEAD_;
    q[i]      = f2bf((x1 * cs.x - x2 * cs.y) * QSCALE_);
    q[i + 32] = f2bf((x2 * cs.x + x1 * cs.y) * QSCALE_);
  } else if (idx < 5242880) {
    int j  = idx - 4194304;
    int i  = j & 31;
    int kh = (j >> 5) & 7;
    int bt = j >> 8;
    int t  = bt & (T_ - 1);
    int b  = bt >> 11;
    float2 cs = tab[(t << 5) + i];
    const unsigned short* row = qkv + (size_t)bt * NTOT_ + 2048 + kh * 64;
    float x1 = bf2f(row[i]), x2 = bf2f(row[i + 32]);
    unsigned short* kp = Kh + ((size_t)(b * NKV_ + kh) * T_ + t) * HEAD_;
    kp[i]      = f2bf(x1 * cs.x - x2 * cs.y);
    kp[i + 32] = f2bf(x2 * cs.x + x1 * cs.y);
  } else {
    int j  = idx - 5242880;   // 0 .. 2097151
    int t  = j & (T_ - 1);
    int d  = (j >> 11) & 63;
    int kh = (j >> 17) & 7;
    int b  = j >> 20;
    Vt[((size_t)((b * NKV_ + kh) * 64 + d)) * T_ + t] =
        qkv[(size_t)(b * T_ + t) * NTOT_ + 2560 + kh * 64 + d];
  }
}

// ---------------- QKV GEMM: 128x192 tile, 3-phase, K=2048 ----------------

__launch_bounds__(512, 4)
__global__ void gemm_qkv_3ph(const unsigned short* __restrict__ A,
                             const unsigned short* __restrict__ BT,
                             const float* __restrict__ bias,
                             unsigned short* __restrict__ C) {
  __shared__ unsigned short sh[2 * 20480];   // 80 KiB
  const int tid = threadIdx.x;
  const int lane = tid & 63, l16 = lane & 15, lg = lane >> 4;
  const int wave = tid >> 6, wm = wave >> 2, wn = wave & 3;
  const int bid = blockIdx.x;
  const int sw = (bid & 7) * 64 + (bid >> 3);
  const int mt = sw & 31, nt = sw >> 5;
  const int m0 = mt * 128, n0 = nt * 192;
  const int arow = tid >> 3;
  const int usrc = (tid & 7) ^ (arow & 7);
  const int swz = l16 & 7;
  const int uo0 = (lg ^ swz) << 3;
  const int uo1 = ((4 + lg) ^ swz) << 3;

  f32x4 acc[4][3];
#pragma unroll
  for (int i = 0; i < 4; ++i)
#pragma unroll
    for (int j = 0; j < 3; ++j) acc[i][j] = (f32x4){0.f, 0.f, 0.f, 0.f};

  auto STG = [&](int u) {
    if (u >= 5 * NK_) return;
    const int kt = u / 5, j = u % 5;
    char* bufb = (char*)sh + (kt & 1) * 40960;
    if (j < 2) {
      gload_lds16(A + (size_t)(m0 + j * 64 + arow) * 2048 + kt * 64 + usrc * 8,
                  bufb + j * 8192 + tid * 16);
    } else {
      const int jj = j - 2;
      gload_lds16(BT + (size_t)(n0 + jj * 64 + arow) * 2048 + kt * 64 + usrc * 8,
                  bufb + 16384 + jj * 8192 + tid * 16);
    }
  };

#pragma unroll
  for (int u = 0; u < 7; ++u) STG(u);
  asm volatile("s_waitcnt vmcnt(2)" ::: "memory");
  __builtin_amdgcn_s_barrier();

  for (int t = 0; t < NK_; ++t) {
    const unsigned short* Ab = sh + (t & 1) * 20480;
    const unsigned short* Bb = Ab + 8192;

    bf16x8 af[4][2], bfr[2];
#pragma unroll
    for (int fi = 0; fi < 4; ++fi) {
      const int ro = (fi * 32 + wm * 16 + l16) * 64;
      af[fi][0] = *(const bf16x8*)(Ab + ro + uo0);
      af[fi][1] = *(const bf16x8*)(Ab + ro + uo1);
    }
    {
      const int ro = (wn * 16 + l16) * 64;
      bfr[0] = *(const bf16x8*)(Bb + ro + uo0);
      bfr[1] = *(const bf16x8*)(Bb + ro + uo1);
    }
    STG(7 + 5 * t);  STG(8 + 5 * t);
    __builtin_amdgcn_s_barrier();
    asm volatile("s_waitcnt lgkmcnt(0)" ::: "memory");
    __builtin_amdgcn_sched_barrier(0);
    __builtin_amdgcn_s_setprio(1);
#pragma unroll
    for (int fi = 0; fi < 4; ++fi) {
      acc[fi][0] = MFMA_(af[fi][0], bfr[0], acc[fi][0], 0, 0, 0);
      acc[fi][0] = MFMA_(af[fi][1], bfr[1], acc[fi][0], 0, 0, 0);
    }
    __builtin_amdgcn_s_setprio(0);
    __builtin_amdgcn_s_barrier();

    {
      const int ro = (64 + wn * 16 + l16) * 64;
      bfr[0] = *(const bf16x8*)(Bb + ro + uo0);
      bfr[1] = *(const bf16x8*)(Bb + ro + uo1);
    }
    STG(9 + 5 * t);  STG(10 + 5 * t);
    __builtin_amdgcn_s_barrier();
    asm volatile("s_waitcnt lgkmcnt(0)" ::: "memory");
    __builtin_amdgcn_sched_barrier(0);
    __builtin_amdgcn_s_setprio(1);
#pragma unroll
    for (int fi = 0; fi < 4; ++fi) {
      acc[fi][1] = MFMA_(af[fi][0], bfr[0], acc[fi][1], 0, 0, 0);
      acc[fi][1] = MFMA_(af[fi][1], bfr[1], acc[fi][1], 0, 0, 0);
    }
    __builtin_amdgcn_s_setprio(0);
    __builtin_amdgcn_s_barrier();

    {
      const int ro = (128 + wn * 16 + l16) * 64;
      bfr[0] = *(const bf16x8*)(Bb + ro + uo0);
      bfr[1] = *(const bf16x8*)(Bb + ro + uo1);
    }
    STG(11 + 5 * t);
    __builtin_amdgcn_s_barrier();
    asm volatile("s_waitcnt lgkmcnt(0)" ::: "memory");
    __builtin_amdgcn_sched_barrier(0);
    __builtin_amdgcn_s_setprio(1);
#pragma unroll
    for (int fi = 0; fi < 4; ++fi) {
      acc[fi][2] = MFMA_(af[fi][0], bfr[0], acc[fi][2], 0, 0, 0);
      acc[fi][2] = MFMA_(af[fi][1], bfr[1], acc[fi][2], 0, 0, 0);
    }
    __builtin_amdgcn_s_setprio(0);
    if (t < NK_ - 2)       asm volatile("s_waitcnt vmcnt(2)" ::: "memory");
    else if (t == NK_ - 2) asm volatile("s_waitcnt vmcnt(0)" ::: "memory");
    __builtin_amdgcn_s_barrier();
  }

#pragma unroll
  for (int fj = 0; fj < 3; ++fj) {
    const int col = n0 + fj * 64 + wn * 16 + l16;
    const float bv = bias[col];
#pragma unroll
    for (int fi = 0; fi < 4; ++fi) {
      const int row0 = m0 + fi * 32 + wm * 16 + lg * 4;
#pragma unroll
      for (int r = 0; r < 4; ++r)
        C[(size_t)(row0 + r) * NTOT_ + col] = f2bf(acc[fi][fj][r] + bv);
    }
  }
}

// ---------------- out GEMM: 128x256 tile, 2-phase, K=2048 ----------------

__launch_bounds__(512, 2)
__global__ void gemm_o_2ph(const unsigned short* __restrict__ A,
                           const unsigned short* __restrict__ BT,
                           const float* __restrict__ bias,
                           float* __restrict__ C) {
  __shared__ unsigned short sh[2 * 24576];   // 96 KiB
  const int tid = threadIdx.x;
  const int lane = tid & 63, l16 = lane & 15, lg = lane >> 4;
  const int wave = tid >> 6, wm = wave >> 2, wn = wave & 3;
  const int bid = blockIdx.x;
  const int sw = (bid & 7) * 32 + (bid >> 3);
  const int mt = sw & 31, nt = sw >> 5;
  const int m0 = mt * 128, n0 = nt * 256;
  const int arow = tid >> 3;
  const int usrc = (tid & 7) ^ (arow & 7);
  const int swz = l16 & 7;
  const int uo0 = (lg ^ swz) << 3;
  const int uo1 = ((4 + lg) ^ swz) << 3;

  f32x4 acc[4][4];
#pragma unroll
  for (int i = 0; i < 4; ++i)
#pragma unroll
    for (int j = 0; j < 4; ++j) acc[i][j] = (f32x4){0.f, 0.f, 0.f, 0.f};

  auto STG = [&](int u) {
    if (u >= 6 * NK_) return;
    const int kt = u / 6, j = u % 6;
    char* bufb = (char*)sh + (kt & 1) * 49152;
    if (j < 2) {
      gload_lds16(A + (size_t)(m0 + j * 64 + arow) * 2048 + kt * 64 + usrc * 8,
                  bufb + j * 8192 + tid * 16);
    } else {
      const int jj = j - 2;
      gload_lds16(BT + (size_t)(n0 + jj * 64 + arow) * 2048 + kt * 64 + usrc * 8,
                  bufb + 16384 + jj * 8192 + tid * 16);
    }
  };

#pragma unroll
  for (int u = 0; u < 9; ++u) STG(u);
  asm volatile("s_waitcnt vmcnt(3)" ::: "memory");
  __builtin_amdgcn_s_barrier();

  for (int t = 0; t < NK_; ++t) {
    const unsigned short* Ab = sh + (t & 1) * 24576;
    const unsigned short* Bb = Ab + 8192;

    bf16x8 af[4][2], bfr[2][2];
#pragma unroll
    for (int fi = 0; fi < 4; ++fi) {
      const int ro = (fi * 32 + wm * 16 + l16) * 64;
      af[fi][0] = *(const bf16x8*)(Ab + ro + uo0);
      af[fi][1] = *(const bf16x8*)(Ab + ro + uo1);
    }
#pragma unroll
    for (int fj = 0; fj < 2; ++fj) {
      const int ro = (fj * 64 + wn * 16 + l16) * 64;
      bfr[fj][0] = *(const bf16x8*)(Bb + ro + uo0);
      bfr[fj][1] = *(const bf16x8*)(Bb + ro + uo1);
    }
    STG(9 + 6 * t);  STG(10 + 6 * t);  STG(11 + 6 * t);
    __builtin_amdgcn_s_barrier();
    asm volatile("s_waitcnt lgkmcnt(0)" ::: "memory");
    __builtin_amdgcn_sched_barrier(0);
    __builtin_amdgcn_s_setprio(1);
#pragma unroll
    for (int fi = 0; fi < 4; ++fi)
#pragma unroll
      for (int fj = 0; fj < 2; ++fj) {
        acc[fi][fj] = MFMA_(af[fi][0], bfr[fj][0], acc[fi][fj], 0, 0, 0);
        acc[fi][fj] = MFMA_(af[fi][1], bfr[fj][1], acc[fi][fj], 0, 0, 0);
      }
    __builtin_amdgcn_s_setprio(0);
    __builtin_amdgcn_s_barrier();

#pragma unroll
    for (int fj = 0; fj < 2; ++fj) {
      const int ro = ((2 + fj) * 64 + wn * 16 + l16) * 64;
      bfr[fj][0] = *(const bf16x8*)(Bb + ro + uo0);
      bfr[fj][1] = *(const bf16x8*)(Bb + ro + uo1);
    }
    STG(12 + 6 * t);  STG(13 + 6 * t);  STG(14 + 6 * t);
    __builtin_amdgcn_s_barrier();
    asm volatile("s_waitcnt lgkmcnt(0)" ::: "memory");
    __builtin_amdgcn_sched_barrier(0);
    __builtin_amdgcn_s_setprio(1);
#pragma unroll
    for (int fi = 0; fi < 4; ++fi)
#pragma unroll
      for (int fj = 0; fj < 2; ++fj) {
        acc[fi][2 + fj] = MFMA_(af[fi][0], bfr[fj][0], acc[fi][2 + fj], 0, 0, 0);
        acc[fi][2 + fj] = MFMA_(af[fi][1], bfr[fj][1], acc[fi][2 + fj], 0, 0, 0);
      }
    __builtin_amdgcn_s_setprio(0);
    if (t < NK_ - 2)       asm volatile("s_waitcnt vmcnt(3)" ::: "memory");
    else if (t == NK_ - 2) asm volatile("s_waitcnt vmcnt(0)" ::: "memory");
    __builtin_amdgcn_s_barrier();
  }

#pragma unroll
  for (int fj = 0; fj < 4; ++fj) {
    const int col = n0 + fj * 64 + wn * 16 + l16;
    const float bv = bias[col];
#pragma unroll
    for (int fi = 0; fi < 4; ++fi) {
      const int row0 = m0 + fi * 32 + wm * 16 + lg * 4;
#pragma unroll
      for (int r = 0; r < 4; ++r)
        C[(size_t)(row0 + r) * EMB_ + col] = acc[fi][fj][r] + bv;
    }
  }
}

// ---------------- flash attention: QBLK=64, 4 blocks/CU ----------------
// vmcnt(8) (not 4): with 16 outstanding loads (tile t's 8 + tile t+1's 8),
// waiting to 8 drains exactly tile t's loads and keeps all of t+1's in
// flight — the over-wait to 4 was serializing ~an L2 round-trip per tile.

__launch_bounds__(256, 2)
__global__ void flash_attn_kernel(const unsigned short* __restrict__ Qh,
                                  const unsigned short* __restrict__ Kh,
                                  const unsigned short* __restrict__ Vt,
                                  unsigned short* __restrict__ Y) {
  __shared__ unsigned short Klds[2][64 * 64];
  __shared__ unsigned short Vlds[2][64 * 64];
  __shared__ unsigned short Plds[4][16 * 64];
  const int tid = threadIdx.x;
  const int wave = tid >> 6, lane = tid & 63;
  const int l16 = lane & 15, lg = lane >> 4;
  const int h = blockIdx.y, b = blockIdx.z;
  const int kh = h >> 2;

  const size_t kbase = (size_t)(b * NKV_ + kh) * T_ * HEAD_;
  const size_t vbase = (size_t)(b * NKV_ + kh) * HEAD_ * T_;
  const int srow = tid >> 3;
  const int csrc = (tid & 7) ^ (srow & 7);
  unsigned short* pl = Plds[wave];
  const f32x4 zero4 = {0.f, 0.f, 0.f, 0.f};
  const short one_bf = (short)0x3F80;
  const bf16x8 onesv = {one_bf, one_bf, one_bf, one_bf,
                        one_bf, one_bf, one_bf, one_bf};

#define STAGE(bi, kv0) do {                                                         \
    gload_lds16(Kh + kbase + (size_t)((kv0) + srow) * HEAD_ + csrc * 8,             \
                (char*)Klds[bi] + tid * 16);                                        \
    gload_lds16(Kh + kbase + (size_t)((kv0) + srow + 32) * HEAD_ + csrc * 8,        \
                (char*)Klds[bi] + 4096 + tid * 16);                                 \
    gload_lds16(Vt + vbase + (size_t)srow * T_ + (kv0) + csrc * 8,                  \
                (char*)Vlds[bi] + tid * 16);                                        \
    gload_lds16(Vt + vbase + (size_t)(srow + 32) * T_ + (kv0) + csrc * 8,           \
                (char*)Vlds[bi] + 4096 + tid * 16);                                 \
  } while (0)

  for (int seg = 0; seg < 2; ++seg) {
    const int qt = seg ? (31 - (int)blockIdx.x) : (int)blockIdx.x;
    const int q0 = qt * QBLK_;
    const int nt = qt + 1;

    bf16x8 aq0, aq1;
    {
      const unsigned short* qp =
          Qh + ((size_t)(b * NQ_ + h) * T_ + q0 + wave * 16 + l16) * HEAD_;
      aq0 = *(const bf16x8*)(qp + lg * 8);
      aq1 = *(const bf16x8*)(qp + 32 + lg * 8);
    }

    f32x4 oacc[4];
    f32x4 lsum = zero4;
#pragma unroll
    for (int df = 0; df < 4; ++df) oacc[df] = zero4;
    float mreg = -1e30f;

    STAGE(0, 0);

    for (int t = 0; t < nt; ++t) {
      if (t + 1 < nt) {
        STAGE((t + 1) & 1, (t + 1) * 64);
        asm volatile("s_waitcnt vmcnt(8)" ::: "memory");
      } else {
        asm volatile("s_waitcnt vmcnt(0)" ::: "memory");
      }
      __builtin_amdgcn_s_barrier();
      __builtin_amdgcn_sched_barrier(0);

      const unsigned short* Kb = Klds[t & 1];
      const unsigned short* Vb = Vlds[t & 1];
      const int kv0 = t * 64;

      float p[4][4];
#pragma unroll
      for (int cf = 0; cf < 4; ++cf) {
        const int krow = cf * 16 + l16;
        const bf16x8 k0 = *(const bf16x8*)(Kb + krow * 64 + ((lg ^ (krow & 7)) << 3));
        const bf16x8 k1 = *(const bf16x8*)(Kb + krow * 64 + (((4 + lg) ^ (krow & 7)) << 3));
        f32x4 z = zero4;
        z = MFMA_(k0, aq0, z, 0, 0, 0);
        z = MFMA_(k1, aq1, z, 0, 0, 0);
#pragma unroll
        for (int r = 0; r < 4; ++r) p[cf][r] = z[r];
      }

      if (t == nt - 1) {
        const int qg = q0 + wave * 16 + l16;
#pragma unroll
        for (int cf = 0; cf < 4; ++cf)
#pragma unroll
          for (int r = 0; r < 4; ++r)
            if (kv0 + cf * 16 + lg * 4 + r > qg) p[cf][r] = -1e30f;
      }

      float m = mreg;
#pragma unroll
      for (int cf = 0; cf < 4; ++cf) {
        m = fmaxf(m, fmaxf(p[cf][0], p[cf][1]));
        m = fmaxf(m, fmaxf(p[cf][2], p[cf][3]));
      }
      m = fmaxf(m, __shfl_xor(m, 16, 64));
      m = fmaxf(m, __shfl_xor(m, 32, 64));

      if (!__all(m - mreg <= 8.f)) {
        const float corr = ex2(mreg - m);
        mreg = m;
        lsum[0] *= corr;
#pragma unroll
        for (int df = 0; df < 4; ++df)
#pragma unroll
          for (int r = 0; r < 4; ++r) oacc[df][r] *= corr;
      }

#pragma unroll
      for (int cf = 0; cf < 4; ++cf)
#pragma unroll
        for (int r = 0; r < 4; ++r)
          p[cf][r] = ex2(p[cf][r] - mreg);

      const int row = l16;
#pragma unroll
      for (int cf = 0; cf < 4; ++cf) {
        const unsigned int w0 = pk_bf16(p[cf][0], p[cf][1]);
        const unsigned int w1 = pk_bf16(p[cf][2], p[cf][3]);
        const int u = cf * 2 + (lg >> 1);
        char* ad = (char*)pl + row * 128 + ((u ^ (row & 7)) << 4) + ((lg & 1) << 3);
        *(unsigned long long*)ad =
            (unsigned long long)w0 | ((unsigned long long)w1 << 32);
      }
      bf16x8 pf[2];
#pragma unroll
      for (int k2 = 0; k2 < 2; ++k2) {
        const int u = k2 * 4 + lg;
        pf[k2] = *(const bf16x8*)((char*)pl + row * 128 + ((u ^ (row & 7)) << 4));
      }

      lsum = MFMA_(onesv, pf[0], lsum, 0, 0, 0);
      lsum = MFMA_(onesv, pf[1], lsum, 0, 0, 0);
#pragma unroll
      for (int df = 0; df < 4; ++df) {
        const int vrow = df * 16 + l16;
        const bf16x8 v0 = *(const bf16x8*)(Vb + vrow * 64 + ((lg ^ (vrow & 7)) << 3));
        const bf16x8 v1 = *(const bf16x8*)(Vb + vrow * 64 + (((4 + lg) ^ (vrow & 7)) << 3));
        oacc[df] = MFMA_(v0, pf[0], oacc[df], 0, 0, 0);
        oacc[df] = MFMA_(v1, pf[1], oacc[df], 0, 0, 0);
      }

      asm volatile("s_waitcnt lgkmcnt(0)" ::: "memory");
      __builtin_amdgcn_sched_barrier(0);
      __builtin_amdgcn_s_barrier();
    }

    {
      const float inv = 1.f / lsum[0];
      const int tq = q0 + wave * 16 + l16;
      unsigned short* yp = Y + ((size_t)(b * T_ + tq)) * EMB_ + h * HEAD_;
#pragma unroll
      for (int df = 0; df < 4; ++df) {
        const unsigned int w0 = pk_bf16(oacc[df][0] * inv, oacc[df][1] * inv);
        const unsigned int w1 = pk_bf16(oacc[df][2] * inv, oacc[df][3] * inv);
        *(unsigned long long*)(yp + df * 16 + lg * 4) =
            (unsigned long long)w0 | ((unsigned long long)w1 << 32);
      }
    }
  }
#undef STAGE
}

// ---------------- launch ----------------

extern "C" void kernel_launch(void* const* d_in, const int* in_sizes, int n_in,
                              void* d_out, int out_size, void* d_ws, size_t ws_size,
                              hipStream_t stream) {
  const float* x  = (const float*)d_in[0];
  const float* Wq = (const float*)d_in[1];
  const float* bq = (const float*)d_in[2];
  const float* Wk = (const float*)d_in[3];
  const float* bk = (const float*)d_in[4];
  const float* Wv = (const float*)d_in[5];
  const float* bv = (const float*)d_in[6];
  const float* Wo = (const float*)d_in[7];
  const float* bo = (const float*)d_in[8];
  float* out = (float*)d_out;

  char* ws = (char*)d_ws;
  size_t off = 0;
  auto alloc = [&](size_t bytes) {
    void* p = ws + off;
    off += (bytes + 255) & ~(size_t)255;
    return p;
  };
  unsigned short* xb     = (unsigned short*)alloc((size_t)M_ * EMB_ * 2);
  unsigned short* WqkvT  = (unsigned short*)alloc((size_t)NTOT_ * EMB_ * 2);
  unsigned short* WoT    = (unsigned short*)alloc((size_t)EMB_ * EMB_ * 2);
  float*          bcat   = (float*)alloc((size_t)NTOT_ * 4);
  float2*         cstab  = (float2*)alloc((size_t)T_ * 32 * 8);
  unsigned short* QKVlin = (unsigned short*)alloc((size_t)M_ * NTOT_ * 2);
  unsigned short* Qh     = (unsigned short*)alloc((size_t)B_ * NQ_ * T_ * HEAD_ * 2);
  unsigned short* Kh     = (unsigned short*)alloc((size_t)B_ * NKV_ * T_ * HEAD_ * 2);
  unsigned short* Vt     = (unsigned short*)alloc((size_t)B_ * NKV_ * HEAD_ * T_ * 2);
  unsigned short* Yb     = (unsigned short*)alloc((size_t)M_ * EMB_ * 2);

  // prep: 1 launch (x cvt + weight transposes + bias concat + cos/sin table)
  prep_all_kernel<<<18689, 256, 0, stream>>>(x, Wq, Wk, Wv, Wo, bq, bk, bv,
                                             xb, WqkvT, WoT, bcat, cstab);

  // QKV projection: 128x192 3-phase, 512 blocks, bf16 out
  gemm_qkv_3ph<<<512, 512, 0, stream>>>(xb, WqkvT, bcat, QKVlin);

  // fused RoPE(Q,K) + V relayout
  rope_fused_kernel<<<28672, 256, 0, stream>>>(QKVlin, cstab, Qh, Kh, Vt);

  // flash attention: QBLK=64, paired (x, 31-x), 1024 blocks = 4/CU
  flash_attn_kernel<<<dim3(16, NQ_, B_), 256, 0, stream>>>(Qh, Kh, Vt, Yb);

  // output projection: 128x256 2-phase, 256 blocks, fp32 out
  gemm_o_2ph<<<256, 512, 0, stream>>>(Yb, WoT, bo, out);

  (void)in_sizes; (void)n_in; (void)out_size; (void)ws_size;
}